// Round 1
// 565.020 us; speedup vs baseline: 1.1798x; 1.1798x over previous
//
#include <hip/hip_runtime.h>

// ---------------- constants ----------------
#define NTOK 8192
#define NORMC 0.35355339059327373f   // 64^-0.25
#define RATIO 0.0625f                // 256^-0.5
#define KEPS  1e-4f

// ws offsets in 4-byte elements  (total 27987008 ele = 106.8 MB)
#define O_KMAX 0                      // 12 x u32 (encoded max)
#define O_KSUM 64                     // 12*256 f32
#define O_CTX  3136                   // 12*256*64 f32
#define O_ZEND 199744                 // zeroed region end
#define O_COS  199744                 // 8192*32
#define O_SIN  461888                 // 8192*32
#define O_Q    724032                 // 2*8*8192*64
#define O_K    9112640                // K; later reused as attG [16384][384]
#define O_V    17501248
#define O_ATTL 25889856               // 2*2*8192*64 (local heads out)
// O_WH: fp16 W^T [3][512][512] lives in the ATTL region (dead until k_local,
// consumed only by k_qkv which runs first) -> zero footprint growth
#define O_WH   25889856
// end: 27987008

typedef _Float16 half8 __attribute__((ext_vector_type(8)));
typedef _Float16 half4h __attribute__((ext_vector_type(4)));
typedef float floatx4 __attribute__((ext_vector_type(4)));

__device__ __forceinline__ unsigned encf(float f) {
    unsigned u = __float_as_uint(f);
    return (u & 0x80000000u) ? ~u : (u | 0x80000000u);
}
__device__ __forceinline__ float decf(unsigned u) {
    return (u & 0x80000000u) ? __uint_as_float(u & 0x7fffffffu) : __uint_as_float(~u);
}

// ---------------- RoPE tables (double precision angles) ----------------
__global__ void k_rope(float* __restrict__ ws) {
    int idx = blockIdx.x * 256 + threadIdx.x;      // 8192*32
    int t = idx >> 5, i = idx & 31;
    double invf = pow(10000.0, -(double)(2 * i) / 64.0);
    double ang = (double)t * invf;
    ws[O_COS + idx] = (float)cos(ang);
    ws[O_SIN + idx] = (float)sin(ang);
}

// ---------------- W -> fp16, transposed to [n][k] ----------------
__launch_bounds__(256)
__global__ void k_half_w(const float* __restrict__ Wq,
                         const float* __restrict__ Wk,
                         const float* __restrict__ Wv,
                         float* __restrict__ ws) {
    __shared__ float T[64][65];
    const int z = blockIdx.z;
    const float* __restrict__ W = (z == 0) ? Wq : ((z == 1) ? Wk : Wv);
    _Float16* __restrict__ Wt = (_Float16*)(ws + O_WH) + (size_t)z * 262144;
    const int k0 = blockIdx.x * 64, n0 = blockIdx.y * 64;
    const int lx = threadIdx.x & 63, ly = threadIdx.x >> 6;   // ly in 0..3
#pragma unroll
    for (int i = 0; i < 16; i++) {
        const int kk = ly * 16 + i;
        T[lx][kk] = W[(k0 + kk) * 512 + n0 + lx];    // T[n-n0][k-k0]
    }
    __syncthreads();
#pragma unroll
    for (int i = 0; i < 16; i++) {
        const int nn = ly * 16 + i;
        Wt[(n0 + nn) * 512 + k0 + lx] = (_Float16)T[nn][lx];
    }
}

// ---------------- QKV projection via fp16 MFMA ----------------
__launch_bounds__(256)
__global__ void k_qkv(const float* __restrict__ x, float* __restrict__ ws) {
    __shared__ _Float16 Ah[128 * 72];
    __shared__ _Float16 Bh[128 * 72];
    const int z = blockIdx.z;
    const _Float16* __restrict__ Wt = (const _Float16*)(ws + O_WH) + (size_t)z * 262144;
    float* __restrict__ out = ws + ((z == 0) ? O_Q : ((z == 1) ? O_K : O_V));
    const int r0 = blockIdx.x * 128, c0 = blockIdx.y * 128;
    const int tid = threadIdx.x;
    const int wv = tid >> 6, lane = tid & 63, lm = lane & 15, lq = lane >> 4;
    const int srow = tid >> 1, skoff = (tid & 1) * 32;
    floatx4 acc[2][8];
#pragma unroll
    for (int m = 0; m < 2; m++)
#pragma unroll
        for (int n = 0; n < 8; n++) acc[m][n] = (floatx4){0.f, 0.f, 0.f, 0.f};

    for (int c = 0; c < 8; c++) {
        const int k0 = c * 64;
        {   // stage A: x fp32 -> fp16 (row-major, k contiguous)
            const float* ap = x + (size_t)(r0 + srow) * 512 + k0 + skoff;
#pragma unroll
            for (int q = 0; q < 4; q++) {
                float4 v0 = *(const float4*)(ap + 8 * q);
                float4 v1 = *(const float4*)(ap + 8 * q + 4);
                half8 h = {(_Float16)v0.x, (_Float16)v0.y, (_Float16)v0.z, (_Float16)v0.w,
                           (_Float16)v1.x, (_Float16)v1.y, (_Float16)v1.z, (_Float16)v1.w};
                *(half8*)&Ah[srow * 72 + skoff + 8 * q] = h;
            }
        }
        {   // stage B: fp16 W^T direct copy
            const _Float16* bp = Wt + (size_t)(c0 + srow) * 512 + k0 + skoff;
#pragma unroll
            for (int q = 0; q < 4; q++)
                *(uint4*)&Bh[srow * 72 + skoff + 8 * q] = *(const uint4*)(bp + 8 * q);
        }
        __syncthreads();
#pragma unroll
        for (int ks = 0; ks < 2; ks++) {
            half8 af[2], bf[8];
            af[0] = *(half8*)&Ah[(wv * 32 + lm) * 72 + ks * 32 + lq * 8];
            af[1] = *(half8*)&Ah[(wv * 32 + 16 + lm) * 72 + ks * 32 + lq * 8];
#pragma unroll
            for (int n = 0; n < 8; n++)
                bf[n] = *(half8*)&Bh[(n * 16 + lm) * 72 + ks * 32 + lq * 8];
#pragma unroll
            for (int m = 0; m < 2; m++)
#pragma unroll
                for (int n = 0; n < 8; n++)
                    acc[m][n] = __builtin_amdgcn_mfma_f32_16x16x32_f16(af[m], bf[n], acc[m][n], 0, 0, 0);
        }
        __syncthreads();
    }
    const int bi = r0 >> 13;
#pragma unroll
    for (int n = 0; n < 8; n++) {
        const int col = c0 + n * 16 + lm;
        const int h = col >> 6, d = col & 63;
#pragma unroll
        for (int m = 0; m < 2; m++) {
            const int rbase = r0 + wv * 32 + m * 16 + lq * 4;
#pragma unroll
            for (int j = 0; j < 4; j++) {
                const int ng = (rbase + j) & 8191;
                out[((size_t)(bi * 8 + h) * 8192 + ng) * 64 + d] = acc[m][n][j];
            }
        }
    }
}

// ---------------- key-side global max of dd = norm*(K.projT) ----------------
__launch_bounds__(256)
__global__ void k_kmax(const float* __restrict__ proj, float* __restrict__ ws) {
    __shared__ float As[16][64];     // [d][n]
    __shared__ float Bs[16][256];    // [d][j]
    __shared__ unsigned bmax;
    const int bh = blockIdx.x, b = bh / 6, h = bh % 6;
    const float* __restrict__ Kp = ws + O_K + (b * 8 + h) * 8192 * 64;
    const int n0 = blockIdx.y * 64;
    const int tid = threadIdx.x, tx = tid & 15, ty = tid >> 4;
    if (tid == 0) bmax = 0u;
    const int an = tid >> 2, adq = (tid & 3) * 4;
    float acc[4][16];
#pragma unroll
    for (int i = 0; i < 4; i++)
#pragma unroll
        for (int j = 0; j < 16; j++) acc[i][j] = 0.f;

    for (int k0 = 0; k0 < 64; k0 += 16) {
        float4 va = *(const float4*)(Kp + (n0 + an) * 64 + k0 + adq);
        float fp[16];
#pragma unroll
        for (int q = 0; q < 4; q++) {
            float4 p = *(const float4*)(proj + tid * 64 + k0 + q * 4);
            fp[q*4+0] = p.x; fp[q*4+1] = p.y; fp[q*4+2] = p.z; fp[q*4+3] = p.w;
        }
        As[adq + 0][an] = va.x; As[adq + 1][an] = va.y;
        As[adq + 2][an] = va.z; As[adq + 3][an] = va.w;
#pragma unroll
        for (int l = 0; l < 16; l++) Bs[l][tid] = fp[l];
        __syncthreads();
#pragma unroll
        for (int kk = 0; kk < 16; kk++) {
            float4 a4 = *(float4*)&As[kk][ty * 4];
            float a[4] = {a4.x, a4.y, a4.z, a4.w};
#pragma unroll
            for (int g = 0; g < 4; g++) {
                float4 b4 = *(float4*)&Bs[kk][g * 64 + tx * 4];
                float bb[4] = {b4.x, b4.y, b4.z, b4.w};
#pragma unroll
                for (int i = 0; i < 4; i++)
#pragma unroll
                    for (int j = 0; j < 4; j++)
                        acc[i][g * 4 + j] = fmaf(a[i], bb[j], acc[i][g * 4 + j]);
            }
        }
        __syncthreads();
    }
    float m = acc[0][0];
#pragma unroll
    for (int i = 0; i < 4; i++)
#pragma unroll
        for (int j = 0; j < 16; j++) m = fmaxf(m, acc[i][j]);
    atomicMax(&bmax, encf(m * NORMC));
    __syncthreads();
    if (tid == 0) atomicMax((unsigned*)ws + O_KMAX + bh, bmax);
}

// ---------------- key-side: kp, k_sum, ctx = kp^T @ V  (fp16 MFMA) ----------------
// Grid (12 bh, 32 n-chunks of 256, 2 j-halves of 128). 4 waves; wave w owns
// j-range w*32 within the half. Per 64-row n-sub: dd=K.projT (MFMA), exp in
// C-layout regs, kp->LDS [j][n] fp16, ctx += kp^T.V (MFMA, V staged [d][n]).
// ctx persists in 32 regs/lane, flushed once. LDS ~53 KB -> 3 blocks/CU.
__launch_bounds__(256)
__global__ void k_kctx(const float* __restrict__ proj, float* __restrict__ ws) {
    __shared__ _Float16 Kh[64 * 68];     // K sub [n][d]
    __shared__ _Float16 Vt[64 * 68];     // V sub transposed [d][n]
    __shared__ _Float16 Ph[128 * 68];    // proj half [j][d]
    __shared__ _Float16 kpt[128 * 68];   // kp transposed [j][n]
    __shared__ float diag4[64][4];       // per-row |K|^2 partials (race-free)
    __shared__ float ksum_s[128];
    const int bh = blockIdx.x, b = bh / 6, h = bh % 6;
    const int n0 = blockIdx.y * 256;
    const int jh = blockIdx.z;
    const float* __restrict__ Kp = ws + O_K + (size_t)(b * 8 + h) * 8192 * 64;
    const float* __restrict__ Vp = ws + O_V + (size_t)(b * 8 + h) * 8192 * 64;
    const float kmax = decf(((const unsigned*)ws)[O_KMAX + bh]);
    const int tid = threadIdx.x;
    const int wv = tid >> 6, lane = tid & 63, lm = lane & 15, lq = lane >> 4;
    if (tid < 128) ksum_s[tid] = 0.f;

    {   // stage Ph once: proj rows jh*128.., [jrel][d] stride 68
        const int r = tid >> 1, doff = (tid & 1) * 32;
        const float* pp = proj + (jh * 128 + r) * 64 + doff;
#pragma unroll
        for (int q = 0; q < 4; q++) {
            float4 v0 = *(const float4*)(pp + 8 * q);
            float4 v1 = *(const float4*)(pp + 8 * q + 4);
            half8 hv = {(_Float16)v0.x, (_Float16)v0.y, (_Float16)v0.z, (_Float16)v0.w,
                        (_Float16)v1.x, (_Float16)v1.y, (_Float16)v1.z, (_Float16)v1.w};
            *(half8*)&Ph[r * 68 + doff + 8 * q] = hv;
        }
    }
    floatx4 acc[2][4];   // ctx tiles [jt][dt]
#pragma unroll
    for (int jt = 0; jt < 2; jt++)
#pragma unroll
        for (int dt = 0; dt < 4; dt++) acc[jt][dt] = (floatx4){0.f, 0.f, 0.f, 0.f};

    for (int nc = 0; nc < 4; nc++) {
        const int ns = n0 + nc * 64;
        {   // stage Kh [n][d] + diag partials
            const int r = tid >> 2, dq = (tid & 3) * 16;
            const float* kpp = Kp + (size_t)(ns + r) * 64 + dq;
            float part = 0.f;
            _Float16 t[16];
#pragma unroll
            for (int q = 0; q < 4; q++) {
                float4 v = *(const float4*)(kpp + 4 * q);
                part = fmaf(v.x, v.x, fmaf(v.y, v.y, fmaf(v.z, v.z, fmaf(v.w, v.w, part))));
                t[4*q+0] = (_Float16)v.x; t[4*q+1] = (_Float16)v.y;
                t[4*q+2] = (_Float16)v.z; t[4*q+3] = (_Float16)v.w;
            }
            *(half8*)&Kh[r * 68 + dq]     = *(half8*)&t[0];
            *(half8*)&Kh[r * 68 + dq + 8] = *(half8*)&t[8];
            diag4[r][tid & 3] = part;
        }
        {   // stage Vt transposed [d][n]: thread d = tid&63, n-block of 16
            const int d = tid & 63, nb = (tid >> 6) * 16;
            _Float16 t[16];
#pragma unroll
            for (int i = 0; i < 16; i++)
                t[i] = (_Float16)Vp[(size_t)(ns + nb + i) * 64 + d];
            *(half8*)&Vt[d * 68 + nb]     = *(half8*)&t[0];
            *(half8*)&Vt[d * 68 + nb + 8] = *(half8*)&t[8];
        }
        __syncthreads();                              // A: Kh/Vt/diag4 ready (kpt free)
        // dd[n][j]: M=64 n, N=32 j (this wave), K=64
        floatx4 s4[4][2];
#pragma unroll
        for (int nt = 0; nt < 4; nt++)
#pragma unroll
            for (int jt = 0; jt < 2; jt++) s4[nt][jt] = (floatx4){0.f, 0.f, 0.f, 0.f};
#pragma unroll
        for (int ks = 0; ks < 2; ks++) {
            half8 af[4], bf[2];
#pragma unroll
            for (int nt = 0; nt < 4; nt++)
                af[nt] = *(half8*)&Kh[(nt * 16 + lm) * 68 + ks * 32 + lq * 8];
#pragma unroll
            for (int jt = 0; jt < 2; jt++)
                bf[jt] = *(half8*)&Ph[(wv * 32 + jt * 16 + lm) * 68 + ks * 32 + lq * 8];
#pragma unroll
            for (int nt = 0; nt < 4; nt++)
#pragma unroll
                for (int jt = 0; jt < 2; jt++)
                    s4[nt][jt] = __builtin_amdgcn_mfma_f32_16x16x32_f16(af[nt], bf[jt], s4[nt][jt], 0, 0, 0);
        }
        // exp in C-layout (col=j=lm, row=n=lq*4+reg), kp -> kpt [j][n] fp16
        float jsum[2] = {0.f, 0.f};
#pragma unroll
        for (int nt = 0; nt < 4; nt++) {
            float dg[4];
#pragma unroll
            for (int r = 0; r < 4; r++) {
                float4 d4 = *(float4*)diag4[nt * 16 + lq * 4 + r];   // broadcast read
                dg[r] = (d4.x + d4.y + d4.z + d4.w) * 0.0625f;
            }
#pragma unroll
            for (int jt = 0; jt < 2; jt++) {
                half4h kv;
#pragma unroll
                for (int r = 0; r < 4; r++) {
                    float v = RATIO * (expf(fminf(NORMC * s4[nt][jt][r] - dg[r] - kmax, 0.f)) + KEPS);
                    jsum[jt] += v;
                    kv[r] = (_Float16)v;
                }
                *(half4h*)&kpt[(wv * 32 + jt * 16 + lm) * 68 + nt * 16 + lq * 4] = kv;
            }
        }
#pragma unroll
        for (int jt = 0; jt < 2; jt++)
            atomicAdd(&ksum_s[wv * 32 + jt * 16 + lm], jsum[jt]);
        __syncthreads();                              // B: kpt ready
        // ctx[j][d] += kp^T @ V: M=32 j (this wave), N=64 d, K=64 n
#pragma unroll
        for (int ks = 0; ks < 2; ks++) {
            half8 af[2], bf[4];
#pragma unroll
            for (int jt = 0; jt < 2; jt++)
                af[jt] = *(half8*)&kpt[(wv * 32 + jt * 16 + lm) * 68 + ks * 32 + lq * 8];
#pragma unroll
            for (int dt = 0; dt < 4; dt++)
                bf[dt] = *(half8*)&Vt[(dt * 16 + lm) * 68 + ks * 32 + lq * 8];
#pragma unroll
            for (int jt = 0; jt < 2; jt++)
#pragma unroll
                for (int dt = 0; dt < 4; dt++)
                    acc[jt][dt] = __builtin_amdgcn_mfma_f32_16x16x32_f16(af[jt], bf[dt], acc[jt][dt], 0, 0, 0);
        }
        __syncthreads();                              // D: before next staging
    }
    // flush: C-layout col=d=lm, row=j=lq*4+reg
    float* __restrict__ ctxp = ws + O_CTX + bh * 16384;
#pragma unroll
    for (int jt = 0; jt < 2; jt++) {
#pragma unroll
        for (int dt = 0; dt < 4; dt++) {
            const int d = dt * 16 + lm;
#pragma unroll
            for (int r = 0; r < 4; r++) {
                const int j = jh * 128 + wv * 32 + jt * 16 + lq * 4 + r;
                atomicAdd(&ctxp[j * 64 + d], acc[jt][dt][r]);
            }
        }
    }
    if (tid < 128) atomicAdd(ws + O_KSUM + bh * 256 + jh * 128 + tid, ksum_s[tid]);
}

// ---------------- query-side: dd, rowmax, qp, attG = qp.ctx / (qp.ksum) ----------------
__launch_bounds__(256)
__global__ void k_qout(const float* __restrict__ proj, float* __restrict__ ws) {
    __shared__ float As1[16][64];
    __shared__ float Bs1[16][256];
    __shared__ float qps[64][68];    // qp [n][j-chunk]
    __shared__ float Bs2[64][68];    // ctx chunk [j][d]
    __shared__ float ksum_s[256];
    __shared__ unsigned rmax[64];
    __shared__ float diag_s[64];
    __shared__ float denom_s[64];
    const int bh = blockIdx.x, b = bh / 6, h = bh % 6;
    const int n0 = blockIdx.y * 64;
    const float* __restrict__ Qp = ws + O_Q + (b * 8 + h) * 8192 * 64;
    const float* __restrict__ ctxp = ws + O_CTX + bh * 16384;
    float* __restrict__ attG = ws + O_K;     // [16384][384]
    const int tid = threadIdx.x, tx = tid & 15, ty = tid >> 4;
    if (tid < 64) { rmax[tid] = 0u; diag_s[tid] = 0.f; denom_s[tid] = 0.f; }
    ksum_s[tid] = ws[O_KSUM + bh * 256 + tid];
    float acc1[4][16];
#pragma unroll
    for (int i = 0; i < 4; i++)
#pragma unroll
        for (int j = 0; j < 16; j++) acc1[i][j] = 0.f;
    const int an = tid >> 2, adq = (tid & 3) * 4;

    for (int kt = 0; kt < 4; kt++) {
        const int k0 = kt * 16;
        float4 va = *(const float4*)(Qp + (n0 + an) * 64 + k0 + adq);
        float fp[16];
#pragma unroll
        for (int q = 0; q < 4; q++) {
            float4 p = *(const float4*)(proj + tid * 64 + k0 + q * 4);
            fp[q*4+0] = p.x; fp[q*4+1] = p.y; fp[q*4+2] = p.z; fp[q*4+3] = p.w;
        }
        As1[adq + 0][an] = va.x; As1[adq + 1][an] = va.y;
        As1[adq + 2][an] = va.z; As1[adq + 3][an] = va.w;
#pragma unroll
        for (int l = 0; l < 16; l++) Bs1[l][tid] = fp[l];
        __syncthreads();
        if (tid < 64) {
            float s = diag_s[tid];
#pragma unroll
            for (int kk = 0; kk < 16; kk++) { float v = As1[kk][tid]; s = fmaf(v, v, s); }
            diag_s[tid] = s;
        }
#pragma unroll
        for (int kk = 0; kk < 16; kk++) {
            float4 a4 = *(float4*)&As1[kk][ty * 4];
            float a[4] = {a4.x, a4.y, a4.z, a4.w};
#pragma unroll
            for (int g = 0; g < 4; g++) {
                float4 b4 = *(float4*)&Bs1[kk][g * 64 + tx * 4];
                float bb[4] = {b4.x, b4.y, b4.z, b4.w};
#pragma unroll
                for (int i = 0; i < 4; i++)
#pragma unroll
                    for (int j = 0; j < 4; j++)
                        acc1[i][g * 4 + j] = fmaf(a[i], bb[j], acc1[i][g * 4 + j]);
            }
        }
        __syncthreads();
    }
#pragma unroll
    for (int i = 0; i < 4; i++) {
        float m = acc1[i][0];
#pragma unroll
        for (int c = 1; c < 16; c++) m = fmaxf(m, acc1[i][c]);
        atomicMax(&rmax[ty * 4 + i], encf(m * NORMC));
    }
    __syncthreads();
    float rmx[4], dg[4];
#pragma unroll
    for (int i = 0; i < 4; i++) {
        rmx[i] = decf(rmax[ty * 4 + i]);
        dg[i] = diag_s[ty * 4 + i] * 0.0625f;
    }
    float acc2[4][4];
#pragma unroll
    for (int i = 0; i < 4; i++)
#pragma unroll
        for (int j = 0; j < 4; j++) acc2[i][j] = 0.f;

    for (int jc = 0; jc < 4; jc++) {
#pragma unroll
        for (int i = 0; i < 4; i++) {
            float q0 = RATIO * (expf(fminf(NORMC * acc1[i][jc * 4 + 0] - dg[i] - rmx[i], 0.f)) + KEPS);
            float q1 = RATIO * (expf(fminf(NORMC * acc1[i][jc * 4 + 1] - dg[i] - rmx[i], 0.f)) + KEPS);
            float q2 = RATIO * (expf(fminf(NORMC * acc1[i][jc * 4 + 2] - dg[i] - rmx[i], 0.f)) + KEPS);
            float q3 = RATIO * (expf(fminf(NORMC * acc1[i][jc * 4 + 3] - dg[i] - rmx[i], 0.f)) + KEPS);
            *(float4*)&qps[ty * 4 + i][tx * 4] = make_float4(q0, q1, q2, q3);
            float ds = q0 * ksum_s[jc * 64 + tx * 4 + 0] + q1 * ksum_s[jc * 64 + tx * 4 + 1]
                     + q2 * ksum_s[jc * 64 + tx * 4 + 2] + q3 * ksum_s[jc * 64 + tx * 4 + 3];
            atomicAdd(&denom_s[ty * 4 + i], ds);
        }
        {   // stage ctx chunk
            const int ck = tid >> 2, cdq = (tid & 3) * 16;
#pragma unroll
            for (int wv = 0; wv < 4; wv++) {
                float4 v = *(const float4*)(ctxp + (jc * 64 + ck) * 64 + cdq + 4 * wv);
                *(float4*)&Bs2[ck][cdq + 4 * wv] = v;
            }
        }
        __syncthreads();
#pragma unroll 8
        for (int kk = 0; kk < 64; kk++) {
            float a[4] = {qps[ty * 4 + 0][kk], qps[ty * 4 + 1][kk],
                          qps[ty * 4 + 2][kk], qps[ty * 4 + 3][kk]};
            float4 b4 = *(float4*)&Bs2[kk][tx * 4];
            float bb[4] = {b4.x, b4.y, b4.z, b4.w};
#pragma unroll
            for (int i = 0; i < 4; i++)
#pragma unroll
                for (int j = 0; j < 4; j++) acc2[i][j] = fmaf(a[i], bb[j], acc2[i][j]);
        }
        __syncthreads();
    }
#pragma unroll
    for (int i = 0; i < 4; i++) {
        int n = n0 + ty * 4 + i;
        float inv = 1.0f / fmaxf(denom_s[ty * 4 + i], 1e-30f);
        *(float4*)&attG[(b * 8192 + n) * 384 + h * 64 + tx * 4] =
            make_float4(acc2[i][0] * inv, acc2[i][1] * inv, acc2[i][2] * inv, acc2[i][3] * inv);
    }
}

// ---------------- local windowed attention w/ RoPE, heads 6..7 (fp16 MFMA) ----------------
// 4 waves; wave wv owns q-rows wv*16..wv*16+15 of the 64-q tile. Per 64-key
// chunk: stage RoPE'd K [k][d] fp16 + V transposed [d][k] fp16; QK^T via
// 16x16x32 MFMA (C layout: col=k=lm, row=q=lq*4+r); online softmax fully in
// registers (row-max via 4-step shfl_xor over lm; l kept as per-lane partial,
// reduced once at the end); P -> fp16 LDS [q][k]; PV via MFMA into fp32 acc.
__launch_bounds__(256)
__global__ void k_local(float* __restrict__ ws) {
    __shared__ _Float16 Qh[64 * 68];     // RoPE'd Q [q][d]
    __shared__ _Float16 Kh[64 * 68];     // RoPE'd K chunk [k][d]
    __shared__ _Float16 Vt[64 * 68];     // V chunk transposed [d][k]
    __shared__ _Float16 pT[64 * 68];     // P [q][k] fp16
    const int bhp = blockIdx.x, b = bhp >> 1, lh = bhp & 1, h = 6 + lh;
    const int tile = blockIdx.y;                 // 0..127 (64-query tiles)
    const int w = tile >> 2;                     // window index
    const int q0 = tile * 64;
    const float* __restrict__ Qb = ws + O_Q + (size_t)(b * 8 + h) * 8192 * 64;
    const float* __restrict__ Kb = ws + O_K + (size_t)(b * 8 + h) * 8192 * 64;
    const float* __restrict__ Vb = ws + O_V + (size_t)(b * 8 + h) * 8192 * 64;
    const float* __restrict__ cosT = ws + O_COS;
    const float* __restrict__ sinT = ws + O_SIN;
    const int tid = threadIdx.x;
    const int wv = tid >> 6, lane = tid & 63, lm = lane & 15, lq = lane >> 4;
    // staging mapping: 4 threads per row, 16 dims each
    const int row = tid >> 2, dq = (tid & 3) * 16;
    const int e = dq & 31;
    const int comp = (dq < 32) ? dq + 32 : dq - 32;
    const float sgn = (dq < 32) ? -1.f : 1.f;

    {   // stage Q tile with RoPE -> fp16 [q][d]
        const int qpos = q0 + row;
        const float* bp = Qb + (size_t)qpos * 64;
        const float* cp = cosT + qpos * 32 + e;
        const float* sp = sinT + qpos * 32 + e;
        _Float16 t[16];
#pragma unroll
        for (int w4 = 0; w4 < 4; w4++) {
            float4 c4 = *(const float4*)(cp + 4 * w4);
            float4 s4v = *(const float4*)(sp + 4 * w4);
            float4 xa = *(const float4*)(bp + dq + 4 * w4);
            float4 xb = *(const float4*)(bp + comp + 4 * w4);
            t[4*w4+0] = (_Float16)fmaf(sgn * xb.x, s4v.x, xa.x * c4.x);
            t[4*w4+1] = (_Float16)fmaf(sgn * xb.y, s4v.y, xa.y * c4.y);
            t[4*w4+2] = (_Float16)fmaf(sgn * xb.z, s4v.z, xa.z * c4.z);
            t[4*w4+3] = (_Float16)fmaf(sgn * xb.w, s4v.w, xa.w * c4.w);
        }
        *(half8*)&Qh[row * 68 + dq]     = *(half8*)&t[0];
        *(half8*)&Qh[row * 68 + dq + 8] = *(half8*)&t[8];
    }
    floatx4 O[4];                    // [df] rows=q (lq*4+r), cols=d (df*16+lm)
#pragma unroll
    for (int df = 0; df < 4; df++) O[df] = (floatx4){0.f, 0.f, 0.f, 0.f};
    float m_run[4] = {-1e30f, -1e30f, -1e30f, -1e30f};
    float l_run[4] = {0.f, 0.f, 0.f, 0.f};

    for (int c = 0; c < 12; c++) {
        const int kp0 = (w - 1) * 256 + c * 64;
        if (kp0 < 0 || kp0 >= 8192) continue;    // look_around pad (block-uniform)
        __syncthreads();             // prior chunk's Vt/pT reads done
        {   // stage K chunk (RoPE) fp16 [k][d]
            const int kpos = kp0 + row;
            const float* bp = Kb + (size_t)kpos * 64;
            const float* cp = cosT + kpos * 32 + e;
            const float* sp = sinT + kpos * 32 + e;
            _Float16 t[16];
#pragma unroll
            for (int w4 = 0; w4 < 4; w4++) {
                float4 c4 = *(const float4*)(cp + 4 * w4);
                float4 s4v = *(const float4*)(sp + 4 * w4);
                float4 xa = *(const float4*)(bp + dq + 4 * w4);
                float4 xb = *(const float4*)(bp + comp + 4 * w4);
                t[4*w4+0] = (_Float16)fmaf(sgn * xb.x, s4v.x, xa.x * c4.x);
                t[4*w4+1] = (_Float16)fmaf(sgn * xb.y, s4v.y, xa.y * c4.y);
                t[4*w4+2] = (_Float16)fmaf(sgn * xb.z, s4v.z, xa.z * c4.z);
                t[4*w4+3] = (_Float16)fmaf(sgn * xb.w, s4v.w, xa.w * c4.w);
            }
            *(half8*)&Kh[row * 68 + dq]     = *(half8*)&t[0];
            *(half8*)&Kh[row * 68 + dq + 8] = *(half8*)&t[8];
        }
        {   // stage V transposed fp16 [d][k]: lane d, wave's 16-row block
            const int d = lane, nb = wv * 16;
            _Float16 t[16];
#pragma unroll
            for (int i = 0; i < 16; i++)
                t[i] = (_Float16)Vb[(size_t)(kp0 + nb + i) * 64 + d];
            *(half8*)&Vt[d * 68 + nb]     = *(half8*)&t[0];
            *(half8*)&Vt[d * 68 + nb + 8] = *(half8*)&t[8];
        }
        __syncthreads();             // Kh/Vt ready
        // QK^T: M=16 q (this wave), N=64 k, K=64 d
        floatx4 s4[4];
#pragma unroll
        for (int nf = 0; nf < 4; nf++) s4[nf] = (floatx4){0.f, 0.f, 0.f, 0.f};
#pragma unroll
        for (int ks = 0; ks < 2; ks++) {
            half8 aq = *(half8*)&Qh[(wv * 16 + lm) * 68 + ks * 32 + lq * 8];
            half8 bf[4];
#pragma unroll
            for (int nf = 0; nf < 4; nf++)
                bf[nf] = *(half8*)&Kh[(nf * 16 + lm) * 68 + ks * 32 + lq * 8];
#pragma unroll
            for (int nf = 0; nf < 4; nf++)
                s4[nf] = __builtin_amdgcn_mfma_f32_16x16x32_f16(aq, bf[nf], s4[nf], 0, 0, 0);
        }
        // online softmax in registers; scale = 64^-0.5 = 0.125
        float p[4][4];
#pragma unroll
        for (int r = 0; r < 4; r++) {
            float m0 = fmaxf(fmaxf(s4[0][r], s4[1][r]), fmaxf(s4[2][r], s4[3][r]));
            m0 = fmaxf(m0, __shfl_xor(m0, 1, 64));
            m0 = fmaxf(m0, __shfl_xor(m0, 2, 64));
            m0 = fmaxf(m0, __shfl_xor(m0, 4, 64));
            m0 = fmaxf(m0, __shfl_xor(m0, 8, 64));
            const float mn = fmaxf(m_run[r], m0 * 0.125f);
            const float al = expf(m_run[r] - mn);
            m_run[r] = mn;
            float rs = 0.f;
#pragma unroll
            for (int nf = 0; nf < 4; nf++) {
                float pv = expf(fmaf(s4[nf][r], 0.125f, -mn));
                p[nf][r] = pv;
                rs += pv;
            }
            l_run[r] = l_run[r] * al + rs;   // per-lane partial (4 of 64 cols)
#pragma unroll
            for (int df = 0; df < 4; df++) O[df][r] *= al;
        }
        // P -> LDS fp16 [q][k] (wave-private rows; conflict-free: lq groups 8 banks apart)
#pragma unroll
        for (int nf = 0; nf < 4; nf++)
#pragma unroll
            for (int r = 0; r < 4; r++)
                pT[(wv * 16 + lq * 4 + r) * 68 + nf * 16 + lm] = (_Float16)p[nf][r];
        __syncthreads();             // pT visible
        // PV: M=16 q (this wave), N=64 d, K=64 k
#pragma unroll
        for (int ks = 0; ks < 2; ks++) {
            half8 ap = *(half8*)&pT[(wv * 16 + lm) * 68 + ks * 32 + lq * 8];
            half8 bf[4];
#pragma unroll
            for (int df = 0; df < 4; df++)
                bf[df] = *(half8*)&Vt[(df * 16 + lm) * 68 + ks * 32 + lq * 8];
#pragma unroll
            for (int df = 0; df < 4; df++)
                O[df] = __builtin_amdgcn_mfma_f32_16x16x32_f16(ap, bf[df], O[df], 0, 0, 0);
        }
    }
    // final l reduce over lm, normalize, store
#pragma unroll
    for (int r = 0; r < 4; r++) {
        l_run[r] += __shfl_xor(l_run[r], 1, 64);
        l_run[r] += __shfl_xor(l_run[r], 2, 64);
        l_run[r] += __shfl_xor(l_run[r], 4, 64);
        l_run[r] += __shfl_xor(l_run[r], 8, 64);
        l_run[r] = 1.f / fmaxf(l_run[r], 1e-30f);
    }
    float* __restrict__ attL = ws + O_ATTL;   // [2][2][8192][64]
#pragma unroll
    for (int df = 0; df < 4; df++) {
#pragma unroll
        for (int r = 0; r < 4; r++) {
            const int q = q0 + wv * 16 + lq * 4 + r;
            attL[((size_t)(b * 2 + lh) * 8192 + q) * 64 + df * 16 + lm] = O[df][r] * l_run[r];
        }
    }
}

// ---------------- output projection + bias ----------------
__launch_bounds__(256)
__global__ void k_out(const float* __restrict__ Wo,
                      const float* __restrict__ bo,
                      const float* __restrict__ ws,
                      float* __restrict__ out) {
    __shared__ float As[16][128];
    __shared__ float Bs[16][128];
    const float* __restrict__ attG = ws + O_K;      // [16384][384]
    const float* __restrict__ attL = ws + O_ATTL;   // [4][8192][64]
    const int r0 = blockIdx.x * 128, c0 = blockIdx.y * 128;
    const int tid = threadIdx.x, tx = tid & 15, ty = tid >> 4;
    const int am = tid >> 1, ako = (tid & 1) * 8;
    const int bk = tid >> 4, bjo = (tid & 15) * 8;
    float acc[8][8];
#pragma unroll
    for (int i = 0; i < 8; i++)
#pragma unroll
        for (int j = 0; j < 8; j++) acc[i][j] = 0.f;

    for (int k0 = 0; k0 < 512; k0 += 16) {
        const int row = r0 + am;
        float4 a0, a1;
        if (k0 < 384) {
            a0 = *(const float4*)(attG + row * 384 + k0 + ako);
            a1 = *(const float4*)(attG + row * 384 + k0 + ako + 4);
        } else {
            const int bb = row >> 13, nn = row & 8191;
            const int kk0 = k0 + ako - 384;
            const int lhh = kk0 >> 6, dd = kk0 & 63;
            const float* src = attL + ((bb * 2 + lhh) * 8192 + nn) * 64 + dd;
            a0 = *(const float4*)(src);
            a1 = *(const float4*)(src + 4);
        }
        float4 b0 = *(const float4*)(Wo + (k0 + bk) * 512 + c0 + bjo);
        float4 b1 = *(const float4*)(Wo + (k0 + bk) * 512 + c0 + bjo + 4);
        As[ako + 0][am] = a0.x; As[ako + 1][am] = a0.y;
        As[ako + 2][am] = a0.z; As[ako + 3][am] = a0.w;
        As[ako + 4][am] = a1.x; As[ako + 5][am] = a1.y;
        As[ako + 6][am] = a1.z; As[ako + 7][am] = a1.w;
        *(float4*)&Bs[bk][bjo]     = b0;
        *(float4*)&Bs[bk][bjo + 4] = b1;
        __syncthreads();
#pragma unroll
        for (int kk = 0; kk < 16; kk++) {
            float4 a04 = *(float4*)&As[kk][ty * 8];
            float4 a14 = *(float4*)&As[kk][ty * 8 + 4];
            float4 b04 = *(float4*)&Bs[kk][tx * 4];
            float4 b14 = *(float4*)&Bs[kk][64 + tx * 4];
            float a[8] = {a04.x, a04.y, a04.z, a04.w, a14.x, a14.y, a14.z, a14.w};
            float b[8] = {b04.x, b04.y, b04.z, b04.w, b14.x, b14.y, b14.z, b14.w};
#pragma unroll
            for (int i = 0; i < 8; i++)
#pragma unroll
                for (int j = 0; j < 8; j++) acc[i][j] = fmaf(a[i], b[j], acc[i][j]);
        }
        __syncthreads();
    }
    const int col0 = c0 + tx * 4, col1 = c0 + 64 + tx * 4;
    float4 bo0 = *(const float4*)(bo + col0);
    float4 bo1 = *(const float4*)(bo + col1);
#pragma unroll
    for (int i = 0; i < 8; i++) {
        int r = r0 + ty * 8 + i;
        *(float4*)&out[r * 512 + col0] =
            make_float4(acc[i][0] + bo0.x, acc[i][1] + bo0.y, acc[i][2] + bo0.z, acc[i][3] + bo0.w);
        *(float4*)&out[r * 512 + col1] =
            make_float4(acc[i][4] + bo1.x, acc[i][5] + bo1.y, acc[i][6] + bo1.z, acc[i][7] + bo1.w);
    }
}

extern "C" void kernel_launch(void* const* d_in, const int* in_sizes, int n_in,
                              void* d_out, int out_size, void* d_ws, size_t ws_size,
                              hipStream_t stream) {
    const float* x    = (const float*)d_in[0];
    const float* Wq   = (const float*)d_in[1];
    const float* Wk   = (const float*)d_in[2];
    const float* Wv   = (const float*)d_in[3];
    const float* Wo   = (const float*)d_in[4];
    const float* bo   = (const float*)d_in[5];
    const float* proj = (const float*)d_in[6];
    float* ws = (float*)d_ws;
    float* out = (float*)d_out;

    hipMemsetAsync(d_ws, 0, (size_t)O_ZEND * 4, stream);                 // kmax/ksum/ctx
    hipLaunchKernelGGL(k_rope,   dim3(1024), dim3(256), 0, stream, ws);
    hipLaunchKernelGGL(k_half_w, dim3(8, 8, 3), dim3(256), 0, stream, Wq, Wk, Wv, ws);
    hipLaunchKernelGGL(k_qkv,    dim3(128, 4, 3), dim3(256), 0, stream, x, ws);
    hipLaunchKernelGGL(k_kmax,   dim3(12, 128), dim3(256), 0, stream, proj, ws);
    hipLaunchKernelGGL(k_kctx,   dim3(12, 32, 2), dim3(256), 0, stream, proj, ws);
    hipLaunchKernelGGL(k_local,  dim3(4, 128), dim3(256), 0, stream, ws);   // before k_qout!
    hipLaunchKernelGGL(k_qout,   dim3(12, 128), dim3(256), 0, stream, proj, ws);
    hipLaunchKernelGGL(k_out,    dim3(128, 4), dim3(256), 0, stream, Wo, bo, ws, out);
}

// Round 2
// 434.379 us; speedup vs baseline: 1.5347x; 1.3008x over previous
//
#include <hip/hip_runtime.h>

// ---------------- constants ----------------
#define NTOK 8192
#define NORMC 0.35355339059327373f   // 64^-0.25
#define RATIO 0.0625f                // 256^-0.5
#define KEPS  1e-4f

// ws offsets in 4-byte elements  (total 27987008 ele = 106.8 MB)
#define O_KMAX 0                      // 12 x u32 (encoded max)
#define O_KSUM 64                     // 12*256 f32
#define O_CTX  3136                   // 12*256*64 f32
#define O_ZEND 199744                 // zeroed region end
#define O_COS  199744                 // 8192*32
#define O_SIN  461888                 // 8192*32
#define O_Q    724032                 // 2*8*8192*64
#define O_K    9112640                // K; later reused as attG [16384][384]
#define O_V    17501248
#define O_ATTL 25889856               // 2*2*8192*64 (local heads out)
// O_WH: fp16 W^T [3][512][512] lives in the ATTL region (dead until k_local,
// consumed only by k_qkv which runs first) -> zero footprint growth
#define O_WH   25889856
// end: 27987008

typedef _Float16 half8 __attribute__((ext_vector_type(8)));
typedef _Float16 half4h __attribute__((ext_vector_type(4)));
typedef float floatx4 __attribute__((ext_vector_type(4)));

__device__ __forceinline__ unsigned encf(float f) {
    unsigned u = __float_as_uint(f);
    return (u & 0x80000000u) ? ~u : (u | 0x80000000u);
}
__device__ __forceinline__ float decf(unsigned u) {
    return (u & 0x80000000u) ? __uint_as_float(u & 0x7fffffffu) : __uint_as_float(~u);
}

// ---------------- RoPE tables (double precision angles) ----------------
__global__ void k_rope(float* __restrict__ ws) {
    int idx = blockIdx.x * 256 + threadIdx.x;      // 8192*32
    int t = idx >> 5, i = idx & 31;
    double invf = pow(10000.0, -(double)(2 * i) / 64.0);
    double ang = (double)t * invf;
    ws[O_COS + idx] = (float)cos(ang);
    ws[O_SIN + idx] = (float)sin(ang);
}

// ---------------- W -> fp16, transposed to [n][k] ----------------
__launch_bounds__(256)
__global__ void k_half_w(const float* __restrict__ Wq,
                         const float* __restrict__ Wk,
                         const float* __restrict__ Wv,
                         float* __restrict__ ws) {
    __shared__ float T[64][65];
    const int z = blockIdx.z;
    const float* __restrict__ W = (z == 0) ? Wq : ((z == 1) ? Wk : Wv);
    _Float16* __restrict__ Wt = (_Float16*)(ws + O_WH) + (size_t)z * 262144;
    const int k0 = blockIdx.x * 64, n0 = blockIdx.y * 64;
    const int lx = threadIdx.x & 63, ly = threadIdx.x >> 6;   // ly in 0..3
#pragma unroll
    for (int i = 0; i < 16; i++) {
        const int kk = ly * 16 + i;
        T[lx][kk] = W[(k0 + kk) * 512 + n0 + lx];    // T[n-n0][k-k0]
    }
    __syncthreads();
#pragma unroll
    for (int i = 0; i < 16; i++) {
        const int nn = ly * 16 + i;
        Wt[(n0 + nn) * 512 + k0 + lx] = (_Float16)T[nn][lx];
    }
}

// ---------------- QKV projection via fp16 MFMA ----------------
__launch_bounds__(256)
__global__ void k_qkv(const float* __restrict__ x, float* __restrict__ ws) {
    __shared__ _Float16 Ah[128 * 72];
    __shared__ _Float16 Bh[128 * 72];
    const int z = blockIdx.z;
    const _Float16* __restrict__ Wt = (const _Float16*)(ws + O_WH) + (size_t)z * 262144;
    float* __restrict__ out = ws + ((z == 0) ? O_Q : ((z == 1) ? O_K : O_V));
    const int r0 = blockIdx.x * 128, c0 = blockIdx.y * 128;
    const int tid = threadIdx.x;
    const int wv = tid >> 6, lane = tid & 63, lm = lane & 15, lq = lane >> 4;
    const int srow = tid >> 1, skoff = (tid & 1) * 32;
    floatx4 acc[2][8];
#pragma unroll
    for (int m = 0; m < 2; m++)
#pragma unroll
        for (int n = 0; n < 8; n++) acc[m][n] = (floatx4){0.f, 0.f, 0.f, 0.f};

    for (int c = 0; c < 8; c++) {
        const int k0 = c * 64;
        {   // stage A: x fp32 -> fp16 (row-major, k contiguous)
            const float* ap = x + (size_t)(r0 + srow) * 512 + k0 + skoff;
#pragma unroll
            for (int q = 0; q < 4; q++) {
                float4 v0 = *(const float4*)(ap + 8 * q);
                float4 v1 = *(const float4*)(ap + 8 * q + 4);
                half8 h = {(_Float16)v0.x, (_Float16)v0.y, (_Float16)v0.z, (_Float16)v0.w,
                           (_Float16)v1.x, (_Float16)v1.y, (_Float16)v1.z, (_Float16)v1.w};
                *(half8*)&Ah[srow * 72 + skoff + 8 * q] = h;
            }
        }
        {   // stage B: fp16 W^T direct copy
            const _Float16* bp = Wt + (size_t)(c0 + srow) * 512 + k0 + skoff;
#pragma unroll
            for (int q = 0; q < 4; q++)
                *(uint4*)&Bh[srow * 72 + skoff + 8 * q] = *(const uint4*)(bp + 8 * q);
        }
        __syncthreads();
#pragma unroll
        for (int ks = 0; ks < 2; ks++) {
            half8 af[2], bf[8];
            af[0] = *(half8*)&Ah[(wv * 32 + lm) * 72 + ks * 32 + lq * 8];
            af[1] = *(half8*)&Ah[(wv * 32 + 16 + lm) * 72 + ks * 32 + lq * 8];
#pragma unroll
            for (int n = 0; n < 8; n++)
                bf[n] = *(half8*)&Bh[(n * 16 + lm) * 72 + ks * 32 + lq * 8];
#pragma unroll
            for (int m = 0; m < 2; m++)
#pragma unroll
                for (int n = 0; n < 8; n++)
                    acc[m][n] = __builtin_amdgcn_mfma_f32_16x16x32_f16(af[m], bf[n], acc[m][n], 0, 0, 0);
        }
        __syncthreads();
    }
    const int bi = r0 >> 13;
#pragma unroll
    for (int n = 0; n < 8; n++) {
        const int col = c0 + n * 16 + lm;
        const int h = col >> 6, d = col & 63;
#pragma unroll
        for (int m = 0; m < 2; m++) {
            const int rbase = r0 + wv * 32 + m * 16 + lq * 4;
#pragma unroll
            for (int j = 0; j < 4; j++) {
                const int ng = (rbase + j) & 8191;
                out[((size_t)(bi * 8 + h) * 8192 + ng) * 64 + d] = acc[m][n][j];
            }
        }
    }
}

// ---------------- key-side global max of dd = norm*(K.projT) (fp16 MFMA) ----------------
// Block = 64 n-rows x all 256 j, K=64. Wave wv owns j-slice wv*64. 32 MFMAs/wave,
// then full-wave shfl max + one LDS atomic. kmax shift nearly cancels between
// ctx and ksum, so fp16 dd error here is harmless (only KEPS sees ~e^1e-3).
__launch_bounds__(256)
__global__ void k_kmax(const float* __restrict__ proj, float* __restrict__ ws) {
    __shared__ _Float16 Kh[64 * 68];      // K tile [n][d] fp16
    __shared__ _Float16 Ph[256 * 68];     // proj [j][d] fp16
    __shared__ unsigned bmax;
    const int bh = blockIdx.x, b = bh / 6, h = bh % 6;
    const float* __restrict__ Kp = ws + O_K + (size_t)(b * 8 + h) * 8192 * 64;
    const int n0 = blockIdx.y * 64;
    const int tid = threadIdx.x;
    const int wv = tid >> 6, lane = tid & 63, lm = lane & 15, lq = lane >> 4;
    if (tid == 0) bmax = 0u;
    {   // stage Kh [n][d] fp16
        const int r = tid >> 2, dq = (tid & 3) * 16;
        const float* kpp = Kp + (size_t)(n0 + r) * 64 + dq;
        _Float16 t[16];
#pragma unroll
        for (int q = 0; q < 4; q++) {
            float4 v = *(const float4*)(kpp + 4 * q);
            t[4*q+0] = (_Float16)v.x; t[4*q+1] = (_Float16)v.y;
            t[4*q+2] = (_Float16)v.z; t[4*q+3] = (_Float16)v.w;
        }
        *(half8*)&Kh[r * 68 + dq]     = *(half8*)&t[0];
        *(half8*)&Kh[r * 68 + dq + 8] = *(half8*)&t[8];
    }
    {   // stage Ph [j][d] fp16 (256 rows, 2 passes, 2 threads/row)
#pragma unroll
        for (int ph = 0; ph < 2; ph++) {
            const int r = ph * 128 + (tid >> 1), doff = (tid & 1) * 32;
            const float* pp = proj + r * 64 + doff;
#pragma unroll
            for (int q = 0; q < 4; q++) {
                float4 v0 = *(const float4*)(pp + 8 * q);
                float4 v1 = *(const float4*)(pp + 8 * q + 4);
                half8 hv = {(_Float16)v0.x, (_Float16)v0.y, (_Float16)v0.z, (_Float16)v0.w,
                            (_Float16)v1.x, (_Float16)v1.y, (_Float16)v1.z, (_Float16)v1.w};
                *(half8*)&Ph[r * 68 + doff + 8 * q] = hv;
            }
        }
    }
    __syncthreads();
    // dd[n][j]: M=64 n, N=64 j (this wave's slice), K=64
    floatx4 s4[4][4];
#pragma unroll
    for (int nt = 0; nt < 4; nt++)
#pragma unroll
        for (int jt = 0; jt < 4; jt++) s4[nt][jt] = (floatx4){0.f, 0.f, 0.f, 0.f};
#pragma unroll
    for (int ks = 0; ks < 2; ks++) {
        half8 af[4], bf[4];
#pragma unroll
        for (int nt = 0; nt < 4; nt++)
            af[nt] = *(half8*)&Kh[(nt * 16 + lm) * 68 + ks * 32 + lq * 8];
#pragma unroll
        for (int jt = 0; jt < 4; jt++)
            bf[jt] = *(half8*)&Ph[(wv * 64 + jt * 16 + lm) * 68 + ks * 32 + lq * 8];
#pragma unroll
        for (int nt = 0; nt < 4; nt++)
#pragma unroll
            for (int jt = 0; jt < 4; jt++)
                s4[nt][jt] = __builtin_amdgcn_mfma_f32_16x16x32_f16(af[nt], bf[jt], s4[nt][jt], 0, 0, 0);
    }
    float m = -1e30f;
#pragma unroll
    for (int nt = 0; nt < 4; nt++)
#pragma unroll
        for (int jt = 0; jt < 4; jt++)
#pragma unroll
            for (int r = 0; r < 4; r++) m = fmaxf(m, s4[nt][jt][r]);
    m = fmaxf(m, __shfl_xor(m, 1, 64));
    m = fmaxf(m, __shfl_xor(m, 2, 64));
    m = fmaxf(m, __shfl_xor(m, 4, 64));
    m = fmaxf(m, __shfl_xor(m, 8, 64));
    m = fmaxf(m, __shfl_xor(m, 16, 64));
    m = fmaxf(m, __shfl_xor(m, 32, 64));
    if (lane == 0) atomicMax(&bmax, encf(m * NORMC));
    __syncthreads();
    if (tid == 0) atomicMax((unsigned*)ws + O_KMAX + bh, bmax);
}

// ---------------- key-side: kp, k_sum, ctx = kp^T @ V  (fp16 MFMA) ----------------
// Grid (12 bh, 32 n-chunks of 256, 2 j-halves of 128). 4 waves; wave w owns
// j-range w*32 within the half. Per 64-row n-sub: dd=K.projT (MFMA), exp in
// C-layout regs, kp->LDS [j][n] fp16, ctx += kp^T.V (MFMA, V staged [d][n]).
// ctx persists in 32 regs/lane, flushed once. LDS ~53 KB -> 3 blocks/CU.
__launch_bounds__(256)
__global__ void k_kctx(const float* __restrict__ proj, float* __restrict__ ws) {
    __shared__ _Float16 Kh[64 * 68];     // K sub [n][d]
    __shared__ _Float16 Vt[64 * 68];     // V sub transposed [d][n]
    __shared__ _Float16 Ph[128 * 68];    // proj half [j][d]
    __shared__ _Float16 kpt[128 * 68];   // kp transposed [j][n]
    __shared__ float diag4[64][4];       // per-row |K|^2 partials (race-free)
    __shared__ float ksum_s[128];
    const int bh = blockIdx.x, b = bh / 6, h = bh % 6;
    const int n0 = blockIdx.y * 256;
    const int jh = blockIdx.z;
    const float* __restrict__ Kp = ws + O_K + (size_t)(b * 8 + h) * 8192 * 64;
    const float* __restrict__ Vp = ws + O_V + (size_t)(b * 8 + h) * 8192 * 64;
    const float kmax = decf(((const unsigned*)ws)[O_KMAX + bh]);
    const int tid = threadIdx.x;
    const int wv = tid >> 6, lane = tid & 63, lm = lane & 15, lq = lane >> 4;
    if (tid < 128) ksum_s[tid] = 0.f;

    {   // stage Ph once: proj rows jh*128.., [jrel][d] stride 68
        const int r = tid >> 1, doff = (tid & 1) * 32;
        const float* pp = proj + (jh * 128 + r) * 64 + doff;
#pragma unroll
        for (int q = 0; q < 4; q++) {
            float4 v0 = *(const float4*)(pp + 8 * q);
            float4 v1 = *(const float4*)(pp + 8 * q + 4);
            half8 hv = {(_Float16)v0.x, (_Float16)v0.y, (_Float16)v0.z, (_Float16)v0.w,
                        (_Float16)v1.x, (_Float16)v1.y, (_Float16)v1.z, (_Float16)v1.w};
            *(half8*)&Ph[r * 68 + doff + 8 * q] = hv;
        }
    }
    floatx4 acc[2][4];   // ctx tiles [jt][dt]
#pragma unroll
    for (int jt = 0; jt < 2; jt++)
#pragma unroll
        for (int dt = 0; dt < 4; dt++) acc[jt][dt] = (floatx4){0.f, 0.f, 0.f, 0.f};

    for (int nc = 0; nc < 4; nc++) {
        const int ns = n0 + nc * 64;
        {   // stage Kh [n][d] + diag partials
            const int r = tid >> 2, dq = (tid & 3) * 16;
            const float* kpp = Kp + (size_t)(ns + r) * 64 + dq;
            float part = 0.f;
            _Float16 t[16];
#pragma unroll
            for (int q = 0; q < 4; q++) {
                float4 v = *(const float4*)(kpp + 4 * q);
                part = fmaf(v.x, v.x, fmaf(v.y, v.y, fmaf(v.z, v.z, fmaf(v.w, v.w, part))));
                t[4*q+0] = (_Float16)v.x; t[4*q+1] = (_Float16)v.y;
                t[4*q+2] = (_Float16)v.z; t[4*q+3] = (_Float16)v.w;
            }
            *(half8*)&Kh[r * 68 + dq]     = *(half8*)&t[0];
            *(half8*)&Kh[r * 68 + dq + 8] = *(half8*)&t[8];
            diag4[r][tid & 3] = part;
        }
        {   // stage Vt transposed [d][n]: thread d = tid&63, n-block of 16
            const int d = tid & 63, nb = (tid >> 6) * 16;
            _Float16 t[16];
#pragma unroll
            for (int i = 0; i < 16; i++)
                t[i] = (_Float16)Vp[(size_t)(ns + nb + i) * 64 + d];
            *(half8*)&Vt[d * 68 + nb]     = *(half8*)&t[0];
            *(half8*)&Vt[d * 68 + nb + 8] = *(half8*)&t[8];
        }
        __syncthreads();                              // A: Kh/Vt/diag4 ready (kpt free)
        // dd[n][j]: M=64 n, N=32 j (this wave), K=64
        floatx4 s4[4][2];
#pragma unroll
        for (int nt = 0; nt < 4; nt++)
#pragma unroll
            for (int jt = 0; jt < 2; jt++) s4[nt][jt] = (floatx4){0.f, 0.f, 0.f, 0.f};
#pragma unroll
        for (int ks = 0; ks < 2; ks++) {
            half8 af[4], bf[2];
#pragma unroll
            for (int nt = 0; nt < 4; nt++)
                af[nt] = *(half8*)&Kh[(nt * 16 + lm) * 68 + ks * 32 + lq * 8];
#pragma unroll
            for (int jt = 0; jt < 2; jt++)
                bf[jt] = *(half8*)&Ph[(wv * 32 + jt * 16 + lm) * 68 + ks * 32 + lq * 8];
#pragma unroll
            for (int nt = 0; nt < 4; nt++)
#pragma unroll
                for (int jt = 0; jt < 2; jt++)
                    s4[nt][jt] = __builtin_amdgcn_mfma_f32_16x16x32_f16(af[nt], bf[jt], s4[nt][jt], 0, 0, 0);
        }
        // exp in C-layout (col=j=lm, row=n=lq*4+reg), kp -> kpt [j][n] fp16
        float jsum[2] = {0.f, 0.f};
#pragma unroll
        for (int nt = 0; nt < 4; nt++) {
            float dg[4];
#pragma unroll
            for (int r = 0; r < 4; r++) {
                float4 d4 = *(float4*)diag4[nt * 16 + lq * 4 + r];   // broadcast read
                dg[r] = (d4.x + d4.y + d4.z + d4.w) * 0.0625f;
            }
#pragma unroll
            for (int jt = 0; jt < 2; jt++) {
                half4h kv;
#pragma unroll
                for (int r = 0; r < 4; r++) {
                    float v = RATIO * (expf(fminf(NORMC * s4[nt][jt][r] - dg[r] - kmax, 0.f)) + KEPS);
                    jsum[jt] += v;
                    kv[r] = (_Float16)v;
                }
                *(half4h*)&kpt[(wv * 32 + jt * 16 + lm) * 68 + nt * 16 + lq * 4] = kv;
            }
        }
#pragma unroll
        for (int jt = 0; jt < 2; jt++)
            atomicAdd(&ksum_s[wv * 32 + jt * 16 + lm], jsum[jt]);
        __syncthreads();                              // B: kpt ready
        // ctx[j][d] += kp^T @ V: M=32 j (this wave), N=64 d, K=64 n
#pragma unroll
        for (int ks = 0; ks < 2; ks++) {
            half8 af[2], bf[4];
#pragma unroll
            for (int jt = 0; jt < 2; jt++)
                af[jt] = *(half8*)&kpt[(wv * 32 + jt * 16 + lm) * 68 + ks * 32 + lq * 8];
#pragma unroll
            for (int dt = 0; dt < 4; dt++)
                bf[dt] = *(half8*)&Vt[(dt * 16 + lm) * 68 + ks * 32 + lq * 8];
#pragma unroll
            for (int jt = 0; jt < 2; jt++)
#pragma unroll
                for (int dt = 0; dt < 4; dt++)
                    acc[jt][dt] = __builtin_amdgcn_mfma_f32_16x16x32_f16(af[jt], bf[dt], acc[jt][dt], 0, 0, 0);
        }
        __syncthreads();                              // D: before next staging
    }
    // flush: C-layout col=d=lm, row=j=lq*4+reg
    float* __restrict__ ctxp = ws + O_CTX + bh * 16384;
#pragma unroll
    for (int jt = 0; jt < 2; jt++) {
#pragma unroll
        for (int dt = 0; dt < 4; dt++) {
            const int d = dt * 16 + lm;
#pragma unroll
            for (int r = 0; r < 4; r++) {
                const int j = jh * 128 + wv * 32 + jt * 16 + lq * 4 + r;
                atomicAdd(&ctxp[j * 64 + d], acc[jt][dt][r]);
            }
        }
    }
    if (tid < 128) atomicAdd(ws + O_KSUM + bh * 256 + jh * 128 + tid, ksum_s[tid]);
}

// ---------------- query-side: dd, rowmax, qp, attG = qp.ctx / (qp.ksum) (fp16 MFMA) ----
// Block = 64 n-rows. Wave wv owns j-slice wv*64 for dd/qp, d-slice wv*16 for PV.
// dd (M=64,N=64,K=64 per wave) kept in s4[4][4] regs; rowmax in-lane + shfl(lm) +
// LDS atomicMax; qp computed in-reg -> fp16 LDS [n][260] (reuses proj region);
// denom folded into freed s4 + shfl reduce; PV = qp.ctxT (M=64,N=16,K=256).
// LDS ~80 KB -> 2 blocks/CU.
__launch_bounds__(256)
__global__ void k_qout(const float* __restrict__ proj, float* __restrict__ ws) {
    __shared__ _Float16 Qh[64 * 68];      // Q tile [n][d] fp16
    __shared__ _Float16 PhQp[256 * 68];   // proj [j][d] fp16; reused as qp [n][j] stride 260
    __shared__ _Float16 Ct[64 * 260];     // ctx^T [d][j] fp16
    __shared__ float ksum_s[256];
    __shared__ float diag4[64][4];
    __shared__ float diag_s[64];
    __shared__ unsigned rmax_s[64];
    __shared__ float denom_s[64];
    const int bh = blockIdx.x, b = bh / 6, h = bh % 6;
    const int n0 = blockIdx.y * 64;
    const float* __restrict__ Qp = ws + O_Q + (size_t)(b * 8 + h) * 8192 * 64;
    const float* __restrict__ ctxp = ws + O_CTX + bh * 16384;
    float* __restrict__ attG = ws + O_K;     // [16384][384]
    const int tid = threadIdx.x;
    const int wv = tid >> 6, lane = tid & 63, lm = lane & 15, lq = lane >> 4;
    if (tid < 64) { rmax_s[tid] = 0u; denom_s[tid] = 0.f; }
    ksum_s[tid] = ws[O_KSUM + bh * 256 + tid];

    {   // stage Qh [n][d] fp16 + |Q|^2 partials
        const int r = tid >> 2, dq = (tid & 3) * 16;
        const float* qpp = Qp + (size_t)(n0 + r) * 64 + dq;
        float part = 0.f;
        _Float16 t[16];
#pragma unroll
        for (int q = 0; q < 4; q++) {
            float4 v = *(const float4*)(qpp + 4 * q);
            part = fmaf(v.x, v.x, fmaf(v.y, v.y, fmaf(v.z, v.z, fmaf(v.w, v.w, part))));
            t[4*q+0] = (_Float16)v.x; t[4*q+1] = (_Float16)v.y;
            t[4*q+2] = (_Float16)v.z; t[4*q+3] = (_Float16)v.w;
        }
        *(half8*)&Qh[r * 68 + dq]     = *(half8*)&t[0];
        *(half8*)&Qh[r * 68 + dq + 8] = *(half8*)&t[8];
        diag4[r][tid & 3] = part;
    }
    {   // stage Ph [j][d] fp16 (256 rows, 2 passes, 2 threads/row)
#pragma unroll
        for (int ph = 0; ph < 2; ph++) {
            const int r = ph * 128 + (tid >> 1), doff = (tid & 1) * 32;
            const float* pp = proj + r * 64 + doff;
#pragma unroll
            for (int q = 0; q < 4; q++) {
                float4 v0 = *(const float4*)(pp + 8 * q);
                float4 v1 = *(const float4*)(pp + 8 * q + 4);
                half8 hv = {(_Float16)v0.x, (_Float16)v0.y, (_Float16)v0.z, (_Float16)v0.w,
                            (_Float16)v1.x, (_Float16)v1.y, (_Float16)v1.z, (_Float16)v1.w};
                *(half8*)&PhQp[r * 68 + doff + 8 * q] = hv;
            }
        }
    }
    {   // stage Ct [d][j] fp16 (transpose of ctx [j][d]; lane sweeps d -> coalesced)
        const int d = tid & 63;
#pragma unroll
        for (int jb = 0; jb < 4; jb++) {
            const int js = jb * 64 + (tid >> 6) * 16;
            _Float16 t[16];
#pragma unroll
            for (int i = 0; i < 16; i++)
                t[i] = (_Float16)ctxp[(js + i) * 64 + d];
            *(half8*)&Ct[d * 260 + js]     = *(half8*)&t[0];
            *(half8*)&Ct[d * 260 + js + 8] = *(half8*)&t[8];
        }
    }
    __syncthreads();
    if (tid < 64) {
        float4 d4 = *(float4*)diag4[tid];
        diag_s[tid] = (d4.x + d4.y + d4.z + d4.w) * 0.0625f;
    }
    // dd = Q . proj^T : M=64 n, N=64 j (this wave's slice), K=64
    floatx4 s4[4][4];
#pragma unroll
    for (int nt = 0; nt < 4; nt++)
#pragma unroll
        for (int jt = 0; jt < 4; jt++) s4[nt][jt] = (floatx4){0.f, 0.f, 0.f, 0.f};
#pragma unroll
    for (int ks = 0; ks < 2; ks++) {
        half8 af[4], bf[4];
#pragma unroll
        for (int nt = 0; nt < 4; nt++)
            af[nt] = *(half8*)&Qh[(nt * 16 + lm) * 68 + ks * 32 + lq * 8];
#pragma unroll
        for (int jt = 0; jt < 4; jt++)
            bf[jt] = *(half8*)&PhQp[(wv * 64 + jt * 16 + lm) * 68 + ks * 32 + lq * 8];
#pragma unroll
        for (int nt = 0; nt < 4; nt++)
#pragma unroll
            for (int jt = 0; jt < 4; jt++)
                s4[nt][jt] = __builtin_amdgcn_mfma_f32_16x16x32_f16(af[nt], bf[jt], s4[nt][jt], 0, 0, 0);
    }
    // row maxima over this wave's 64 j -> cross-wave via LDS atomicMax
#pragma unroll
    for (int nt = 0; nt < 4; nt++) {
#pragma unroll
        for (int rr = 0; rr < 4; rr++) {
            float m0 = fmaxf(fmaxf(s4[nt][0][rr], s4[nt][1][rr]),
                             fmaxf(s4[nt][2][rr], s4[nt][3][rr]));
            m0 = fmaxf(m0, __shfl_xor(m0, 1, 64));
            m0 = fmaxf(m0, __shfl_xor(m0, 2, 64));
            m0 = fmaxf(m0, __shfl_xor(m0, 4, 64));
            m0 = fmaxf(m0, __shfl_xor(m0, 8, 64));
            if (lm == 0) atomicMax(&rmax_s[nt * 16 + lq * 4 + rr], encf(m0 * NORMC));
        }
    }
    __syncthreads();     // rmax_s/diag_s ready; all Ph reads done (qp may overwrite)
    // qp = RATIO*(exp(NORMC*dd - diag - rmax)+KEPS) -> fp16 LDS; denom into s4
#pragma unroll
    for (int nt = 0; nt < 4; nt++) {
#pragma unroll
        for (int rr = 0; rr < 4; rr++) {
            const int row = nt * 16 + lq * 4 + rr;
            const float rmx = decf(rmax_s[row]);
            const float dgv = diag_s[row];
#pragma unroll
            for (int jt = 0; jt < 4; jt++) {
                const int j = wv * 64 + jt * 16 + lm;
                float v = RATIO * (expf(fminf(NORMC * s4[nt][jt][rr] - dgv - rmx, 0.f)) + KEPS);
                PhQp[row * 260 + j] = (_Float16)v;
                s4[nt][jt][rr] = v * ksum_s[j];
            }
            float ds = s4[nt][0][rr] + s4[nt][1][rr] + s4[nt][2][rr] + s4[nt][3][rr];
            ds += __shfl_xor(ds, 1, 64);
            ds += __shfl_xor(ds, 2, 64);
            ds += __shfl_xor(ds, 4, 64);
            ds += __shfl_xor(ds, 8, 64);
            if (lm == 0) atomicAdd(&denom_s[row], ds);
        }
    }
    __syncthreads();     // qp + denom ready
    // attG = qp . ctx : M=64 n, N=16 d (this wave's slice), K=256 j
    floatx4 acc2[4];
#pragma unroll
    for (int nt = 0; nt < 4; nt++) acc2[nt] = (floatx4){0.f, 0.f, 0.f, 0.f};
#pragma unroll
    for (int ks = 0; ks < 8; ks++) {
        half8 bfv = *(half8*)&Ct[(wv * 16 + lm) * 260 + ks * 32 + lq * 8];
#pragma unroll
        for (int nt = 0; nt < 4; nt++) {
            half8 af = *(half8*)&PhQp[(nt * 16 + lm) * 260 + ks * 32 + lq * 8];
            acc2[nt] = __builtin_amdgcn_mfma_f32_16x16x32_f16(af, bfv, acc2[nt], 0, 0, 0);
        }
    }
#pragma unroll
    for (int nt = 0; nt < 4; nt++) {
#pragma unroll
        for (int rr = 0; rr < 4; rr++) {
            const int row = nt * 16 + lq * 4 + rr;
            const float inv = 1.0f / fmaxf(denom_s[row], 1e-30f);
            attG[((size_t)(b * 8192 + n0 + row)) * 384 + h * 64 + wv * 16 + lm] =
                acc2[nt][rr] * inv;
        }
    }
}

// ---------------- local windowed attention w/ RoPE, heads 6..7 (fp16 MFMA) ----------------
// 4 waves; wave wv owns q-rows wv*16..wv*16+15 of the 64-q tile. Per 64-key
// chunk: stage RoPE'd K [k][d] fp16 + V transposed [d][k] fp16; QK^T via
// 16x16x32 MFMA (C layout: col=k=lm, row=q=lq*4+r); online softmax fully in
// registers (row-max via 4-step shfl_xor over lm; l kept as per-lane partial,
// reduced once at the end); P -> fp16 LDS [q][k]; PV via MFMA into fp32 acc.
__launch_bounds__(256)
__global__ void k_local(float* __restrict__ ws) {
    __shared__ _Float16 Qh[64 * 68];     // RoPE'd Q [q][d]
    __shared__ _Float16 Kh[64 * 68];     // RoPE'd K chunk [k][d]
    __shared__ _Float16 Vt[64 * 68];     // V chunk transposed [d][k]
    __shared__ _Float16 pT[64 * 68];     // P [q][k] fp16
    const int bhp = blockIdx.x, b = bhp >> 1, lh = bhp & 1, h = 6 + lh;
    const int tile = blockIdx.y;                 // 0..127 (64-query tiles)
    const int w = tile >> 2;                     // window index
    const int q0 = tile * 64;
    const float* __restrict__ Qb = ws + O_Q + (size_t)(b * 8 + h) * 8192 * 64;
    const float* __restrict__ Kb = ws + O_K + (size_t)(b * 8 + h) * 8192 * 64;
    const float* __restrict__ Vb = ws + O_V + (size_t)(b * 8 + h) * 8192 * 64;
    const float* __restrict__ cosT = ws + O_COS;
    const float* __restrict__ sinT = ws + O_SIN;
    const int tid = threadIdx.x;
    const int wv = tid >> 6, lane = tid & 63, lm = lane & 15, lq = lane >> 4;
    // staging mapping: 4 threads per row, 16 dims each
    const int row = tid >> 2, dq = (tid & 3) * 16;
    const int e = dq & 31;
    const int comp = (dq < 32) ? dq + 32 : dq - 32;
    const float sgn = (dq < 32) ? -1.f : 1.f;

    {   // stage Q tile with RoPE -> fp16 [q][d]
        const int qpos = q0 + row;
        const float* bp = Qb + (size_t)qpos * 64;
        const float* cp = cosT + qpos * 32 + e;
        const float* sp = sinT + qpos * 32 + e;
        _Float16 t[16];
#pragma unroll
        for (int w4 = 0; w4 < 4; w4++) {
            float4 c4 = *(const float4*)(cp + 4 * w4);
            float4 s4v = *(const float4*)(sp + 4 * w4);
            float4 xa = *(const float4*)(bp + dq + 4 * w4);
            float4 xb = *(const float4*)(bp + comp + 4 * w4);
            t[4*w4+0] = (_Float16)fmaf(sgn * xb.x, s4v.x, xa.x * c4.x);
            t[4*w4+1] = (_Float16)fmaf(sgn * xb.y, s4v.y, xa.y * c4.y);
            t[4*w4+2] = (_Float16)fmaf(sgn * xb.z, s4v.z, xa.z * c4.z);
            t[4*w4+3] = (_Float16)fmaf(sgn * xb.w, s4v.w, xa.w * c4.w);
        }
        *(half8*)&Qh[row * 68 + dq]     = *(half8*)&t[0];
        *(half8*)&Qh[row * 68 + dq + 8] = *(half8*)&t[8];
    }
    floatx4 O[4];                    // [df] rows=q (lq*4+r), cols=d (df*16+lm)
#pragma unroll
    for (int df = 0; df < 4; df++) O[df] = (floatx4){0.f, 0.f, 0.f, 0.f};
    float m_run[4] = {-1e30f, -1e30f, -1e30f, -1e30f};
    float l_run[4] = {0.f, 0.f, 0.f, 0.f};

    for (int c = 0; c < 12; c++) {
        const int kp0 = (w - 1) * 256 + c * 64;
        if (kp0 < 0 || kp0 >= 8192) continue;    // look_around pad (block-uniform)
        __syncthreads();             // prior chunk's Vt/pT reads done
        {   // stage K chunk (RoPE) fp16 [k][d]
            const int kpos = kp0 + row;
            const float* bp = Kb + (size_t)kpos * 64;
            const float* cp = cosT + kpos * 32 + e;
            const float* sp = sinT + kpos * 32 + e;
            _Float16 t[16];
#pragma unroll
            for (int w4 = 0; w4 < 4; w4++) {
                float4 c4 = *(const float4*)(cp + 4 * w4);
                float4 s4v = *(const float4*)(sp + 4 * w4);
                float4 xa = *(const float4*)(bp + dq + 4 * w4);
                float4 xb = *(const float4*)(bp + comp + 4 * w4);
                t[4*w4+0] = (_Float16)fmaf(sgn * xb.x, s4v.x, xa.x * c4.x);
                t[4*w4+1] = (_Float16)fmaf(sgn * xb.y, s4v.y, xa.y * c4.y);
                t[4*w4+2] = (_Float16)fmaf(sgn * xb.z, s4v.z, xa.z * c4.z);
                t[4*w4+3] = (_Float16)fmaf(sgn * xb.w, s4v.w, xa.w * c4.w);
            }
            *(half8*)&Kh[row * 68 + dq]     = *(half8*)&t[0];
            *(half8*)&Kh[row * 68 + dq + 8] = *(half8*)&t[8];
        }
        {   // stage V transposed fp16 [d][k]: lane d, wave's 16-row block
            const int d = lane, nb = wv * 16;
            _Float16 t[16];
#pragma unroll
            for (int i = 0; i < 16; i++)
                t[i] = (_Float16)Vb[(size_t)(kp0 + nb + i) * 64 + d];
            *(half8*)&Vt[d * 68 + nb]     = *(half8*)&t[0];
            *(half8*)&Vt[d * 68 + nb + 8] = *(half8*)&t[8];
        }
        __syncthreads();             // Kh/Vt ready
        // QK^T: M=16 q (this wave), N=64 k, K=64 d
        floatx4 s4[4];
#pragma unroll
        for (int nf = 0; nf < 4; nf++) s4[nf] = (floatx4){0.f, 0.f, 0.f, 0.f};
#pragma unroll
        for (int ks = 0; ks < 2; ks++) {
            half8 aq = *(half8*)&Qh[(wv * 16 + lm) * 68 + ks * 32 + lq * 8];
            half8 bf[4];
#pragma unroll
            for (int nf = 0; nf < 4; nf++)
                bf[nf] = *(half8*)&Kh[(nf * 16 + lm) * 68 + ks * 32 + lq * 8];
#pragma unroll
            for (int nf = 0; nf < 4; nf++)
                s4[nf] = __builtin_amdgcn_mfma_f32_16x16x32_f16(aq, bf[nf], s4[nf], 0, 0, 0);
        }
        // online softmax in registers; scale = 64^-0.5 = 0.125
        float p[4][4];
#pragma unroll
        for (int r = 0; r < 4; r++) {
            float m0 = fmaxf(fmaxf(s4[0][r], s4[1][r]), fmaxf(s4[2][r], s4[3][r]));
            m0 = fmaxf(m0, __shfl_xor(m0, 1, 64));
            m0 = fmaxf(m0, __shfl_xor(m0, 2, 64));
            m0 = fmaxf(m0, __shfl_xor(m0, 4, 64));
            m0 = fmaxf(m0, __shfl_xor(m0, 8, 64));
            const float mn = fmaxf(m_run[r], m0 * 0.125f);
            const float al = expf(m_run[r] - mn);
            m_run[r] = mn;
            float rs = 0.f;
#pragma unroll
            for (int nf = 0; nf < 4; nf++) {
                float pv = expf(fmaf(s4[nf][r], 0.125f, -mn));
                p[nf][r] = pv;
                rs += pv;
            }
            l_run[r] = l_run[r] * al + rs;   // per-lane partial (4 of 64 cols)
#pragma unroll
            for (int df = 0; df < 4; df++) O[df][r] *= al;
        }
        // P -> LDS fp16 [q][k] (wave-private rows; conflict-free: lq groups 8 banks apart)
#pragma unroll
        for (int nf = 0; nf < 4; nf++)
#pragma unroll
            for (int r = 0; r < 4; r++)
                pT[(wv * 16 + lq * 4 + r) * 68 + nf * 16 + lm] = (_Float16)p[nf][r];
        __syncthreads();             // pT visible
        // PV: M=16 q (this wave), N=64 d, K=64 k
#pragma unroll
        for (int ks = 0; ks < 2; ks++) {
            half8 ap = *(half8*)&pT[(wv * 16 + lm) * 68 + ks * 32 + lq * 8];
            half8 bf[4];
#pragma unroll
            for (int df = 0; df < 4; df++)
                bf[df] = *(half8*)&Vt[(df * 16 + lm) * 68 + ks * 32 + lq * 8];
#pragma unroll
            for (int df = 0; df < 4; df++)
                O[df] = __builtin_amdgcn_mfma_f32_16x16x32_f16(ap, bf[df], O[df], 0, 0, 0);
        }
    }
    // final l reduce over lm, normalize, store
#pragma unroll
    for (int r = 0; r < 4; r++) {
        l_run[r] += __shfl_xor(l_run[r], 1, 64);
        l_run[r] += __shfl_xor(l_run[r], 2, 64);
        l_run[r] += __shfl_xor(l_run[r], 4, 64);
        l_run[r] += __shfl_xor(l_run[r], 8, 64);
        l_run[r] = 1.f / fmaxf(l_run[r], 1e-30f);
    }
    float* __restrict__ attL = ws + O_ATTL;   // [2][2][8192][64]
#pragma unroll
    for (int df = 0; df < 4; df++) {
#pragma unroll
        for (int r = 0; r < 4; r++) {
            const int q = q0 + wv * 16 + lq * 4 + r;
            attL[((size_t)(b * 2 + lh) * 8192 + q) * 64 + df * 16 + lm] = O[df][r] * l_run[r];
        }
    }
}

// ---------------- output projection + bias ----------------
__launch_bounds__(256)
__global__ void k_out(const float* __restrict__ Wo,
                      const float* __restrict__ bo,
                      const float* __restrict__ ws,
                      float* __restrict__ out) {
    __shared__ float As[16][128];
    __shared__ float Bs[16][128];
    const float* __restrict__ attG = ws + O_K;      // [16384][384]
    const float* __restrict__ attL = ws + O_ATTL;   // [4][8192][64]
    const int r0 = blockIdx.x * 128, c0 = blockIdx.y * 128;
    const int tid = threadIdx.x, tx = tid & 15, ty = tid >> 4;
    const int am = tid >> 1, ako = (tid & 1) * 8;
    const int bk = tid >> 4, bjo = (tid & 15) * 8;
    float acc[8][8];
#pragma unroll
    for (int i = 0; i < 8; i++)
#pragma unroll
        for (int j = 0; j < 8; j++) acc[i][j] = 0.f;

    for (int k0 = 0; k0 < 512; k0 += 16) {
        const int row = r0 + am;
        float4 a0, a1;
        if (k0 < 384) {
            a0 = *(const float4*)(attG + row * 384 + k0 + ako);
            a1 = *(const float4*)(attG + row * 384 + k0 + ako + 4);
        } else {
            const int bb = row >> 13, nn = row & 8191;
            const int kk0 = k0 + ako - 384;
            const int lhh = kk0 >> 6, dd = kk0 & 63;
            const float* src = attL + ((bb * 2 + lhh) * 8192 + nn) * 64 + dd;
            a0 = *(const float4*)(src);
            a1 = *(const float4*)(src + 4);
        }
        float4 b0 = *(const float4*)(Wo + (k0 + bk) * 512 + c0 + bjo);
        float4 b1 = *(const float4*)(Wo + (k0 + bk) * 512 + c0 + bjo + 4);
        As[ako + 0][am] = a0.x; As[ako + 1][am] = a0.y;
        As[ako + 2][am] = a0.z; As[ako + 3][am] = a0.w;
        As[ako + 4][am] = a1.x; As[ako + 5][am] = a1.y;
        As[ako + 6][am] = a1.z; As[ako + 7][am] = a1.w;
        *(float4*)&Bs[bk][bjo]     = b0;
        *(float4*)&Bs[bk][bjo + 4] = b1;
        __syncthreads();
#pragma unroll
        for (int kk = 0; kk < 16; kk++) {
            float4 a04 = *(float4*)&As[kk][ty * 8];
            float4 a14 = *(float4*)&As[kk][ty * 8 + 4];
            float4 b04 = *(float4*)&Bs[kk][tx * 4];
            float4 b14 = *(float4*)&Bs[kk][64 + tx * 4];
            float a[8] = {a04.x, a04.y, a04.z, a04.w, a14.x, a14.y, a14.z, a14.w};
            float b[8] = {b04.x, b04.y, b04.z, b04.w, b14.x, b14.y, b14.z, b14.w};
#pragma unroll
            for (int i = 0; i < 8; i++)
#pragma unroll
                for (int j = 0; j < 8; j++) acc[i][j] = fmaf(a[i], b[j], acc[i][j]);
        }
        __syncthreads();
    }
    const int col0 = c0 + tx * 4, col1 = c0 + 64 + tx * 4;
    float4 bo0 = *(const float4*)(bo + col0);
    float4 bo1 = *(const float4*)(bo + col1);
#pragma unroll
    for (int i = 0; i < 8; i++) {
        int r = r0 + ty * 8 + i;
        *(float4*)&out[r * 512 + col0] =
            make_float4(acc[i][0] + bo0.x, acc[i][1] + bo0.y, acc[i][2] + bo0.z, acc[i][3] + bo0.w);
        *(float4*)&out[r * 512 + col1] =
            make_float4(acc[i][4] + bo1.x, acc[i][5] + bo1.y, acc[i][6] + bo1.z, acc[i][7] + bo1.w);
    }
}

extern "C" void kernel_launch(void* const* d_in, const int* in_sizes, int n_in,
                              void* d_out, int out_size, void* d_ws, size_t ws_size,
                              hipStream_t stream) {
    const float* x    = (const float*)d_in[0];
    const float* Wq   = (const float*)d_in[1];
    const float* Wk   = (const float*)d_in[2];
    const float* Wv   = (const float*)d_in[3];
    const float* Wo   = (const float*)d_in[4];
    const float* bo   = (const float*)d_in[5];
    const float* proj = (const float*)d_in[6];
    float* ws = (float*)d_ws;
    float* out = (float*)d_out;

    hipMemsetAsync(d_ws, 0, (size_t)O_ZEND * 4, stream);                 // kmax/ksum/ctx
    hipLaunchKernelGGL(k_rope,   dim3(1024), dim3(256), 0, stream, ws);
    hipLaunchKernelGGL(k_half_w, dim3(8, 8, 3), dim3(256), 0, stream, Wq, Wk, Wv, ws);
    hipLaunchKernelGGL(k_qkv,    dim3(128, 4, 3), dim3(256), 0, stream, x, ws);
    hipLaunchKernelGGL(k_kmax,   dim3(12, 128), dim3(256), 0, stream, proj, ws);
    hipLaunchKernelGGL(k_kctx,   dim3(12, 32, 2), dim3(256), 0, stream, proj, ws);
    hipLaunchKernelGGL(k_local,  dim3(4, 128), dim3(256), 0, stream, ws);   // before k_qout!
    hipLaunchKernelGGL(k_qout,   dim3(12, 128), dim3(256), 0, stream, proj, ws);
    hipLaunchKernelGGL(k_out,    dim3(128, 4), dim3(256), 0, stream, Wo, bo, ws, out);
}

// Round 3
// 366.364 us; speedup vs baseline: 1.8196x; 1.1856x over previous
//
#include <hip/hip_runtime.h>

// ---------------- constants ----------------
#define NTOK 8192
#define NORMC 0.35355339059327373f   // 64^-0.25
#define RATIO 0.0625f                // 256^-0.5
#define KEPS  1e-4f

// ws offsets in 4-byte elements  (total 27987008 ele = 106.8 MB)
#define O_KMAX 0                      // 12 x u32 (encoded max)
#define O_KSUM 64                     // 12*256 f32
#define O_CTX  3136                   // 12*256*64 f32; after k_qout reused as WoT fp16 [512][512]
#define O_ZEND 199744                 // zeroed region end
#define O_COS  199744                 // 8192*32
#define O_SIN  461888                 // 8192*32
#define O_Q    724032                 // 2*8*8192*64
#define O_K    9112640                // K; later reused as attG [16384][384]
#define O_V    17501248
#define O_ATTL 25889856               // 2*2*8192*64 (local heads out)
// O_WH: fp16 W^T [3][512][512] lives in the ATTL region (dead until k_local,
// consumed only by k_qkv which runs first) -> zero footprint growth
#define O_WH   25889856
// end: 27987008

typedef _Float16 half8 __attribute__((ext_vector_type(8)));
typedef _Float16 half4h __attribute__((ext_vector_type(4)));
typedef float floatx4 __attribute__((ext_vector_type(4)));

__device__ __forceinline__ unsigned encf(float f) {
    unsigned u = __float_as_uint(f);
    return (u & 0x80000000u) ? ~u : (u | 0x80000000u);
}
__device__ __forceinline__ float decf(unsigned u) {
    return (u & 0x80000000u) ? __uint_as_float(u & 0x7fffffffu) : __uint_as_float(~u);
}

// ---------------- RoPE tables (double precision angles) ----------------
__global__ void k_rope(float* __restrict__ ws) {
    int idx = blockIdx.x * 256 + threadIdx.x;      // 8192*32
    int t = idx >> 5, i = idx & 31;
    double invf = pow(10000.0, -(double)(2 * i) / 64.0);
    double ang = (double)t * invf;
    ws[O_COS + idx] = (float)cos(ang);
    ws[O_SIN + idx] = (float)sin(ang);
}

// ---------------- W -> fp16, transposed to [n][k] ----------------
__launch_bounds__(256)
__global__ void k_half_w(const float* __restrict__ Wq,
                         const float* __restrict__ Wk,
                         const float* __restrict__ Wv,
                         float* __restrict__ ws) {
    __shared__ float T[64][65];
    const int z = blockIdx.z;
    const float* __restrict__ W = (z == 0) ? Wq : ((z == 1) ? Wk : Wv);
    _Float16* __restrict__ Wt = (_Float16*)(ws + O_WH) + (size_t)z * 262144;
    const int k0 = blockIdx.x * 64, n0 = blockIdx.y * 64;
    const int lx = threadIdx.x & 63, ly = threadIdx.x >> 6;   // ly in 0..3
#pragma unroll
    for (int i = 0; i < 16; i++) {
        const int kk = ly * 16 + i;
        T[lx][kk] = W[(k0 + kk) * 512 + n0 + lx];    // T[n-n0][k-k0]
    }
    __syncthreads();
#pragma unroll
    for (int i = 0; i < 16; i++) {
        const int nn = ly * 16 + i;
        Wt[(n0 + nn) * 512 + k0 + lx] = (_Float16)T[nn][lx];
    }
}

// ---------------- Wo -> fp16 transposed [n][k], into dead ctx region ----------------
// Launched AFTER k_qout (last reader of ctx). 512*512 fp16 = 131072 f32 slots
// fits the 196608-f32 ctx region.
__launch_bounds__(256)
__global__ void k_half_wo(const float* __restrict__ Wo, float* __restrict__ ws) {
    __shared__ float T[64][65];
    _Float16* __restrict__ Wt = (_Float16*)(ws + O_CTX);
    const int k0 = blockIdx.x * 64, n0 = blockIdx.y * 64;
    const int lx = threadIdx.x & 63, ly = threadIdx.x >> 6;
#pragma unroll
    for (int i = 0; i < 16; i++) {
        const int kk = ly * 16 + i;
        T[lx][kk] = Wo[(k0 + kk) * 512 + n0 + lx];
    }
    __syncthreads();
#pragma unroll
    for (int i = 0; i < 16; i++) {
        const int nn = ly * 16 + i;
        Wt[(n0 + nn) * 512 + k0 + lx] = (_Float16)T[nn][lx];
    }
}

// ---------------- QKV projection via fp16 MFMA ----------------
__launch_bounds__(256)
__global__ void k_qkv(const float* __restrict__ x, float* __restrict__ ws) {
    __shared__ _Float16 Ah[128 * 72];
    __shared__ _Float16 Bh[128 * 72];
    const int z = blockIdx.z;
    const _Float16* __restrict__ Wt = (const _Float16*)(ws + O_WH) + (size_t)z * 262144;
    float* __restrict__ out = ws + ((z == 0) ? O_Q : ((z == 1) ? O_K : O_V));
    const int r0 = blockIdx.x * 128, c0 = blockIdx.y * 128;
    const int tid = threadIdx.x;
    const int wv = tid >> 6, lane = tid & 63, lm = lane & 15, lq = lane >> 4;
    const int srow = tid >> 1, skoff = (tid & 1) * 32;
    floatx4 acc[2][8];
#pragma unroll
    for (int m = 0; m < 2; m++)
#pragma unroll
        for (int n = 0; n < 8; n++) acc[m][n] = (floatx4){0.f, 0.f, 0.f, 0.f};

    for (int c = 0; c < 8; c++) {
        const int k0 = c * 64;
        {   // stage A: x fp32 -> fp16 (row-major, k contiguous)
            const float* ap = x + (size_t)(r0 + srow) * 512 + k0 + skoff;
#pragma unroll
            for (int q = 0; q < 4; q++) {
                float4 v0 = *(const float4*)(ap + 8 * q);
                float4 v1 = *(const float4*)(ap + 8 * q + 4);
                half8 h = {(_Float16)v0.x, (_Float16)v0.y, (_Float16)v0.z, (_Float16)v0.w,
                           (_Float16)v1.x, (_Float16)v1.y, (_Float16)v1.z, (_Float16)v1.w};
                *(half8*)&Ah[srow * 72 + skoff + 8 * q] = h;
            }
        }
        {   // stage B: fp16 W^T direct copy
            const _Float16* bp = Wt + (size_t)(c0 + srow) * 512 + k0 + skoff;
#pragma unroll
            for (int q = 0; q < 4; q++)
                *(uint4*)&Bh[srow * 72 + skoff + 8 * q] = *(const uint4*)(bp + 8 * q);
        }
        __syncthreads();
#pragma unroll
        for (int ks = 0; ks < 2; ks++) {
            half8 af[2], bf[8];
            af[0] = *(half8*)&Ah[(wv * 32 + lm) * 72 + ks * 32 + lq * 8];
            af[1] = *(half8*)&Ah[(wv * 32 + 16 + lm) * 72 + ks * 32 + lq * 8];
#pragma unroll
            for (int n = 0; n < 8; n++)
                bf[n] = *(half8*)&Bh[(n * 16 + lm) * 72 + ks * 32 + lq * 8];
#pragma unroll
            for (int m = 0; m < 2; m++)
#pragma unroll
                for (int n = 0; n < 8; n++)
                    acc[m][n] = __builtin_amdgcn_mfma_f32_16x16x32_f16(af[m], bf[n], acc[m][n], 0, 0, 0);
        }
        __syncthreads();
    }
    const int bi = r0 >> 13;
#pragma unroll
    for (int n = 0; n < 8; n++) {
        const int col = c0 + n * 16 + lm;
        const int h = col >> 6, d = col & 63;
#pragma unroll
        for (int m = 0; m < 2; m++) {
            const int rbase = r0 + wv * 32 + m * 16 + lq * 4;
#pragma unroll
            for (int j = 0; j < 4; j++) {
                const int ng = (rbase + j) & 8191;
                out[((size_t)(bi * 8 + h) * 8192 + ng) * 64 + d] = acc[m][n][j];
            }
        }
    }
}

// ---------------- key-side global max of dd = norm*(K.projT) (fp16 MFMA) ----------------
__launch_bounds__(256)
__global__ void k_kmax(const float* __restrict__ proj, float* __restrict__ ws) {
    __shared__ _Float16 Kh[64 * 68];      // K tile [n][d] fp16
    __shared__ _Float16 Ph[256 * 68];     // proj [j][d] fp16
    __shared__ unsigned bmax;
    const int bh = blockIdx.x, b = bh / 6, h = bh % 6;
    const float* __restrict__ Kp = ws + O_K + (size_t)(b * 8 + h) * 8192 * 64;
    const int n0 = blockIdx.y * 64;
    const int tid = threadIdx.x;
    const int wv = tid >> 6, lane = tid & 63, lm = lane & 15, lq = lane >> 4;
    if (tid == 0) bmax = 0u;
    {   // stage Kh [n][d] fp16
        const int r = tid >> 2, dq = (tid & 3) * 16;
        const float* kpp = Kp + (size_t)(n0 + r) * 64 + dq;
        _Float16 t[16];
#pragma unroll
        for (int q = 0; q < 4; q++) {
            float4 v = *(const float4*)(kpp + 4 * q);
            t[4*q+0] = (_Float16)v.x; t[4*q+1] = (_Float16)v.y;
            t[4*q+2] = (_Float16)v.z; t[4*q+3] = (_Float16)v.w;
        }
        *(half8*)&Kh[r * 68 + dq]     = *(half8*)&t[0];
        *(half8*)&Kh[r * 68 + dq + 8] = *(half8*)&t[8];
    }
    {   // stage Ph [j][d] fp16 (256 rows, 2 passes, 2 threads/row)
#pragma unroll
        for (int ph = 0; ph < 2; ph++) {
            const int r = ph * 128 + (tid >> 1), doff = (tid & 1) * 32;
            const float* pp = proj + r * 64 + doff;
#pragma unroll
            for (int q = 0; q < 4; q++) {
                float4 v0 = *(const float4*)(pp + 8 * q);
                float4 v1 = *(const float4*)(pp + 8 * q + 4);
                half8 hv = {(_Float16)v0.x, (_Float16)v0.y, (_Float16)v0.z, (_Float16)v0.w,
                            (_Float16)v1.x, (_Float16)v1.y, (_Float16)v1.z, (_Float16)v1.w};
                *(half8*)&Ph[r * 68 + doff + 8 * q] = hv;
            }
        }
    }
    __syncthreads();
    // dd[n][j]: M=64 n, N=64 j (this wave's slice), K=64
    floatx4 s4[4][4];
#pragma unroll
    for (int nt = 0; nt < 4; nt++)
#pragma unroll
        for (int jt = 0; jt < 4; jt++) s4[nt][jt] = (floatx4){0.f, 0.f, 0.f, 0.f};
#pragma unroll
    for (int ks = 0; ks < 2; ks++) {
        half8 af[4], bf[4];
#pragma unroll
        for (int nt = 0; nt < 4; nt++)
            af[nt] = *(half8*)&Kh[(nt * 16 + lm) * 68 + ks * 32 + lq * 8];
#pragma unroll
        for (int jt = 0; jt < 4; jt++)
            bf[jt] = *(half8*)&Ph[(wv * 64 + jt * 16 + lm) * 68 + ks * 32 + lq * 8];
#pragma unroll
        for (int nt = 0; nt < 4; nt++)
#pragma unroll
            for (int jt = 0; jt < 4; jt++)
                s4[nt][jt] = __builtin_amdgcn_mfma_f32_16x16x32_f16(af[nt], bf[jt], s4[nt][jt], 0, 0, 0);
    }
    float m = -1e30f;
#pragma unroll
    for (int nt = 0; nt < 4; nt++)
#pragma unroll
        for (int jt = 0; jt < 4; jt++)
#pragma unroll
            for (int r = 0; r < 4; r++) m = fmaxf(m, s4[nt][jt][r]);
    m = fmaxf(m, __shfl_xor(m, 1, 64));
    m = fmaxf(m, __shfl_xor(m, 2, 64));
    m = fmaxf(m, __shfl_xor(m, 4, 64));
    m = fmaxf(m, __shfl_xor(m, 8, 64));
    m = fmaxf(m, __shfl_xor(m, 16, 64));
    m = fmaxf(m, __shfl_xor(m, 32, 64));
    if (lane == 0) atomicMax(&bmax, encf(m * NORMC));
    __syncthreads();
    if (tid == 0) atomicMax((unsigned*)ws + O_KMAX + bh, bmax);
}

// ---------------- key-side: kp, k_sum, ctx = kp^T @ V  (fp16 MFMA) ----------------
__launch_bounds__(256)
__global__ void k_kctx(const float* __restrict__ proj, float* __restrict__ ws) {
    __shared__ _Float16 Kh[64 * 68];     // K sub [n][d]
    __shared__ _Float16 Vt[64 * 68];     // V sub transposed [d][n]
    __shared__ _Float16 Ph[128 * 68];    // proj half [j][d]
    __shared__ _Float16 kpt[128 * 68];   // kp transposed [j][n]
    __shared__ float diag4[64][4];       // per-row |K|^2 partials (race-free)
    __shared__ float ksum_s[128];
    const int bh = blockIdx.x, b = bh / 6, h = bh % 6;
    const int n0 = blockIdx.y * 256;
    const int jh = blockIdx.z;
    const float* __restrict__ Kp = ws + O_K + (size_t)(b * 8 + h) * 8192 * 64;
    const float* __restrict__ Vp = ws + O_V + (size_t)(b * 8 + h) * 8192 * 64;
    const float kmax = decf(((const unsigned*)ws)[O_KMAX + bh]);
    const int tid = threadIdx.x;
    const int wv = tid >> 6, lane = tid & 63, lm = lane & 15, lq = lane >> 4;
    if (tid < 128) ksum_s[tid] = 0.f;

    {   // stage Ph once: proj rows jh*128.., [jrel][d] stride 68
        const int r = tid >> 1, doff = (tid & 1) * 32;
        const float* pp = proj + (jh * 128 + r) * 64 + doff;
#pragma unroll
        for (int q = 0; q < 4; q++) {
            float4 v0 = *(const float4*)(pp + 8 * q);
            float4 v1 = *(const float4*)(pp + 8 * q + 4);
            half8 hv = {(_Float16)v0.x, (_Float16)v0.y, (_Float16)v0.z, (_Float16)v0.w,
                        (_Float16)v1.x, (_Float16)v1.y, (_Float16)v1.z, (_Float16)v1.w};
            *(half8*)&Ph[r * 68 + doff + 8 * q] = hv;
        }
    }
    floatx4 acc[2][4];   // ctx tiles [jt][dt]
#pragma unroll
    for (int jt = 0; jt < 2; jt++)
#pragma unroll
        for (int dt = 0; dt < 4; dt++) acc[jt][dt] = (floatx4){0.f, 0.f, 0.f, 0.f};

    for (int nc = 0; nc < 4; nc++) {
        const int ns = n0 + nc * 64;
        {   // stage Kh [n][d] + diag partials
            const int r = tid >> 2, dq = (tid & 3) * 16;
            const float* kpp = Kp + (size_t)(ns + r) * 64 + dq;
            float part = 0.f;
            _Float16 t[16];
#pragma unroll
            for (int q = 0; q < 4; q++) {
                float4 v = *(const float4*)(kpp + 4 * q);
                part = fmaf(v.x, v.x, fmaf(v.y, v.y, fmaf(v.z, v.z, fmaf(v.w, v.w, part))));
                t[4*q+0] = (_Float16)v.x; t[4*q+1] = (_Float16)v.y;
                t[4*q+2] = (_Float16)v.z; t[4*q+3] = (_Float16)v.w;
            }
            *(half8*)&Kh[r * 68 + dq]     = *(half8*)&t[0];
            *(half8*)&Kh[r * 68 + dq + 8] = *(half8*)&t[8];
            diag4[r][tid & 3] = part;
        }
        {   // stage Vt transposed [d][n]: thread d = tid&63, n-block of 16
            const int d = tid & 63, nb = (tid >> 6) * 16;
            _Float16 t[16];
#pragma unroll
            for (int i = 0; i < 16; i++)
                t[i] = (_Float16)Vp[(size_t)(ns + nb + i) * 64 + d];
            *(half8*)&Vt[d * 68 + nb]     = *(half8*)&t[0];
            *(half8*)&Vt[d * 68 + nb + 8] = *(half8*)&t[8];
        }
        __syncthreads();                              // A: Kh/Vt/diag4 ready (kpt free)
        // dd[n][j]: M=64 n, N=32 j (this wave), K=64
        floatx4 s4[4][2];
#pragma unroll
        for (int nt = 0; nt < 4; nt++)
#pragma unroll
            for (int jt = 0; jt < 2; jt++) s4[nt][jt] = (floatx4){0.f, 0.f, 0.f, 0.f};
#pragma unroll
        for (int ks = 0; ks < 2; ks++) {
            half8 af[4], bf[2];
#pragma unroll
            for (int nt = 0; nt < 4; nt++)
                af[nt] = *(half8*)&Kh[(nt * 16 + lm) * 68 + ks * 32 + lq * 8];
#pragma unroll
            for (int jt = 0; jt < 2; jt++)
                bf[jt] = *(half8*)&Ph[(wv * 32 + jt * 16 + lm) * 68 + ks * 32 + lq * 8];
#pragma unroll
            for (int nt = 0; nt < 4; nt++)
#pragma unroll
                for (int jt = 0; jt < 2; jt++)
                    s4[nt][jt] = __builtin_amdgcn_mfma_f32_16x16x32_f16(af[nt], bf[jt], s4[nt][jt], 0, 0, 0);
        }
        // exp in C-layout (col=j=lm, row=n=lq*4+reg), kp -> kpt [j][n] fp16
        float jsum[2] = {0.f, 0.f};
#pragma unroll
        for (int nt = 0; nt < 4; nt++) {
            float dg[4];
#pragma unroll
            for (int r = 0; r < 4; r++) {
                float4 d4 = *(float4*)diag4[nt * 16 + lq * 4 + r];   // broadcast read
                dg[r] = (d4.x + d4.y + d4.z + d4.w) * 0.0625f;
            }
#pragma unroll
            for (int jt = 0; jt < 2; jt++) {
                half4h kv;
#pragma unroll
                for (int r = 0; r < 4; r++) {
                    float v = RATIO * (expf(fminf(NORMC * s4[nt][jt][r] - dg[r] - kmax, 0.f)) + KEPS);
                    jsum[jt] += v;
                    kv[r] = (_Float16)v;
                }
                *(half4h*)&kpt[(wv * 32 + jt * 16 + lm) * 68 + nt * 16 + lq * 4] = kv;
            }
        }
#pragma unroll
        for (int jt = 0; jt < 2; jt++)
            atomicAdd(&ksum_s[wv * 32 + jt * 16 + lm], jsum[jt]);
        __syncthreads();                              // B: kpt ready
        // ctx[j][d] += kp^T @ V: M=32 j (this wave), N=64 d, K=64 n
#pragma unroll
        for (int ks = 0; ks < 2; ks++) {
            half8 af[2], bf[4];
#pragma unroll
            for (int jt = 0; jt < 2; jt++)
                af[jt] = *(half8*)&kpt[(wv * 32 + jt * 16 + lm) * 68 + ks * 32 + lq * 8];
#pragma unroll
            for (int dt = 0; dt < 4; dt++)
                bf[dt] = *(half8*)&Vt[(dt * 16 + lm) * 68 + ks * 32 + lq * 8];
#pragma unroll
            for (int jt = 0; jt < 2; jt++)
#pragma unroll
                for (int dt = 0; dt < 4; dt++)
                    acc[jt][dt] = __builtin_amdgcn_mfma_f32_16x16x32_f16(af[jt], bf[dt], acc[jt][dt], 0, 0, 0);
        }
        __syncthreads();                              // D: before next staging
    }
    // flush: C-layout col=d=lm, row=j=lq*4+reg
    float* __restrict__ ctxp = ws + O_CTX + bh * 16384;
#pragma unroll
    for (int jt = 0; jt < 2; jt++) {
#pragma unroll
        for (int dt = 0; dt < 4; dt++) {
            const int d = dt * 16 + lm;
#pragma unroll
            for (int r = 0; r < 4; r++) {
                const int j = jh * 128 + wv * 32 + jt * 16 + lq * 4 + r;
                atomicAdd(&ctxp[j * 64 + d], acc[jt][dt][r]);
            }
        }
    }
    if (tid < 128) atomicAdd(ws + O_KSUM + bh * 256 + jh * 128 + tid, ksum_s[tid]);
}

// ---------------- query-side: dd, rowmax, qp, attG = qp.ctx / (qp.ksum) (fp16 MFMA) ----
__launch_bounds__(256)
__global__ void k_qout(const float* __restrict__ proj, float* __restrict__ ws) {
    __shared__ _Float16 Qh[64 * 68];      // Q tile [n][d] fp16
    __shared__ _Float16 PhQp[256 * 68];   // proj [j][d] fp16; reused as qp [n][j] stride 260
    __shared__ _Float16 Ct[64 * 260];     // ctx^T [d][j] fp16
    __shared__ float ksum_s[256];
    __shared__ float diag4[64][4];
    __shared__ float diag_s[64];
    __shared__ unsigned rmax_s[64];
    __shared__ float denom_s[64];
    const int bh = blockIdx.x, b = bh / 6, h = bh % 6;
    const int n0 = blockIdx.y * 64;
    const float* __restrict__ Qp = ws + O_Q + (size_t)(b * 8 + h) * 8192 * 64;
    const float* __restrict__ ctxp = ws + O_CTX + bh * 16384;
    float* __restrict__ attG = ws + O_K;     // [16384][384]
    const int tid = threadIdx.x;
    const int wv = tid >> 6, lane = tid & 63, lm = lane & 15, lq = lane >> 4;
    if (tid < 64) { rmax_s[tid] = 0u; denom_s[tid] = 0.f; }
    ksum_s[tid] = ws[O_KSUM + bh * 256 + tid];

    {   // stage Qh [n][d] fp16 + |Q|^2 partials
        const int r = tid >> 2, dq = (tid & 3) * 16;
        const float* qpp = Qp + (size_t)(n0 + r) * 64 + dq;
        float part = 0.f;
        _Float16 t[16];
#pragma unroll
        for (int q = 0; q < 4; q++) {
            float4 v = *(const float4*)(qpp + 4 * q);
            part = fmaf(v.x, v.x, fmaf(v.y, v.y, fmaf(v.z, v.z, fmaf(v.w, v.w, part))));
            t[4*q+0] = (_Float16)v.x; t[4*q+1] = (_Float16)v.y;
            t[4*q+2] = (_Float16)v.z; t[4*q+3] = (_Float16)v.w;
        }
        *(half8*)&Qh[r * 68 + dq]     = *(half8*)&t[0];
        *(half8*)&Qh[r * 68 + dq + 8] = *(half8*)&t[8];
        diag4[r][tid & 3] = part;
    }
    {   // stage Ph [j][d] fp16 (256 rows, 2 passes, 2 threads/row)
#pragma unroll
        for (int ph = 0; ph < 2; ph++) {
            const int r = ph * 128 + (tid >> 1), doff = (tid & 1) * 32;
            const float* pp = proj + r * 64 + doff;
#pragma unroll
            for (int q = 0; q < 4; q++) {
                float4 v0 = *(const float4*)(pp + 8 * q);
                float4 v1 = *(const float4*)(pp + 8 * q + 4);
                half8 hv = {(_Float16)v0.x, (_Float16)v0.y, (_Float16)v0.z, (_Float16)v0.w,
                            (_Float16)v1.x, (_Float16)v1.y, (_Float16)v1.z, (_Float16)v1.w};
                *(half8*)&PhQp[r * 68 + doff + 8 * q] = hv;
            }
        }
    }
    {   // stage Ct [d][j] fp16 (transpose of ctx [j][d]; lane sweeps d -> coalesced)
        const int d = tid & 63;
#pragma unroll
        for (int jb = 0; jb < 4; jb++) {
            const int js = jb * 64 + (tid >> 6) * 16;
            _Float16 t[16];
#pragma unroll
            for (int i = 0; i < 16; i++)
                t[i] = (_Float16)ctxp[(js + i) * 64 + d];
            *(half8*)&Ct[d * 260 + js]     = *(half8*)&t[0];
            *(half8*)&Ct[d * 260 + js + 8] = *(half8*)&t[8];
        }
    }
    __syncthreads();
    if (tid < 64) {
        float4 d4 = *(float4*)diag4[tid];
        diag_s[tid] = (d4.x + d4.y + d4.z + d4.w) * 0.0625f;
    }
    // dd = Q . proj^T : M=64 n, N=64 j (this wave's slice), K=64
    floatx4 s4[4][4];
#pragma unroll
    for (int nt = 0; nt < 4; nt++)
#pragma unroll
        for (int jt = 0; jt < 4; jt++) s4[nt][jt] = (floatx4){0.f, 0.f, 0.f, 0.f};
#pragma unroll
    for (int ks = 0; ks < 2; ks++) {
        half8 af[4], bf[4];
#pragma unroll
        for (int nt = 0; nt < 4; nt++)
            af[nt] = *(half8*)&Qh[(nt * 16 + lm) * 68 + ks * 32 + lq * 8];
#pragma unroll
        for (int jt = 0; jt < 4; jt++)
            bf[jt] = *(half8*)&PhQp[(wv * 64 + jt * 16 + lm) * 68 + ks * 32 + lq * 8];
#pragma unroll
        for (int nt = 0; nt < 4; nt++)
#pragma unroll
            for (int jt = 0; jt < 4; jt++)
                s4[nt][jt] = __builtin_amdgcn_mfma_f32_16x16x32_f16(af[nt], bf[jt], s4[nt][jt], 0, 0, 0);
    }
    // row maxima over this wave's 64 j -> cross-wave via LDS atomicMax
#pragma unroll
    for (int nt = 0; nt < 4; nt++) {
#pragma unroll
        for (int rr = 0; rr < 4; rr++) {
            float m0 = fmaxf(fmaxf(s4[nt][0][rr], s4[nt][1][rr]),
                             fmaxf(s4[nt][2][rr], s4[nt][3][rr]));
            m0 = fmaxf(m0, __shfl_xor(m0, 1, 64));
            m0 = fmaxf(m0, __shfl_xor(m0, 2, 64));
            m0 = fmaxf(m0, __shfl_xor(m0, 4, 64));
            m0 = fmaxf(m0, __shfl_xor(m0, 8, 64));
            if (lm == 0) atomicMax(&rmax_s[nt * 16 + lq * 4 + rr], encf(m0 * NORMC));
        }
    }
    __syncthreads();     // rmax_s/diag_s ready; all Ph reads done (qp may overwrite)
    // qp = RATIO*(exp(NORMC*dd - diag - rmax)+KEPS) -> fp16 LDS; denom into s4
#pragma unroll
    for (int nt = 0; nt < 4; nt++) {
#pragma unroll
        for (int rr = 0; rr < 4; rr++) {
            const int row = nt * 16 + lq * 4 + rr;
            const float rmx = decf(rmax_s[row]);
            const float dgv = diag_s[row];
#pragma unroll
            for (int jt = 0; jt < 4; jt++) {
                const int j = wv * 64 + jt * 16 + lm;
                float v = RATIO * (expf(fminf(NORMC * s4[nt][jt][rr] - dgv - rmx, 0.f)) + KEPS);
                PhQp[row * 260 + j] = (_Float16)v;
                s4[nt][jt][rr] = v * ksum_s[j];
            }
            float ds = s4[nt][0][rr] + s4[nt][1][rr] + s4[nt][2][rr] + s4[nt][3][rr];
            ds += __shfl_xor(ds, 1, 64);
            ds += __shfl_xor(ds, 2, 64);
            ds += __shfl_xor(ds, 4, 64);
            ds += __shfl_xor(ds, 8, 64);
            if (lm == 0) atomicAdd(&denom_s[row], ds);
        }
    }
    __syncthreads();     // qp + denom ready
    // attG = qp . ctx : M=64 n, N=16 d (this wave's slice), K=256 j
    floatx4 acc2[4];
#pragma unroll
    for (int nt = 0; nt < 4; nt++) acc2[nt] = (floatx4){0.f, 0.f, 0.f, 0.f};
#pragma unroll
    for (int ks = 0; ks < 8; ks++) {
        half8 bfv = *(half8*)&Ct[(wv * 16 + lm) * 260 + ks * 32 + lq * 8];
#pragma unroll
        for (int nt = 0; nt < 4; nt++) {
            half8 af = *(half8*)&PhQp[(nt * 16 + lm) * 260 + ks * 32 + lq * 8];
            acc2[nt] = __builtin_amdgcn_mfma_f32_16x16x32_f16(af, bfv, acc2[nt], 0, 0, 0);
        }
    }
#pragma unroll
    for (int nt = 0; nt < 4; nt++) {
#pragma unroll
        for (int rr = 0; rr < 4; rr++) {
            const int row = nt * 16 + lq * 4 + rr;
            const float inv = 1.0f / fmaxf(denom_s[row], 1e-30f);
            attG[((size_t)(b * 8192 + n0 + row)) * 384 + h * 64 + wv * 16 + lm] =
                acc2[nt][rr] * inv;
        }
    }
}

// ---------------- local windowed attention w/ RoPE, heads 6..7 (fp16 MFMA) ----------------
__launch_bounds__(256)
__global__ void k_local(float* __restrict__ ws) {
    __shared__ _Float16 Qh[64 * 68];     // RoPE'd Q [q][d]
    __shared__ _Float16 Kh[64 * 68];     // RoPE'd K chunk [k][d]
    __shared__ _Float16 Vt[64 * 68];     // V chunk transposed [d][k]
    __shared__ _Float16 pT[64 * 68];     // P [q][k] fp16
    const int bhp = blockIdx.x, b = bhp >> 1, lh = bhp & 1, h = 6 + lh;
    const int tile = blockIdx.y;                 // 0..127 (64-query tiles)
    const int w = tile >> 2;                     // window index
    const int q0 = tile * 64;
    const float* __restrict__ Qb = ws + O_Q + (size_t)(b * 8 + h) * 8192 * 64;
    const float* __restrict__ Kb = ws + O_K + (size_t)(b * 8 + h) * 8192 * 64;
    const float* __restrict__ Vb = ws + O_V + (size_t)(b * 8 + h) * 8192 * 64;
    const float* __restrict__ cosT = ws + O_COS;
    const float* __restrict__ sinT = ws + O_SIN;
    const int tid = threadIdx.x;
    const int wv = tid >> 6, lane = tid & 63, lm = lane & 15, lq = lane >> 4;
    // staging mapping: 4 threads per row, 16 dims each
    const int row = tid >> 2, dq = (tid & 3) * 16;
    const int e = dq & 31;
    const int comp = (dq < 32) ? dq + 32 : dq - 32;
    const float sgn = (dq < 32) ? -1.f : 1.f;

    {   // stage Q tile with RoPE -> fp16 [q][d]
        const int qpos = q0 + row;
        const float* bp = Qb + (size_t)qpos * 64;
        const float* cp = cosT + qpos * 32 + e;
        const float* sp = sinT + qpos * 32 + e;
        _Float16 t[16];
#pragma unroll
        for (int w4 = 0; w4 < 4; w4++) {
            float4 c4 = *(const float4*)(cp + 4 * w4);
            float4 s4v = *(const float4*)(sp + 4 * w4);
            float4 xa = *(const float4*)(bp + dq + 4 * w4);
            float4 xb = *(const float4*)(bp + comp + 4 * w4);
            t[4*w4+0] = (_Float16)fmaf(sgn * xb.x, s4v.x, xa.x * c4.x);
            t[4*w4+1] = (_Float16)fmaf(sgn * xb.y, s4v.y, xa.y * c4.y);
            t[4*w4+2] = (_Float16)fmaf(sgn * xb.z, s4v.z, xa.z * c4.z);
            t[4*w4+3] = (_Float16)fmaf(sgn * xb.w, s4v.w, xa.w * c4.w);
        }
        *(half8*)&Qh[row * 68 + dq]     = *(half8*)&t[0];
        *(half8*)&Qh[row * 68 + dq + 8] = *(half8*)&t[8];
    }
    floatx4 O[4];                    // [df] rows=q (lq*4+r), cols=d (df*16+lm)
#pragma unroll
    for (int df = 0; df < 4; df++) O[df] = (floatx4){0.f, 0.f, 0.f, 0.f};
    float m_run[4] = {-1e30f, -1e30f, -1e30f, -1e30f};
    float l_run[4] = {0.f, 0.f, 0.f, 0.f};

    for (int c = 0; c < 12; c++) {
        const int kp0 = (w - 1) * 256 + c * 64;
        if (kp0 < 0 || kp0 >= 8192) continue;    // look_around pad (block-uniform)
        __syncthreads();             // prior chunk's Vt/pT reads done
        {   // stage K chunk (RoPE) fp16 [k][d]
            const int kpos = kp0 + row;
            const float* bp = Kb + (size_t)kpos * 64;
            const float* cp = cosT + kpos * 32 + e;
            const float* sp = sinT + kpos * 32 + e;
            _Float16 t[16];
#pragma unroll
            for (int w4 = 0; w4 < 4; w4++) {
                float4 c4 = *(const float4*)(cp + 4 * w4);
                float4 s4v = *(const float4*)(sp + 4 * w4);
                float4 xa = *(const float4*)(bp + dq + 4 * w4);
                float4 xb = *(const float4*)(bp + comp + 4 * w4);
                t[4*w4+0] = (_Float16)fmaf(sgn * xb.x, s4v.x, xa.x * c4.x);
                t[4*w4+1] = (_Float16)fmaf(sgn * xb.y, s4v.y, xa.y * c4.y);
                t[4*w4+2] = (_Float16)fmaf(sgn * xb.z, s4v.z, xa.z * c4.z);
                t[4*w4+3] = (_Float16)fmaf(sgn * xb.w, s4v.w, xa.w * c4.w);
            }
            *(half8*)&Kh[row * 68 + dq]     = *(half8*)&t[0];
            *(half8*)&Kh[row * 68 + dq + 8] = *(half8*)&t[8];
        }
        {   // stage V transposed fp16 [d][k]: lane d, wave's 16-row block
            const int d = lane, nb = wv * 16;
            _Float16 t[16];
#pragma unroll
            for (int i = 0; i < 16; i++)
                t[i] = (_Float16)Vb[(size_t)(kp0 + nb + i) * 64 + d];
            *(half8*)&Vt[d * 68 + nb]     = *(half8*)&t[0];
            *(half8*)&Vt[d * 68 + nb + 8] = *(half8*)&t[8];
        }
        __syncthreads();             // Kh/Vt ready
        // QK^T: M=16 q (this wave), N=64 k, K=64 d
        floatx4 s4[4];
#pragma unroll
        for (int nf = 0; nf < 4; nf++) s4[nf] = (floatx4){0.f, 0.f, 0.f, 0.f};
#pragma unroll
        for (int ks = 0; ks < 2; ks++) {
            half8 aq = *(half8*)&Qh[(wv * 16 + lm) * 68 + ks * 32 + lq * 8];
            half8 bf[4];
#pragma unroll
            for (int nf = 0; nf < 4; nf++)
                bf[nf] = *(half8*)&Kh[(nf * 16 + lm) * 68 + ks * 32 + lq * 8];
#pragma unroll
            for (int nf = 0; nf < 4; nf++)
                s4[nf] = __builtin_amdgcn_mfma_f32_16x16x32_f16(aq, bf[nf], s4[nf], 0, 0, 0);
        }
        // online softmax in registers; scale = 64^-0.5 = 0.125
        float p[4][4];
#pragma unroll
        for (int r = 0; r < 4; r++) {
            float m0 = fmaxf(fmaxf(s4[0][r], s4[1][r]), fmaxf(s4[2][r], s4[3][r]));
            m0 = fmaxf(m0, __shfl_xor(m0, 1, 64));
            m0 = fmaxf(m0, __shfl_xor(m0, 2, 64));
            m0 = fmaxf(m0, __shfl_xor(m0, 4, 64));
            m0 = fmaxf(m0, __shfl_xor(m0, 8, 64));
            const float mn = fmaxf(m_run[r], m0 * 0.125f);
            const float al = expf(m_run[r] - mn);
            m_run[r] = mn;
            float rs = 0.f;
#pragma unroll
            for (int nf = 0; nf < 4; nf++) {
                float pv = expf(fmaf(s4[nf][r], 0.125f, -mn));
                p[nf][r] = pv;
                rs += pv;
            }
            l_run[r] = l_run[r] * al + rs;   // per-lane partial (4 of 64 cols)
#pragma unroll
            for (int df = 0; df < 4; df++) O[df][r] *= al;
        }
        // P -> LDS fp16 [q][k] (wave-private rows; conflict-free: lq groups 8 banks apart)
#pragma unroll
        for (int nf = 0; nf < 4; nf++)
#pragma unroll
            for (int r = 0; r < 4; r++)
                pT[(wv * 16 + lq * 4 + r) * 68 + nf * 16 + lm] = (_Float16)p[nf][r];
        __syncthreads();             // pT visible
        // PV: M=16 q (this wave), N=64 d, K=64 k
#pragma unroll
        for (int ks = 0; ks < 2; ks++) {
            half8 ap = *(half8*)&pT[(wv * 16 + lm) * 68 + ks * 32 + lq * 8];
            half8 bf[4];
#pragma unroll
            for (int df = 0; df < 4; df++)
                bf[df] = *(half8*)&Vt[(df * 16 + lm) * 68 + ks * 32 + lq * 8];
#pragma unroll
            for (int df = 0; df < 4; df++)
                O[df] = __builtin_amdgcn_mfma_f32_16x16x32_f16(ap, bf[df], O[df], 0, 0, 0);
        }
    }
    // final l reduce over lm, normalize, store
#pragma unroll
    for (int r = 0; r < 4; r++) {
        l_run[r] += __shfl_xor(l_run[r], 1, 64);
        l_run[r] += __shfl_xor(l_run[r], 2, 64);
        l_run[r] += __shfl_xor(l_run[r], 4, 64);
        l_run[r] += __shfl_xor(l_run[r], 8, 64);
        l_run[r] = 1.f / fmaxf(l_run[r], 1e-30f);
    }
    float* __restrict__ attL = ws + O_ATTL;   // [2][2][8192][64]
#pragma unroll
    for (int df = 0; df < 4; df++) {
#pragma unroll
        for (int r = 0; r < 4; r++) {
            const int q = q0 + wv * 16 + lq * 4 + r;
            attL[((size_t)(b * 2 + lh) * 8192 + q) * 64 + df * 16 + lm] = O[df][r] * l_run[r];
        }
    }
}

// ---------------- output projection + bias (fp16 MFMA) ----------------
// att [16384][512] (attG cols 0..383, attL cols 384..511) @ WoT fp16 -> out.
// k_qkv structure: 128x128 tile, Ah/Bh stride-72 fp16 LDS, acc[2][8]/wave.
__launch_bounds__(256)
__global__ void k_out(const float* __restrict__ bo,
                      const float* __restrict__ ws,
                      float* __restrict__ out) {
    __shared__ _Float16 Ah[128 * 72];
    __shared__ _Float16 Bh[128 * 72];
    const float* __restrict__ attG = ws + O_K;      // [16384][384]
    const float* __restrict__ attL = ws + O_ATTL;   // [4][8192][64]
    const _Float16* __restrict__ WoT = (const _Float16*)(ws + O_CTX);  // [512][512] [n][k]
    const int r0 = blockIdx.x * 128, c0 = blockIdx.y * 128;
    const int tid = threadIdx.x;
    const int wv = tid >> 6, lane = tid & 63, lm = lane & 15, lq = lane >> 4;
    const int srow = tid >> 1, skoff = (tid & 1) * 32;
    floatx4 acc[2][8];
#pragma unroll
    for (int m = 0; m < 2; m++)
#pragma unroll
        for (int n = 0; n < 8; n++) acc[m][n] = (floatx4){0.f, 0.f, 0.f, 0.f};

    for (int c = 0; c < 8; c++) {
        const int k0 = c * 64;
        {   // stage A: att fp32 -> fp16 (32-seg never straddles the 384 boundary)
            const int row = r0 + srow;
            const int kk = k0 + skoff;
            const float* ap;
            if (kk < 384) {
                ap = attG + (size_t)row * 384 + kk;
            } else {
                const int bb = row >> 13, nn = row & 8191;
                const int kr = kk - 384;
                ap = attL + ((size_t)(bb * 2 + (kr >> 6)) * 8192 + nn) * 64 + (kr & 63);
            }
#pragma unroll
            for (int q = 0; q < 4; q++) {
                float4 v0 = *(const float4*)(ap + 8 * q);
                float4 v1 = *(const float4*)(ap + 8 * q + 4);
                half8 h = {(_Float16)v0.x, (_Float16)v0.y, (_Float16)v0.z, (_Float16)v0.w,
                           (_Float16)v1.x, (_Float16)v1.y, (_Float16)v1.z, (_Float16)v1.w};
                *(half8*)&Ah[srow * 72 + skoff + 8 * q] = h;
            }
        }
        {   // stage B: WoT fp16 direct copy
            const _Float16* bp = WoT + (size_t)(c0 + srow) * 512 + k0 + skoff;
#pragma unroll
            for (int q = 0; q < 4; q++)
                *(uint4*)&Bh[srow * 72 + skoff + 8 * q] = *(const uint4*)(bp + 8 * q);
        }
        __syncthreads();
#pragma unroll
        for (int ks = 0; ks < 2; ks++) {
            half8 af[2], bf[8];
            af[0] = *(half8*)&Ah[(wv * 32 + lm) * 72 + ks * 32 + lq * 8];
            af[1] = *(half8*)&Ah[(wv * 32 + 16 + lm) * 72 + ks * 32 + lq * 8];
#pragma unroll
            for (int n = 0; n < 8; n++)
                bf[n] = *(half8*)&Bh[(n * 16 + lm) * 72 + ks * 32 + lq * 8];
#pragma unroll
            for (int m = 0; m < 2; m++)
#pragma unroll
                for (int n = 0; n < 8; n++)
                    acc[m][n] = __builtin_amdgcn_mfma_f32_16x16x32_f16(af[m], bf[n], acc[m][n], 0, 0, 0);
        }
        __syncthreads();
    }
#pragma unroll
    for (int n = 0; n < 8; n++) {
        const int col = c0 + n * 16 + lm;
        const float bias = bo[col];
#pragma unroll
        for (int m = 0; m < 2; m++) {
            const int rbase = r0 + wv * 32 + m * 16 + lq * 4;
#pragma unroll
            for (int j = 0; j < 4; j++)
                out[(size_t)(rbase + j) * 512 + col] = acc[m][n][j] + bias;
        }
    }
}

extern "C" void kernel_launch(void* const* d_in, const int* in_sizes, int n_in,
                              void* d_out, int out_size, void* d_ws, size_t ws_size,
                              hipStream_t stream) {
    const float* x    = (const float*)d_in[0];
    const float* Wq   = (const float*)d_in[1];
    const float* Wk   = (const float*)d_in[2];
    const float* Wv   = (const float*)d_in[3];
    const float* Wo   = (const float*)d_in[4];
    const float* bo   = (const float*)d_in[5];
    const float* proj = (const float*)d_in[6];
    float* ws = (float*)d_ws;
    float* out = (float*)d_out;

    hipMemsetAsync(d_ws, 0, (size_t)O_ZEND * 4, stream);                 // kmax/ksum/ctx
    hipLaunchKernelGGL(k_rope,   dim3(1024), dim3(256), 0, stream, ws);
    hipLaunchKernelGGL(k_half_w, dim3(8, 8, 3), dim3(256), 0, stream, Wq, Wk, Wv, ws);
    hipLaunchKernelGGL(k_qkv,    dim3(128, 4, 3), dim3(256), 0, stream, x, ws);
    hipLaunchKernelGGL(k_kmax,   dim3(12, 128), dim3(256), 0, stream, proj, ws);
    hipLaunchKernelGGL(k_kctx,   dim3(12, 32, 2), dim3(256), 0, stream, proj, ws);
    hipLaunchKernelGGL(k_local,  dim3(4, 128), dim3(256), 0, stream, ws);   // before k_qout!
    hipLaunchKernelGGL(k_qout,   dim3(12, 128), dim3(256), 0, stream, proj, ws);
    hipLaunchKernelGGL(k_half_wo, dim3(8, 8), dim3(256), 0, stream, Wo, ws); // ctx dead -> WoT
    hipLaunchKernelGGL(k_out,    dim3(128, 4), dim3(256), 0, stream, bo, ws, out);
}

// Round 4
// 335.902 us; speedup vs baseline: 1.9846x; 1.0907x over previous
//
#include <hip/hip_runtime.h>

// ---------------- constants ----------------
#define NTOK 8192
#define NORMC 0.35355339059327373f   // 64^-0.25
#define RATIO 0.0625f                // 256^-0.5
#define KEPS  1e-4f

// ws offsets in 4-byte elements  (total 27987008 ele = 106.8 MB)
// Q/K/V/attG/attL are now fp16 (half the region footprint).
#define O_KMAX 0                      // 12 x u32 (encoded max)
#define O_KSUM 64                     // 12*256 f32
#define O_CTX  3136                   // 12*256*64 f32; after k_qout reused as WoT fp16 [512][512]
#define O_ZEND 199744                 // zeroed region end
#define O_COS  199744                 // 8192*32
#define O_SIN  461888                 // 8192*32
#define O_Q    724032                 // fp16 [2][8][8192][64] (uses half the old region)
#define O_K    9112640                // fp16 K; later reused as attG fp16 [16384][384]
#define O_V    17501248               // fp16 V
#define O_ATTL 25889856               // fp16 [2][2][8192][64] (local heads out)
// O_WH: fp16 W^T [3][512][512] at region start (dead after k_qkv).
#define O_WH   25889856
// O_XH: fp16 x [16384][512] after WH (dead after k_qkv); attL overwrites later.
#define O_XH   26283072
// end: 27987008

typedef _Float16 half8 __attribute__((ext_vector_type(8)));
typedef _Float16 half4h __attribute__((ext_vector_type(4)));
typedef float floatx4 __attribute__((ext_vector_type(4)));

__device__ __forceinline__ unsigned encf(float f) {
    unsigned u = __float_as_uint(f);
    return (u & 0x80000000u) ? ~u : (u | 0x80000000u);
}
__device__ __forceinline__ float decf(unsigned u) {
    return (u & 0x80000000u) ? __uint_as_float(u & 0x7fffffffu) : __uint_as_float(~u);
}
__device__ __forceinline__ float sumsq8(half8 h) {
    float s = 0.f;
#pragma unroll
    for (int i = 0; i < 8; i++) { float v = (float)h[i]; s = fmaf(v, v, s); }
    return s;
}

// ---------------- RoPE tables (double precision angles) ----------------
__global__ void k_rope(float* __restrict__ ws) {
    int idx = blockIdx.x * 256 + threadIdx.x;      // 8192*32
    int t = idx >> 5, i = idx & 31;
    double invf = pow(10000.0, -(double)(2 * i) / 64.0);
    double ang = (double)t * invf;
    ws[O_COS + idx] = (float)cos(ang);
    ws[O_SIN + idx] = (float)sin(ang);
}

// ---------------- x -> fp16 ----------------
__launch_bounds__(256)
__global__ void k_half_x(const float* __restrict__ x, float* __restrict__ ws) {
    const int idx = blockIdx.x * 256 + threadIdx.x;   // *8 elements, 16384*512/8 = 1048576
    const float* p = x + (size_t)idx * 8;
    float4 a = *(const float4*)p, b = *(const float4*)(p + 4);
    half8 h = {(_Float16)a.x, (_Float16)a.y, (_Float16)a.z, (_Float16)a.w,
               (_Float16)b.x, (_Float16)b.y, (_Float16)b.z, (_Float16)b.w};
    *(half8*)((_Float16*)(ws + O_XH) + (size_t)idx * 8) = h;
}

// ---------------- W -> fp16, transposed to [n][k] ----------------
__launch_bounds__(256)
__global__ void k_half_w(const float* __restrict__ Wq,
                         const float* __restrict__ Wk,
                         const float* __restrict__ Wv,
                         float* __restrict__ ws) {
    __shared__ float T[64][65];
    const int z = blockIdx.z;
    const float* __restrict__ W = (z == 0) ? Wq : ((z == 1) ? Wk : Wv);
    _Float16* __restrict__ Wt = (_Float16*)(ws + O_WH) + (size_t)z * 262144;
    const int k0 = blockIdx.x * 64, n0 = blockIdx.y * 64;
    const int lx = threadIdx.x & 63, ly = threadIdx.x >> 6;   // ly in 0..3
#pragma unroll
    for (int i = 0; i < 16; i++) {
        const int kk = ly * 16 + i;
        T[lx][kk] = W[(k0 + kk) * 512 + n0 + lx];    // T[n-n0][k-k0]
    }
    __syncthreads();
#pragma unroll
    for (int i = 0; i < 16; i++) {
        const int nn = ly * 16 + i;
        Wt[(n0 + nn) * 512 + k0 + lx] = (_Float16)T[nn][lx];
    }
}

// ---------------- Wo -> fp16 transposed [n][k], into dead ctx region ----------------
__launch_bounds__(256)
__global__ void k_half_wo(const float* __restrict__ Wo, float* __restrict__ ws) {
    __shared__ float T[64][65];
    _Float16* __restrict__ Wt = (_Float16*)(ws + O_CTX);
    const int k0 = blockIdx.x * 64, n0 = blockIdx.y * 64;
    const int lx = threadIdx.x & 63, ly = threadIdx.x >> 6;
#pragma unroll
    for (int i = 0; i < 16; i++) {
        const int kk = ly * 16 + i;
        T[lx][kk] = Wo[(k0 + kk) * 512 + n0 + lx];
    }
    __syncthreads();
#pragma unroll
    for (int i = 0; i < 16; i++) {
        const int nn = ly * 16 + i;
        Wt[(n0 + nn) * 512 + k0 + lx] = (_Float16)T[nn][lx];
    }
}

// ---------------- QKV projection via fp16 MFMA (fp16 in, fp16 out) ----------------
__launch_bounds__(256)
__global__ void k_qkv(float* __restrict__ ws) {
    __shared__ _Float16 Ah[128 * 72];
    __shared__ _Float16 Bh[128 * 72];
    const int z = blockIdx.z;
    const _Float16* __restrict__ xh = (const _Float16*)(ws + O_XH);
    const _Float16* __restrict__ Wt = (const _Float16*)(ws + O_WH) + (size_t)z * 262144;
    _Float16* __restrict__ out = (_Float16*)(ws + ((z == 0) ? O_Q : ((z == 1) ? O_K : O_V)));
    const int r0 = blockIdx.x * 128, c0 = blockIdx.y * 128;
    const int tid = threadIdx.x;
    const int wv = tid >> 6, lane = tid & 63, lm = lane & 15, lq = lane >> 4;
    const int srow = tid >> 1, skoff = (tid & 1) * 32;
    floatx4 acc[2][8];
#pragma unroll
    for (int m = 0; m < 2; m++)
#pragma unroll
        for (int n = 0; n < 8; n++) acc[m][n] = (floatx4){0.f, 0.f, 0.f, 0.f};

    for (int c = 0; c < 8; c++) {
        const int k0 = c * 64;
        {   // stage A: x fp16 direct copy
            const _Float16* ap = xh + (size_t)(r0 + srow) * 512 + k0 + skoff;
#pragma unroll
            for (int q = 0; q < 4; q++)
                *(uint4*)&Ah[srow * 72 + skoff + 8 * q] = *(const uint4*)(ap + 8 * q);
        }
        {   // stage B: fp16 W^T direct copy
            const _Float16* bp = Wt + (size_t)(c0 + srow) * 512 + k0 + skoff;
#pragma unroll
            for (int q = 0; q < 4; q++)
                *(uint4*)&Bh[srow * 72 + skoff + 8 * q] = *(const uint4*)(bp + 8 * q);
        }
        __syncthreads();
#pragma unroll
        for (int ks = 0; ks < 2; ks++) {
            half8 af[2], bf[8];
            af[0] = *(half8*)&Ah[(wv * 32 + lm) * 72 + ks * 32 + lq * 8];
            af[1] = *(half8*)&Ah[(wv * 32 + 16 + lm) * 72 + ks * 32 + lq * 8];
#pragma unroll
            for (int n = 0; n < 8; n++)
                bf[n] = *(half8*)&Bh[(n * 16 + lm) * 72 + ks * 32 + lq * 8];
#pragma unroll
            for (int m = 0; m < 2; m++)
#pragma unroll
                for (int n = 0; n < 8; n++)
                    acc[m][n] = __builtin_amdgcn_mfma_f32_16x16x32_f16(af[m], bf[n], acc[m][n], 0, 0, 0);
        }
        __syncthreads();
    }
    const int bi = r0 >> 13;
#pragma unroll
    for (int n = 0; n < 8; n++) {
        const int col = c0 + n * 16 + lm;
        const int h = col >> 6, d = col & 63;
#pragma unroll
        for (int m = 0; m < 2; m++) {
            const int rbase = r0 + wv * 32 + m * 16 + lq * 4;
#pragma unroll
            for (int j = 0; j < 4; j++) {
                const int ng = (rbase + j) & 8191;
                out[((size_t)(bi * 8 + h) * 8192 + ng) * 64 + d] = (_Float16)acc[m][n][j];
            }
        }
    }
}

// ---------------- key-side global max of dd = norm*(K.projT) (fp16 MFMA) ----------------
__launch_bounds__(256)
__global__ void k_kmax(const float* __restrict__ proj, float* __restrict__ ws) {
    __shared__ _Float16 Kh[64 * 68];      // K tile [n][d] fp16
    __shared__ _Float16 Ph[256 * 68];     // proj [j][d] fp16
    __shared__ unsigned bmax;
    const int bh = blockIdx.x, b = bh / 6, h = bh % 6;
    const _Float16* __restrict__ Kp = (const _Float16*)(ws + O_K) + (size_t)(b * 8 + h) * 8192 * 64;
    const int n0 = blockIdx.y * 64;
    const int tid = threadIdx.x;
    const int wv = tid >> 6, lane = tid & 63, lm = lane & 15, lq = lane >> 4;
    if (tid == 0) bmax = 0u;
    {   // stage Kh [n][d] fp16 direct copy
        const int r = tid >> 2, dq = (tid & 3) * 16;
        const _Float16* kpp = Kp + (size_t)(n0 + r) * 64 + dq;
        *(uint4*)&Kh[r * 68 + dq]     = *(const uint4*)(kpp);
        *(uint4*)&Kh[r * 68 + dq + 8] = *(const uint4*)(kpp + 8);
    }
    {   // stage Ph [j][d] fp16 (256 rows, 2 passes, 2 threads/row)
#pragma unroll
        for (int ph = 0; ph < 2; ph++) {
            const int r = ph * 128 + (tid >> 1), doff = (tid & 1) * 32;
            const float* pp = proj + r * 64 + doff;
#pragma unroll
            for (int q = 0; q < 4; q++) {
                float4 v0 = *(const float4*)(pp + 8 * q);
                float4 v1 = *(const float4*)(pp + 8 * q + 4);
                half8 hv = {(_Float16)v0.x, (_Float16)v0.y, (_Float16)v0.z, (_Float16)v0.w,
                            (_Float16)v1.x, (_Float16)v1.y, (_Float16)v1.z, (_Float16)v1.w};
                *(half8*)&Ph[r * 68 + doff + 8 * q] = hv;
            }
        }
    }
    __syncthreads();
    // dd[n][j]: M=64 n, N=64 j (this wave's slice), K=64
    floatx4 s4[4][4];
#pragma unroll
    for (int nt = 0; nt < 4; nt++)
#pragma unroll
        for (int jt = 0; jt < 4; jt++) s4[nt][jt] = (floatx4){0.f, 0.f, 0.f, 0.f};
#pragma unroll
    for (int ks = 0; ks < 2; ks++) {
        half8 af[4], bf[4];
#pragma unroll
        for (int nt = 0; nt < 4; nt++)
            af[nt] = *(half8*)&Kh[(nt * 16 + lm) * 68 + ks * 32 + lq * 8];
#pragma unroll
        for (int jt = 0; jt < 4; jt++)
            bf[jt] = *(half8*)&Ph[(wv * 64 + jt * 16 + lm) * 68 + ks * 32 + lq * 8];
#pragma unroll
        for (int nt = 0; nt < 4; nt++)
#pragma unroll
            for (int jt = 0; jt < 4; jt++)
                s4[nt][jt] = __builtin_amdgcn_mfma_f32_16x16x32_f16(af[nt], bf[jt], s4[nt][jt], 0, 0, 0);
    }
    float m = -1e30f;
#pragma unroll
    for (int nt = 0; nt < 4; nt++)
#pragma unroll
        for (int jt = 0; jt < 4; jt++)
#pragma unroll
            for (int r = 0; r < 4; r++) m = fmaxf(m, s4[nt][jt][r]);
    m = fmaxf(m, __shfl_xor(m, 1, 64));
    m = fmaxf(m, __shfl_xor(m, 2, 64));
    m = fmaxf(m, __shfl_xor(m, 4, 64));
    m = fmaxf(m, __shfl_xor(m, 8, 64));
    m = fmaxf(m, __shfl_xor(m, 16, 64));
    m = fmaxf(m, __shfl_xor(m, 32, 64));
    if (lane == 0) atomicMax(&bmax, encf(m * NORMC));
    __syncthreads();
    if (tid == 0) atomicMax((unsigned*)ws + O_KMAX + bh, bmax);
}

// ---------------- key-side: kp, k_sum, ctx = kp^T @ V  (fp16 MFMA) ----------------
__launch_bounds__(256)
__global__ void k_kctx(const float* __restrict__ proj, float* __restrict__ ws) {
    __shared__ _Float16 Kh[64 * 68];     // K sub [n][d]
    __shared__ _Float16 Vt[64 * 68];     // V sub transposed [d][n]
    __shared__ _Float16 Ph[128 * 68];    // proj half [j][d]
    __shared__ _Float16 kpt[128 * 68];   // kp transposed [j][n]
    __shared__ float diag4[64][4];       // per-row |K|^2 partials (race-free)
    __shared__ float ksum_s[128];
    const int bh = blockIdx.x, b = bh / 6, h = bh % 6;
    const int n0 = blockIdx.y * 256;
    const int jh = blockIdx.z;
    const _Float16* __restrict__ Kp = (const _Float16*)(ws + O_K) + (size_t)(b * 8 + h) * 8192 * 64;
    const _Float16* __restrict__ Vp = (const _Float16*)(ws + O_V) + (size_t)(b * 8 + h) * 8192 * 64;
    const float kmax = decf(((const unsigned*)ws)[O_KMAX + bh]);
    const int tid = threadIdx.x;
    const int wv = tid >> 6, lane = tid & 63, lm = lane & 15, lq = lane >> 4;
    if (tid < 128) ksum_s[tid] = 0.f;

    {   // stage Ph once: proj rows jh*128.., [jrel][d] stride 68
        const int r = tid >> 1, doff = (tid & 1) * 32;
        const float* pp = proj + (jh * 128 + r) * 64 + doff;
#pragma unroll
        for (int q = 0; q < 4; q++) {
            float4 v0 = *(const float4*)(pp + 8 * q);
            float4 v1 = *(const float4*)(pp + 8 * q + 4);
            half8 hv = {(_Float16)v0.x, (_Float16)v0.y, (_Float16)v0.z, (_Float16)v0.w,
                        (_Float16)v1.x, (_Float16)v1.y, (_Float16)v1.z, (_Float16)v1.w};
            *(half8*)&Ph[r * 68 + doff + 8 * q] = hv;
        }
    }
    floatx4 acc[2][4];   // ctx tiles [jt][dt]
#pragma unroll
    for (int jt = 0; jt < 2; jt++)
#pragma unroll
        for (int dt = 0; dt < 4; dt++) acc[jt][dt] = (floatx4){0.f, 0.f, 0.f, 0.f};

    for (int nc = 0; nc < 4; nc++) {
        const int ns = n0 + nc * 64;
        {   // stage Kh [n][d] fp16 copy + diag partials from fp16
            const int r = tid >> 2, dq = (tid & 3) * 16;
            const _Float16* kpp = Kp + (size_t)(ns + r) * 64 + dq;
            half8 h0 = *(const half8*)(kpp);
            half8 h1 = *(const half8*)(kpp + 8);
            *(half8*)&Kh[r * 68 + dq]     = h0;
            *(half8*)&Kh[r * 68 + dq + 8] = h1;
            diag4[r][tid & 3] = sumsq8(h0) + sumsq8(h1);
        }
        {   // stage Vt transposed [d][n]: thread d = tid&63, n-block of 16
            const int d = tid & 63, nb = (tid >> 6) * 16;
            _Float16 t[16];
#pragma unroll
            for (int i = 0; i < 16; i++)
                t[i] = Vp[(size_t)(ns + nb + i) * 64 + d];
            *(half8*)&Vt[d * 68 + nb]     = *(half8*)&t[0];
            *(half8*)&Vt[d * 68 + nb + 8] = *(half8*)&t[8];
        }
        __syncthreads();                              // A: Kh/Vt/diag4 ready (kpt free)
        // dd[n][j]: M=64 n, N=32 j (this wave), K=64
        floatx4 s4[4][2];
#pragma unroll
        for (int nt = 0; nt < 4; nt++)
#pragma unroll
            for (int jt = 0; jt < 2; jt++) s4[nt][jt] = (floatx4){0.f, 0.f, 0.f, 0.f};
#pragma unroll
        for (int ks = 0; ks < 2; ks++) {
            half8 af[4], bf[2];
#pragma unroll
            for (int nt = 0; nt < 4; nt++)
                af[nt] = *(half8*)&Kh[(nt * 16 + lm) * 68 + ks * 32 + lq * 8];
#pragma unroll
            for (int jt = 0; jt < 2; jt++)
                bf[jt] = *(half8*)&Ph[(wv * 32 + jt * 16 + lm) * 68 + ks * 32 + lq * 8];
#pragma unroll
            for (int nt = 0; nt < 4; nt++)
#pragma unroll
                for (int jt = 0; jt < 2; jt++)
                    s4[nt][jt] = __builtin_amdgcn_mfma_f32_16x16x32_f16(af[nt], bf[jt], s4[nt][jt], 0, 0, 0);
        }
        // exp in C-layout (col=j=lm, row=n=lq*4+reg), kp -> kpt [j][n] fp16
        float jsum[2] = {0.f, 0.f};
#pragma unroll
        for (int nt = 0; nt < 4; nt++) {
            float dg[4];
#pragma unroll
            for (int r = 0; r < 4; r++) {
                float4 d4 = *(float4*)diag4[nt * 16 + lq * 4 + r];   // broadcast read
                dg[r] = (d4.x + d4.y + d4.z + d4.w) * 0.0625f;
            }
#pragma unroll
            for (int jt = 0; jt < 2; jt++) {
                half4h kv;
#pragma unroll
                for (int r = 0; r < 4; r++) {
                    float v = RATIO * (expf(fminf(NORMC * s4[nt][jt][r] - dg[r] - kmax, 0.f)) + KEPS);
                    jsum[jt] += v;
                    kv[r] = (_Float16)v;
                }
                *(half4h*)&kpt[(wv * 32 + jt * 16 + lm) * 68 + nt * 16 + lq * 4] = kv;
            }
        }
#pragma unroll
        for (int jt = 0; jt < 2; jt++)
            atomicAdd(&ksum_s[wv * 32 + jt * 16 + lm], jsum[jt]);
        __syncthreads();                              // B: kpt ready
        // ctx[j][d] += kp^T @ V: M=32 j (this wave), N=64 d, K=64 n
#pragma unroll
        for (int ks = 0; ks < 2; ks++) {
            half8 af[2], bf[4];
#pragma unroll
            for (int jt = 0; jt < 2; jt++)
                af[jt] = *(half8*)&kpt[(wv * 32 + jt * 16 + lm) * 68 + ks * 32 + lq * 8];
#pragma unroll
            for (int dt = 0; dt < 4; dt++)
                bf[dt] = *(half8*)&Vt[(dt * 16 + lm) * 68 + ks * 32 + lq * 8];
#pragma unroll
            for (int jt = 0; jt < 2; jt++)
#pragma unroll
                for (int dt = 0; dt < 4; dt++)
                    acc[jt][dt] = __builtin_amdgcn_mfma_f32_16x16x32_f16(af[jt], bf[dt], acc[jt][dt], 0, 0, 0);
        }
        __syncthreads();                              // D: before next staging
    }
    // flush: C-layout col=d=lm, row=j=lq*4+reg
    float* __restrict__ ctxp = ws + O_CTX + bh * 16384;
#pragma unroll
    for (int jt = 0; jt < 2; jt++) {
#pragma unroll
        for (int dt = 0; dt < 4; dt++) {
            const int d = dt * 16 + lm;
#pragma unroll
            for (int r = 0; r < 4; r++) {
                const int j = jh * 128 + wv * 32 + jt * 16 + lq * 4 + r;
                atomicAdd(&ctxp[j * 64 + d], acc[jt][dt][r]);
            }
        }
    }
    if (tid < 128) atomicAdd(ws + O_KSUM + bh * 256 + jh * 128 + tid, ksum_s[tid]);
}

// ---------------- query-side: dd, rowmax, qp, attG = qp.ctx / (qp.ksum) (fp16 MFMA) ----
__launch_bounds__(256)
__global__ void k_qout(const float* __restrict__ proj, float* __restrict__ ws) {
    __shared__ _Float16 Qh[64 * 68];      // Q tile [n][d] fp16
    __shared__ _Float16 PhQp[256 * 68];   // proj [j][d] fp16; reused as qp [n][j] stride 260
    __shared__ _Float16 Ct[64 * 260];     // ctx^T [d][j] fp16
    __shared__ float ksum_s[256];
    __shared__ float diag4[64][4];
    __shared__ float diag_s[64];
    __shared__ unsigned rmax_s[64];
    __shared__ float denom_s[64];
    const int bh = blockIdx.x, b = bh / 6, h = bh % 6;
    const int n0 = blockIdx.y * 64;
    const _Float16* __restrict__ Qp = (const _Float16*)(ws + O_Q) + (size_t)(b * 8 + h) * 8192 * 64;
    const float* __restrict__ ctxp = ws + O_CTX + bh * 16384;
    _Float16* __restrict__ attG = (_Float16*)(ws + O_K);     // [16384][384] fp16
    const int tid = threadIdx.x;
    const int wv = tid >> 6, lane = tid & 63, lm = lane & 15, lq = lane >> 4;
    if (tid < 64) { rmax_s[tid] = 0u; denom_s[tid] = 0.f; }
    ksum_s[tid] = ws[O_KSUM + bh * 256 + tid];

    {   // stage Qh [n][d] fp16 copy + |Q|^2 partials from fp16
        const int r = tid >> 2, dq = (tid & 3) * 16;
        const _Float16* qpp = Qp + (size_t)(n0 + r) * 64 + dq;
        half8 h0 = *(const half8*)(qpp);
        half8 h1 = *(const half8*)(qpp + 8);
        *(half8*)&Qh[r * 68 + dq]     = h0;
        *(half8*)&Qh[r * 68 + dq + 8] = h1;
        diag4[r][tid & 3] = sumsq8(h0) + sumsq8(h1);
    }
    {   // stage Ph [j][d] fp16 (256 rows, 2 passes, 2 threads/row)
#pragma unroll
        for (int ph = 0; ph < 2; ph++) {
            const int r = ph * 128 + (tid >> 1), doff = (tid & 1) * 32;
            const float* pp = proj + r * 64 + doff;
#pragma unroll
            for (int q = 0; q < 4; q++) {
                float4 v0 = *(const float4*)(pp + 8 * q);
                float4 v1 = *(const float4*)(pp + 8 * q + 4);
                half8 hv = {(_Float16)v0.x, (_Float16)v0.y, (_Float16)v0.z, (_Float16)v0.w,
                            (_Float16)v1.x, (_Float16)v1.y, (_Float16)v1.z, (_Float16)v1.w};
                *(half8*)&PhQp[r * 68 + doff + 8 * q] = hv;
            }
        }
    }
    {   // stage Ct [d][j] fp16 (transpose of ctx [j][d]; lane sweeps d -> coalesced)
        const int d = tid & 63;
#pragma unroll
        for (int jb = 0; jb < 4; jb++) {
            const int js = jb * 64 + (tid >> 6) * 16;
            _Float16 t[16];
#pragma unroll
            for (int i = 0; i < 16; i++)
                t[i] = (_Float16)ctxp[(js + i) * 64 + d];
            *(half8*)&Ct[d * 260 + js]     = *(half8*)&t[0];
            *(half8*)&Ct[d * 260 + js + 8] = *(half8*)&t[8];
        }
    }
    __syncthreads();
    if (tid < 64) {
        float4 d4 = *(float4*)diag4[tid];
        diag_s[tid] = (d4.x + d4.y + d4.z + d4.w) * 0.0625f;
    }
    // dd = Q . proj^T : M=64 n, N=64 j (this wave's slice), K=64
    floatx4 s4[4][4];
#pragma unroll
    for (int nt = 0; nt < 4; nt++)
#pragma unroll
        for (int jt = 0; jt < 4; jt++) s4[nt][jt] = (floatx4){0.f, 0.f, 0.f, 0.f};
#pragma unroll
    for (int ks = 0; ks < 2; ks++) {
        half8 af[4], bf[4];
#pragma unroll
        for (int nt = 0; nt < 4; nt++)
            af[nt] = *(half8*)&Qh[(nt * 16 + lm) * 68 + ks * 32 + lq * 8];
#pragma unroll
        for (int jt = 0; jt < 4; jt++)
            bf[jt] = *(half8*)&PhQp[(wv * 64 + jt * 16 + lm) * 68 + ks * 32 + lq * 8];
#pragma unroll
        for (int nt = 0; nt < 4; nt++)
#pragma unroll
            for (int jt = 0; jt < 4; jt++)
                s4[nt][jt] = __builtin_amdgcn_mfma_f32_16x16x32_f16(af[nt], bf[jt], s4[nt][jt], 0, 0, 0);
    }
    // row maxima over this wave's 64 j -> cross-wave via LDS atomicMax
#pragma unroll
    for (int nt = 0; nt < 4; nt++) {
#pragma unroll
        for (int rr = 0; rr < 4; rr++) {
            float m0 = fmaxf(fmaxf(s4[nt][0][rr], s4[nt][1][rr]),
                             fmaxf(s4[nt][2][rr], s4[nt][3][rr]));
            m0 = fmaxf(m0, __shfl_xor(m0, 1, 64));
            m0 = fmaxf(m0, __shfl_xor(m0, 2, 64));
            m0 = fmaxf(m0, __shfl_xor(m0, 4, 64));
            m0 = fmaxf(m0, __shfl_xor(m0, 8, 64));
            if (lm == 0) atomicMax(&rmax_s[nt * 16 + lq * 4 + rr], encf(m0 * NORMC));
        }
    }
    __syncthreads();     // rmax_s/diag_s ready; all Ph reads done (qp may overwrite)
    // qp = RATIO*(exp(NORMC*dd - diag - rmax)+KEPS) -> fp16 LDS; denom into s4
#pragma unroll
    for (int nt = 0; nt < 4; nt++) {
#pragma unroll
        for (int rr = 0; rr < 4; rr++) {
            const int row = nt * 16 + lq * 4 + rr;
            const float rmx = decf(rmax_s[row]);
            const float dgv = diag_s[row];
#pragma unroll
            for (int jt = 0; jt < 4; jt++) {
                const int j = wv * 64 + jt * 16 + lm;
                float v = RATIO * (expf(fminf(NORMC * s4[nt][jt][rr] - dgv - rmx, 0.f)) + KEPS);
                PhQp[row * 260 + j] = (_Float16)v;
                s4[nt][jt][rr] = v * ksum_s[j];
            }
            float ds = s4[nt][0][rr] + s4[nt][1][rr] + s4[nt][2][rr] + s4[nt][3][rr];
            ds += __shfl_xor(ds, 1, 64);
            ds += __shfl_xor(ds, 2, 64);
            ds += __shfl_xor(ds, 4, 64);
            ds += __shfl_xor(ds, 8, 64);
            if (lm == 0) atomicAdd(&denom_s[row], ds);
        }
    }
    __syncthreads();     // qp + denom ready
    // attG = qp . ctx : M=64 n, N=16 d (this wave's slice), K=256 j
    floatx4 acc2[4];
#pragma unroll
    for (int nt = 0; nt < 4; nt++) acc2[nt] = (floatx4){0.f, 0.f, 0.f, 0.f};
#pragma unroll
    for (int ks = 0; ks < 8; ks++) {
        half8 bfv = *(half8*)&Ct[(wv * 16 + lm) * 260 + ks * 32 + lq * 8];
#pragma unroll
        for (int nt = 0; nt < 4; nt++) {
            half8 af = *(half8*)&PhQp[(nt * 16 + lm) * 260 + ks * 32 + lq * 8];
            acc2[nt] = __builtin_amdgcn_mfma_f32_16x16x32_f16(af, bfv, acc2[nt], 0, 0, 0);
        }
    }
#pragma unroll
    for (int nt = 0; nt < 4; nt++) {
#pragma unroll
        for (int rr = 0; rr < 4; rr++) {
            const int row = nt * 16 + lq * 4 + rr;
            const float inv = 1.0f / fmaxf(denom_s[row], 1e-30f);
            attG[((size_t)(b * 8192 + n0 + row)) * 384 + h * 64 + wv * 16 + lm] =
                (_Float16)(acc2[nt][rr] * inv);
        }
    }
}

// ---------------- local windowed attention w/ RoPE, heads 6..7 (fp16 MFMA) ----------------
__launch_bounds__(256)
__global__ void k_local(float* __restrict__ ws) {
    __shared__ _Float16 Qh[64 * 68];     // RoPE'd Q [q][d]
    __shared__ _Float16 Kh[64 * 68];     // RoPE'd K chunk [k][d]
    __shared__ _Float16 Vt[64 * 68];     // V chunk transposed [d][k]
    __shared__ _Float16 pT[64 * 68];     // P [q][k] fp16
    const int bhp = blockIdx.x, b = bhp >> 1, lh = bhp & 1, h = 6 + lh;
    const int tile = blockIdx.y;                 // 0..127 (64-query tiles)
    const int w = tile >> 2;                     // window index
    const int q0 = tile * 64;
    const _Float16* __restrict__ Qb = (const _Float16*)(ws + O_Q) + (size_t)(b * 8 + h) * 8192 * 64;
    const _Float16* __restrict__ Kb = (const _Float16*)(ws + O_K) + (size_t)(b * 8 + h) * 8192 * 64;
    const _Float16* __restrict__ Vb = (const _Float16*)(ws + O_V) + (size_t)(b * 8 + h) * 8192 * 64;
    const float* __restrict__ cosT = ws + O_COS;
    const float* __restrict__ sinT = ws + O_SIN;
    const int tid = threadIdx.x;
    const int wv = tid >> 6, lane = tid & 63, lm = lane & 15, lq = lane >> 4;
    // staging mapping: 4 threads per row, 16 dims each
    const int row = tid >> 2, dq = (tid & 3) * 16;
    const int e = dq & 31;
    const int comp = (dq < 32) ? dq + 32 : dq - 32;
    const float sgn = (dq < 32) ? -1.f : 1.f;

    {   // stage Q tile with RoPE -> fp16 [q][d]
        const int qpos = q0 + row;
        const _Float16* bp = Qb + (size_t)qpos * 64;
        const float* cp = cosT + qpos * 32 + e;
        const float* sp = sinT + qpos * 32 + e;
        _Float16 t[16];
#pragma unroll
        for (int w4 = 0; w4 < 4; w4++) {
            float4 c4 = *(const float4*)(cp + 4 * w4);
            float4 s4v = *(const float4*)(sp + 4 * w4);
            half4h xah = *(const half4h*)(bp + dq + 4 * w4);
            half4h xbh = *(const half4h*)(bp + comp + 4 * w4);
            t[4*w4+0] = (_Float16)fmaf(sgn * (float)xbh[0], s4v.x, (float)xah[0] * c4.x);
            t[4*w4+1] = (_Float16)fmaf(sgn * (float)xbh[1], s4v.y, (float)xah[1] * c4.y);
            t[4*w4+2] = (_Float16)fmaf(sgn * (float)xbh[2], s4v.z, (float)xah[2] * c4.z);
            t[4*w4+3] = (_Float16)fmaf(sgn * (float)xbh[3], s4v.w, (float)xah[3] * c4.w);
        }
        *(half8*)&Qh[row * 68 + dq]     = *(half8*)&t[0];
        *(half8*)&Qh[row * 68 + dq + 8] = *(half8*)&t[8];
    }
    floatx4 O[4];                    // [df] rows=q (lq*4+r), cols=d (df*16+lm)
#pragma unroll
    for (int df = 0; df < 4; df++) O[df] = (floatx4){0.f, 0.f, 0.f, 0.f};
    float m_run[4] = {-1e30f, -1e30f, -1e30f, -1e30f};
    float l_run[4] = {0.f, 0.f, 0.f, 0.f};

    for (int c = 0; c < 12; c++) {
        const int kp0 = (w - 1) * 256 + c * 64;
        if (kp0 < 0 || kp0 >= 8192) continue;    // look_around pad (block-uniform)
        __syncthreads();             // prior chunk's Vt/pT reads done
        {   // stage K chunk (RoPE) fp16 [k][d]
            const int kpos = kp0 + row;
            const _Float16* bp = Kb + (size_t)kpos * 64;
            const float* cp = cosT + kpos * 32 + e;
            const float* sp = sinT + kpos * 32 + e;
            _Float16 t[16];
#pragma unroll
            for (int w4 = 0; w4 < 4; w4++) {
                float4 c4 = *(const float4*)(cp + 4 * w4);
                float4 s4v = *(const float4*)(sp + 4 * w4);
                half4h xah = *(const half4h*)(bp + dq + 4 * w4);
                half4h xbh = *(const half4h*)(bp + comp + 4 * w4);
                t[4*w4+0] = (_Float16)fmaf(sgn * (float)xbh[0], s4v.x, (float)xah[0] * c4.x);
                t[4*w4+1] = (_Float16)fmaf(sgn * (float)xbh[1], s4v.y, (float)xah[1] * c4.y);
                t[4*w4+2] = (_Float16)fmaf(sgn * (float)xbh[2], s4v.z, (float)xah[2] * c4.z);
                t[4*w4+3] = (_Float16)fmaf(sgn * (float)xbh[3], s4v.w, (float)xah[3] * c4.w);
            }
            *(half8*)&Kh[row * 68 + dq]     = *(half8*)&t[0];
            *(half8*)&Kh[row * 68 + dq + 8] = *(half8*)&t[8];
        }
        {   // stage V transposed fp16 [d][k]: lane d, wave's 16-row block
            const int d = lane, nb = wv * 16;
            _Float16 t[16];
#pragma unroll
            for (int i = 0; i < 16; i++)
                t[i] = Vb[(size_t)(kp0 + nb + i) * 64 + d];
            *(half8*)&Vt[d * 68 + nb]     = *(half8*)&t[0];
            *(half8*)&Vt[d * 68 + nb + 8] = *(half8*)&t[8];
        }
        __syncthreads();             // Kh/Vt ready
        // QK^T: M=16 q (this wave), N=64 k, K=64 d
        floatx4 s4[4];
#pragma unroll
        for (int nf = 0; nf < 4; nf++) s4[nf] = (floatx4){0.f, 0.f, 0.f, 0.f};
#pragma unroll
        for (int ks = 0; ks < 2; ks++) {
            half8 aq = *(half8*)&Qh[(wv * 16 + lm) * 68 + ks * 32 + lq * 8];
            half8 bf[4];
#pragma unroll
            for (int nf = 0; nf < 4; nf++)
                bf[nf] = *(half8*)&Kh[(nf * 16 + lm) * 68 + ks * 32 + lq * 8];
#pragma unroll
            for (int nf = 0; nf < 4; nf++)
                s4[nf] = __builtin_amdgcn_mfma_f32_16x16x32_f16(aq, bf[nf], s4[nf], 0, 0, 0);
        }
        // online softmax in registers; scale = 64^-0.5 = 0.125
        float p[4][4];
#pragma unroll
        for (int r = 0; r < 4; r++) {
            float m0 = fmaxf(fmaxf(s4[0][r], s4[1][r]), fmaxf(s4[2][r], s4[3][r]));
            m0 = fmaxf(m0, __shfl_xor(m0, 1, 64));
            m0 = fmaxf(m0, __shfl_xor(m0, 2, 64));
            m0 = fmaxf(m0, __shfl_xor(m0, 4, 64));
            m0 = fmaxf(m0, __shfl_xor(m0, 8, 64));
            const float mn = fmaxf(m_run[r], m0 * 0.125f);
            const float al = expf(m_run[r] - mn);
            m_run[r] = mn;
            float rs = 0.f;
#pragma unroll
            for (int nf = 0; nf < 4; nf++) {
                float pv = expf(fmaf(s4[nf][r], 0.125f, -mn));
                p[nf][r] = pv;
                rs += pv;
            }
            l_run[r] = l_run[r] * al + rs;   // per-lane partial (4 of 64 cols)
#pragma unroll
            for (int df = 0; df < 4; df++) O[df][r] *= al;
        }
        // P -> LDS fp16 [q][k] (wave-private rows; conflict-free: lq groups 8 banks apart)
#pragma unroll
        for (int nf = 0; nf < 4; nf++)
#pragma unroll
            for (int r = 0; r < 4; r++)
                pT[(wv * 16 + lq * 4 + r) * 68 + nf * 16 + lm] = (_Float16)p[nf][r];
        __syncthreads();             // pT visible
        // PV: M=16 q (this wave), N=64 d, K=64 k
#pragma unroll
        for (int ks = 0; ks < 2; ks++) {
            half8 ap = *(half8*)&pT[(wv * 16 + lm) * 68 + ks * 32 + lq * 8];
            half8 bf[4];
#pragma unroll
            for (int df = 0; df < 4; df++)
                bf[df] = *(half8*)&Vt[(df * 16 + lm) * 68 + ks * 32 + lq * 8];
#pragma unroll
            for (int df = 0; df < 4; df++)
                O[df] = __builtin_amdgcn_mfma_f32_16x16x32_f16(ap, bf[df], O[df], 0, 0, 0);
        }
    }
    // final l reduce over lm, normalize, store
#pragma unroll
    for (int r = 0; r < 4; r++) {
        l_run[r] += __shfl_xor(l_run[r], 1, 64);
        l_run[r] += __shfl_xor(l_run[r], 2, 64);
        l_run[r] += __shfl_xor(l_run[r], 4, 64);
        l_run[r] += __shfl_xor(l_run[r], 8, 64);
        l_run[r] = 1.f / fmaxf(l_run[r], 1e-30f);
    }
    _Float16* __restrict__ attL = (_Float16*)(ws + O_ATTL);   // [2][2][8192][64] fp16
#pragma unroll
    for (int df = 0; df < 4; df++) {
#pragma unroll
        for (int r = 0; r < 4; r++) {
            const int q = q0 + wv * 16 + lq * 4 + r;
            attL[((size_t)(b * 2 + lh) * 8192 + q) * 64 + df * 16 + lm] =
                (_Float16)(O[df][r] * l_run[r]);
        }
    }
}

// ---------------- output projection + bias (fp16 MFMA) ----------------
__launch_bounds__(256)
__global__ void k_out(const float* __restrict__ bo,
                      const float* __restrict__ ws,
                      float* __restrict__ out) {
    __shared__ _Float16 Ah[128 * 72];
    __shared__ _Float16 Bh[128 * 72];
    const _Float16* __restrict__ attG = (const _Float16*)(ws + O_K);      // [16384][384]
    const _Float16* __restrict__ attL = (const _Float16*)(ws + O_ATTL);   // [4][8192][64]
    const _Float16* __restrict__ WoT = (const _Float16*)(ws + O_CTX);     // [512][512] [n][k]
    const int r0 = blockIdx.x * 128, c0 = blockIdx.y * 128;
    const int tid = threadIdx.x;
    const int wv = tid >> 6, lane = tid & 63, lm = lane & 15, lq = lane >> 4;
    const int srow = tid >> 1, skoff = (tid & 1) * 32;
    floatx4 acc[2][8];
#pragma unroll
    for (int m = 0; m < 2; m++)
#pragma unroll
        for (int n = 0; n < 8; n++) acc[m][n] = (floatx4){0.f, 0.f, 0.f, 0.f};

    for (int c = 0; c < 8; c++) {
        const int k0 = c * 64;
        {   // stage A: att fp16 direct copy (32-seg never straddles the 384 boundary)
            const int row = r0 + srow;
            const int kk = k0 + skoff;
            const _Float16* ap;
            if (kk < 384) {
                ap = attG + (size_t)row * 384 + kk;
            } else {
                const int bb = row >> 13, nn = row & 8191;
                const int kr = kk - 384;
                ap = attL + ((size_t)(bb * 2 + (kr >> 6)) * 8192 + nn) * 64 + (kr & 63);
            }
#pragma unroll
            for (int q = 0; q < 4; q++)
                *(uint4*)&Ah[srow * 72 + skoff + 8 * q] = *(const uint4*)(ap + 8 * q);
        }
        {   // stage B: WoT fp16 direct copy
            const _Float16* bp = WoT + (size_t)(c0 + srow) * 512 + k0 + skoff;
#pragma unroll
            for (int q = 0; q < 4; q++)
                *(uint4*)&Bh[srow * 72 + skoff + 8 * q] = *(const uint4*)(bp + 8 * q);
        }
        __syncthreads();
#pragma unroll
        for (int ks = 0; ks < 2; ks++) {
            half8 af[2], bf[8];
            af[0] = *(half8*)&Ah[(wv * 32 + lm) * 72 + ks * 32 + lq * 8];
            af[1] = *(half8*)&Ah[(wv * 32 + 16 + lm) * 72 + ks * 32 + lq * 8];
#pragma unroll
            for (int n = 0; n < 8; n++)
                bf[n] = *(half8*)&Bh[(n * 16 + lm) * 72 + ks * 32 + lq * 8];
#pragma unroll
            for (int m = 0; m < 2; m++)
#pragma unroll
                for (int n = 0; n < 8; n++)
                    acc[m][n] = __builtin_amdgcn_mfma_f32_16x16x32_f16(af[m], bf[n], acc[m][n], 0, 0, 0);
        }
        __syncthreads();
    }
#pragma unroll
    for (int n = 0; n < 8; n++) {
        const int col = c0 + n * 16 + lm;
        const float bias = bo[col];
#pragma unroll
        for (int m = 0; m < 2; m++) {
            const int rbase = r0 + wv * 32 + m * 16 + lq * 4;
#pragma unroll
            for (int j = 0; j < 4; j++)
                out[(size_t)(rbase + j) * 512 + col] = acc[m][n][j] + bias;
        }
    }
}

extern "C" void kernel_launch(void* const* d_in, const int* in_sizes, int n_in,
                              void* d_out, int out_size, void* d_ws, size_t ws_size,
                              hipStream_t stream) {
    const float* x    = (const float*)d_in[0];
    const float* Wq   = (const float*)d_in[1];
    const float* Wk   = (const float*)d_in[2];
    const float* Wv   = (const float*)d_in[3];
    const float* Wo   = (const float*)d_in[4];
    const float* bo   = (const float*)d_in[5];
    const float* proj = (const float*)d_in[6];
    float* ws = (float*)d_ws;
    float* out = (float*)d_out;

    hipMemsetAsync(d_ws, 0, (size_t)O_ZEND * 4, stream);                 // kmax/ksum/ctx
    hipLaunchKernelGGL(k_rope,   dim3(1024), dim3(256), 0, stream, ws);
    hipLaunchKernelGGL(k_half_x, dim3(4096), dim3(256), 0, stream, x, ws);
    hipLaunchKernelGGL(k_half_w, dim3(8, 8, 3), dim3(256), 0, stream, Wq, Wk, Wv, ws);
    hipLaunchKernelGGL(k_qkv,    dim3(128, 4, 3), dim3(256), 0, stream, ws);
    hipLaunchKernelGGL(k_kmax,   dim3(12, 128), dim3(256), 0, stream, proj, ws);
    hipLaunchKernelGGL(k_kctx,   dim3(12, 32, 2), dim3(256), 0, stream, proj, ws);
    hipLaunchKernelGGL(k_local,  dim3(4, 128), dim3(256), 0, stream, ws);   // before k_qout!
    hipLaunchKernelGGL(k_qout,   dim3(12, 128), dim3(256), 0, stream, proj, ws);
    hipLaunchKernelGGL(k_half_wo, dim3(8, 8), dim3(256), 0, stream, Wo, ws); // ctx dead -> WoT
    hipLaunchKernelGGL(k_out,    dim3(128, 4), dim3(256), 0, stream, bo, ws, out);
}

// Round 5
// 324.761 us; speedup vs baseline: 2.0527x; 1.0343x over previous
//
#include <hip/hip_runtime.h>

// ---------------- constants ----------------
#define NTOK 8192
#define NORMC 0.35355339059327373f   // 64^-0.25
#define RATIO 0.0625f                // 256^-0.5
#define KEPS  1e-4f

// ws offsets in 4-byte elements
#define O_KMAX 0                      // 12 x u32 (encoded max)
#define O_KSUM 64                     // 12*256 f32
#define O_CTX  3136                   // 12*256*64 f32; after k_ctxt reused as WoT fp16 [512][512]
#define O_ZEND 199744                 // zeroed region end
#define O_COS  199744                 // 8192*32
#define O_SIN  461888                 // 8192*32
#define O_Q    724032                 // fp16 [2][8][8192][64]
#define O_K    9112640                // fp16 K; later reused as attG fp16 [16384][384]
#define O_V    17501248               // fp16 V
#define O_ATTL 25889856               // fp16 [2][2][8192][64] (ends 26938432)
// O_WH: fp16 W^T [3][512][512] (dead after k_qkv; overlapped by attL later)
#define O_WH   25889856
// O_XH: fp16 x [16384][512] (dead after k_qkv)
#define O_XH   26283072
// O_PH: fp16 proj [256][64] (8192 f32), after attL end; written after k_qkv
#define O_PH   26938432
// O_CTXT: fp16 ctxT [12][64][256] (98304 f32); written after k_kctx
#define O_CTXT 26946624
// end of our use: 27044928

typedef _Float16 half8 __attribute__((ext_vector_type(8)));
typedef _Float16 half4h __attribute__((ext_vector_type(4)));
typedef float floatx4 __attribute__((ext_vector_type(4)));

__device__ __forceinline__ unsigned encf(float f) {
    unsigned u = __float_as_uint(f);
    return (u & 0x80000000u) ? ~u : (u | 0x80000000u);
}
__device__ __forceinline__ float decf(unsigned u) {
    return (u & 0x80000000u) ? __uint_as_float(u & 0x7fffffffu) : __uint_as_float(~u);
}
__device__ __forceinline__ float sumsq8(half8 h) {
    float s = 0.f;
#pragma unroll
    for (int i = 0; i < 8; i++) { float v = (float)h[i]; s = fmaf(v, v, s); }
    return s;
}

// ---------------- RoPE tables (double precision angles) ----------------
__global__ void k_rope(float* __restrict__ ws) {
    int idx = blockIdx.x * 256 + threadIdx.x;      // 8192*32
    int t = idx >> 5, i = idx & 31;
    double invf = pow(10000.0, -(double)(2 * i) / 64.0);
    double ang = (double)t * invf;
    ws[O_COS + idx] = (float)cos(ang);
    ws[O_SIN + idx] = (float)sin(ang);
}

// ---------------- x -> fp16 ----------------
__launch_bounds__(256)
__global__ void k_half_x(const float* __restrict__ x, float* __restrict__ ws) {
    const int idx = blockIdx.x * 256 + threadIdx.x;   // *8 elements
    const float* p = x + (size_t)idx * 8;
    float4 a = *(const float4*)p, b = *(const float4*)(p + 4);
    half8 h = {(_Float16)a.x, (_Float16)a.y, (_Float16)a.z, (_Float16)a.w,
               (_Float16)b.x, (_Float16)b.y, (_Float16)b.z, (_Float16)b.w};
    *(half8*)((_Float16*)(ws + O_XH) + (size_t)idx * 8) = h;
}

// ---------------- proj -> fp16 [256][64] ----------------
__launch_bounds__(256)
__global__ void k_half_p(const float* __restrict__ proj, float* __restrict__ ws) {
    const int idx = blockIdx.x * 256 + threadIdx.x;   // 2048 threads * 8 = 16384
    const float* p = proj + (size_t)idx * 8;
    float4 a = *(const float4*)p, b = *(const float4*)(p + 4);
    half8 h = {(_Float16)a.x, (_Float16)a.y, (_Float16)a.z, (_Float16)a.w,
               (_Float16)b.x, (_Float16)b.y, (_Float16)b.z, (_Float16)b.w};
    *(half8*)((_Float16*)(ws + O_PH) + (size_t)idx * 8) = h;
}

// ---------------- ctx f32 [12][256][64] -> ctxT fp16 [12][64][256] ----------------
__launch_bounds__(256)
__global__ void k_ctxt(float* __restrict__ ws) {
    __shared__ float T[64][65];
    const int bh = blockIdx.x, j0 = blockIdx.y * 64;
    const float* __restrict__ ctxp = ws + O_CTX + bh * 16384;
    _Float16* __restrict__ ct = (_Float16*)(ws + O_CTXT) + bh * 16384;
    const int lx = threadIdx.x & 63, ly = threadIdx.x >> 6;
#pragma unroll
    for (int i = 0; i < 16; i++) {
        const int jl = ly * 16 + i;
        T[jl][lx] = ctxp[(j0 + jl) * 64 + lx];
    }
    __syncthreads();
#pragma unroll
    for (int i = 0; i < 16; i++) {
        const int d = ly * 16 + i;
        ct[d * 256 + j0 + lx] = (_Float16)T[lx][d];
    }
}

// ---------------- W -> fp16, transposed to [n][k] ----------------
__launch_bounds__(256)
__global__ void k_half_w(const float* __restrict__ Wq,
                         const float* __restrict__ Wk,
                         const float* __restrict__ Wv,
                         float* __restrict__ ws) {
    __shared__ float T[64][65];
    const int z = blockIdx.z;
    const float* __restrict__ W = (z == 0) ? Wq : ((z == 1) ? Wk : Wv);
    _Float16* __restrict__ Wt = (_Float16*)(ws + O_WH) + (size_t)z * 262144;
    const int k0 = blockIdx.x * 64, n0 = blockIdx.y * 64;
    const int lx = threadIdx.x & 63, ly = threadIdx.x >> 6;   // ly in 0..3
#pragma unroll
    for (int i = 0; i < 16; i++) {
        const int kk = ly * 16 + i;
        T[lx][kk] = W[(k0 + kk) * 512 + n0 + lx];    // T[n-n0][k-k0]
    }
    __syncthreads();
#pragma unroll
    for (int i = 0; i < 16; i++) {
        const int nn = ly * 16 + i;
        Wt[(n0 + nn) * 512 + k0 + lx] = (_Float16)T[nn][lx];
    }
}

// ---------------- Wo -> fp16 transposed [n][k], into dead ctx region ----------------
__launch_bounds__(256)
__global__ void k_half_wo(const float* __restrict__ Wo, float* __restrict__ ws) {
    __shared__ float T[64][65];
    _Float16* __restrict__ Wt = (_Float16*)(ws + O_CTX);
    const int k0 = blockIdx.x * 64, n0 = blockIdx.y * 64;
    const int lx = threadIdx.x & 63, ly = threadIdx.x >> 6;
#pragma unroll
    for (int i = 0; i < 16; i++) {
        const int kk = ly * 16 + i;
        T[lx][kk] = Wo[(k0 + kk) * 512 + n0 + lx];
    }
    __syncthreads();
#pragma unroll
    for (int i = 0; i < 16; i++) {
        const int nn = ly * 16 + i;
        Wt[(n0 + nn) * 512 + k0 + lx] = (_Float16)T[nn][lx];
    }
}

// ---------------- QKV projection via fp16 MFMA (fp16 in, fp16 out) ----------------
__launch_bounds__(256)
__global__ void k_qkv(float* __restrict__ ws) {
    __shared__ _Float16 Ah[128 * 72];
    __shared__ _Float16 Bh[128 * 72];
    const int z = blockIdx.z;
    const _Float16* __restrict__ xh = (const _Float16*)(ws + O_XH);
    const _Float16* __restrict__ Wt = (const _Float16*)(ws + O_WH) + (size_t)z * 262144;
    _Float16* __restrict__ out = (_Float16*)(ws + ((z == 0) ? O_Q : ((z == 1) ? O_K : O_V)));
    const int r0 = blockIdx.x * 128, c0 = blockIdx.y * 128;
    const int tid = threadIdx.x;
    const int wv = tid >> 6, lane = tid & 63, lm = lane & 15, lq = lane >> 4;
    const int srow = tid >> 1, skoff = (tid & 1) * 32;
    floatx4 acc[2][8];
#pragma unroll
    for (int m = 0; m < 2; m++)
#pragma unroll
        for (int n = 0; n < 8; n++) acc[m][n] = (floatx4){0.f, 0.f, 0.f, 0.f};

    for (int c = 0; c < 8; c++) {
        const int k0 = c * 64;
        {   // stage A: x fp16 direct copy
            const _Float16* ap = xh + (size_t)(r0 + srow) * 512 + k0 + skoff;
#pragma unroll
            for (int q = 0; q < 4; q++)
                *(uint4*)&Ah[srow * 72 + skoff + 8 * q] = *(const uint4*)(ap + 8 * q);
        }
        {   // stage B: fp16 W^T direct copy
            const _Float16* bp = Wt + (size_t)(c0 + srow) * 512 + k0 + skoff;
#pragma unroll
            for (int q = 0; q < 4; q++)
                *(uint4*)&Bh[srow * 72 + skoff + 8 * q] = *(const uint4*)(bp + 8 * q);
        }
        __syncthreads();
#pragma unroll
        for (int ks = 0; ks < 2; ks++) {
            half8 af[2], bf[8];
            af[0] = *(half8*)&Ah[(wv * 32 + lm) * 72 + ks * 32 + lq * 8];
            af[1] = *(half8*)&Ah[(wv * 32 + 16 + lm) * 72 + ks * 32 + lq * 8];
#pragma unroll
            for (int n = 0; n < 8; n++)
                bf[n] = *(half8*)&Bh[(n * 16 + lm) * 72 + ks * 32 + lq * 8];
#pragma unroll
            for (int m = 0; m < 2; m++)
#pragma unroll
                for (int n = 0; n < 8; n++)
                    acc[m][n] = __builtin_amdgcn_mfma_f32_16x16x32_f16(af[m], bf[n], acc[m][n], 0, 0, 0);
        }
        __syncthreads();
    }
    const int bi = r0 >> 13;
#pragma unroll
    for (int n = 0; n < 8; n++) {
        const int col = c0 + n * 16 + lm;
        const int h = col >> 6, d = col & 63;
#pragma unroll
        for (int m = 0; m < 2; m++) {
            const int rbase = r0 + wv * 32 + m * 16 + lq * 4;
#pragma unroll
            for (int j = 0; j < 4; j++) {
                const int ng = (rbase + j) & 8191;
                out[((size_t)(bi * 8 + h) * 8192 + ng) * 64 + d] = (_Float16)acc[m][n][j];
            }
        }
    }
}

// ---------------- key-side global max of dd = norm*(K.projT) (fp16 MFMA) ----------------
// B-fragments read directly from projh (L2-resident, no per-block restage).
__launch_bounds__(256)
__global__ void k_kmax(float* __restrict__ ws) {
    __shared__ _Float16 Kh[64 * 68];      // K tile [n][d] fp16
    __shared__ unsigned bmax;
    const int bh = blockIdx.x, b = bh / 6, h = bh % 6;
    const _Float16* __restrict__ Kp = (const _Float16*)(ws + O_K) + (size_t)(b * 8 + h) * 8192 * 64;
    const _Float16* __restrict__ projh = (const _Float16*)(ws + O_PH);
    const int n0 = blockIdx.y * 64;
    const int tid = threadIdx.x;
    const int wv = tid >> 6, lane = tid & 63, lm = lane & 15, lq = lane >> 4;
    if (tid == 0) bmax = 0u;
    {   // stage Kh [n][d] fp16 direct copy
        const int r = tid >> 2, dq = (tid & 3) * 16;
        const _Float16* kpp = Kp + (size_t)(n0 + r) * 64 + dq;
        *(uint4*)&Kh[r * 68 + dq]     = *(const uint4*)(kpp);
        *(uint4*)&Kh[r * 68 + dq + 8] = *(const uint4*)(kpp + 8);
    }
    __syncthreads();
    // dd[n][j]: M=64 n, N=64 j (this wave's slice), K=64
    floatx4 s4[4][4];
#pragma unroll
    for (int nt = 0; nt < 4; nt++)
#pragma unroll
        for (int jt = 0; jt < 4; jt++) s4[nt][jt] = (floatx4){0.f, 0.f, 0.f, 0.f};
#pragma unroll
    for (int ks = 0; ks < 2; ks++) {
        half8 af[4], bf[4];
#pragma unroll
        for (int nt = 0; nt < 4; nt++)
            af[nt] = *(half8*)&Kh[(nt * 16 + lm) * 68 + ks * 32 + lq * 8];
#pragma unroll
        for (int jt = 0; jt < 4; jt++)
            bf[jt] = *(const half8*)(projh + (wv * 64 + jt * 16 + lm) * 64 + ks * 32 + lq * 8);
#pragma unroll
        for (int nt = 0; nt < 4; nt++)
#pragma unroll
            for (int jt = 0; jt < 4; jt++)
                s4[nt][jt] = __builtin_amdgcn_mfma_f32_16x16x32_f16(af[nt], bf[jt], s4[nt][jt], 0, 0, 0);
    }
    float m = -1e30f;
#pragma unroll
    for (int nt = 0; nt < 4; nt++)
#pragma unroll
        for (int jt = 0; jt < 4; jt++)
#pragma unroll
            for (int r = 0; r < 4; r++) m = fmaxf(m, s4[nt][jt][r]);
    m = fmaxf(m, __shfl_xor(m, 1, 64));
    m = fmaxf(m, __shfl_xor(m, 2, 64));
    m = fmaxf(m, __shfl_xor(m, 4, 64));
    m = fmaxf(m, __shfl_xor(m, 8, 64));
    m = fmaxf(m, __shfl_xor(m, 16, 64));
    m = fmaxf(m, __shfl_xor(m, 32, 64));
    if (lane == 0) atomicMax(&bmax, encf(m * NORMC));
    __syncthreads();
    if (tid == 0) atomicMax((unsigned*)ws + O_KMAX + bh, bmax);
}

// ---------------- key-side: kp, k_sum, ctx = kp^T @ V  (fp16 MFMA) ----------------
// Ph dropped (direct projh reads) -> LDS ~36 KB -> 4 blocks/CU.
__launch_bounds__(256)
__global__ void k_kctx(float* __restrict__ ws) {
    __shared__ _Float16 Kh[64 * 68];     // K sub [n][d]
    __shared__ _Float16 Vt[64 * 68];     // V sub transposed [d][n]
    __shared__ _Float16 kpt[128 * 68];   // kp transposed [j][n]
    __shared__ float diag4[64][4];       // per-row |K|^2 partials (race-free)
    __shared__ float ksum_s[128];
    const int bh = blockIdx.x, b = bh / 6, h = bh % 6;
    const int n0 = blockIdx.y * 256;
    const int jh = blockIdx.z;
    const _Float16* __restrict__ Kp = (const _Float16*)(ws + O_K) + (size_t)(b * 8 + h) * 8192 * 64;
    const _Float16* __restrict__ Vp = (const _Float16*)(ws + O_V) + (size_t)(b * 8 + h) * 8192 * 64;
    const _Float16* __restrict__ projh = (const _Float16*)(ws + O_PH);
    const float kmax = decf(((const unsigned*)ws)[O_KMAX + bh]);
    const int tid = threadIdx.x;
    const int wv = tid >> 6, lane = tid & 63, lm = lane & 15, lq = lane >> 4;
    if (tid < 128) ksum_s[tid] = 0.f;

    floatx4 acc[2][4];   // ctx tiles [jt][dt]
#pragma unroll
    for (int jt = 0; jt < 2; jt++)
#pragma unroll
        for (int dt = 0; dt < 4; dt++) acc[jt][dt] = (floatx4){0.f, 0.f, 0.f, 0.f};

    for (int nc = 0; nc < 4; nc++) {
        const int ns = n0 + nc * 64;
        {   // stage Kh [n][d] fp16 copy + diag partials from fp16
            const int r = tid >> 2, dq = (tid & 3) * 16;
            const _Float16* kpp = Kp + (size_t)(ns + r) * 64 + dq;
            half8 h0 = *(const half8*)(kpp);
            half8 h1 = *(const half8*)(kpp + 8);
            *(half8*)&Kh[r * 68 + dq]     = h0;
            *(half8*)&Kh[r * 68 + dq + 8] = h1;
            diag4[r][tid & 3] = sumsq8(h0) + sumsq8(h1);
        }
        {   // stage Vt transposed [d][n]: thread d = tid&63, n-block of 16
            const int d = tid & 63, nb = (tid >> 6) * 16;
            _Float16 t[16];
#pragma unroll
            for (int i = 0; i < 16; i++)
                t[i] = Vp[(size_t)(ns + nb + i) * 64 + d];
            *(half8*)&Vt[d * 68 + nb]     = *(half8*)&t[0];
            *(half8*)&Vt[d * 68 + nb + 8] = *(half8*)&t[8];
        }
        __syncthreads();                              // A: Kh/Vt/diag4 ready (kpt free)
        // dd[n][j]: M=64 n, N=32 j (this wave), K=64
        floatx4 s4[4][2];
#pragma unroll
        for (int nt = 0; nt < 4; nt++)
#pragma unroll
            for (int jt = 0; jt < 2; jt++) s4[nt][jt] = (floatx4){0.f, 0.f, 0.f, 0.f};
#pragma unroll
        for (int ks = 0; ks < 2; ks++) {
            half8 af[4], bf[2];
#pragma unroll
            for (int nt = 0; nt < 4; nt++)
                af[nt] = *(half8*)&Kh[(nt * 16 + lm) * 68 + ks * 32 + lq * 8];
#pragma unroll
            for (int jt = 0; jt < 2; jt++)
                bf[jt] = *(const half8*)(projh + (jh * 128 + wv * 32 + jt * 16 + lm) * 64 + ks * 32 + lq * 8);
#pragma unroll
            for (int nt = 0; nt < 4; nt++)
#pragma unroll
                for (int jt = 0; jt < 2; jt++)
                    s4[nt][jt] = __builtin_amdgcn_mfma_f32_16x16x32_f16(af[nt], bf[jt], s4[nt][jt], 0, 0, 0);
        }
        // exp in C-layout (col=j=lm, row=n=lq*4+reg), kp -> kpt [j][n] fp16
        float jsum[2] = {0.f, 0.f};
#pragma unroll
        for (int nt = 0; nt < 4; nt++) {
            float dg[4];
#pragma unroll
            for (int r = 0; r < 4; r++) {
                float4 d4 = *(float4*)diag4[nt * 16 + lq * 4 + r];   // broadcast read
                dg[r] = (d4.x + d4.y + d4.z + d4.w) * 0.0625f;
            }
#pragma unroll
            for (int jt = 0; jt < 2; jt++) {
                half4h kv;
#pragma unroll
                for (int r = 0; r < 4; r++) {
                    float v = RATIO * (expf(fminf(NORMC * s4[nt][jt][r] - dg[r] - kmax, 0.f)) + KEPS);
                    jsum[jt] += v;
                    kv[r] = (_Float16)v;
                }
                *(half4h*)&kpt[(wv * 32 + jt * 16 + lm) * 68 + nt * 16 + lq * 4] = kv;
            }
        }
#pragma unroll
        for (int jt = 0; jt < 2; jt++)
            atomicAdd(&ksum_s[wv * 32 + jt * 16 + lm], jsum[jt]);
        __syncthreads();                              // B: kpt ready
        // ctx[j][d] += kp^T @ V: M=32 j (this wave), N=64 d, K=64 n
#pragma unroll
        for (int ks = 0; ks < 2; ks++) {
            half8 af[2], bf[4];
#pragma unroll
            for (int jt = 0; jt < 2; jt++)
                af[jt] = *(half8*)&kpt[(wv * 32 + jt * 16 + lm) * 68 + ks * 32 + lq * 8];
#pragma unroll
            for (int dt = 0; dt < 4; dt++)
                bf[dt] = *(half8*)&Vt[(dt * 16 + lm) * 68 + ks * 32 + lq * 8];
#pragma unroll
            for (int jt = 0; jt < 2; jt++)
#pragma unroll
                for (int dt = 0; dt < 4; dt++)
                    acc[jt][dt] = __builtin_amdgcn_mfma_f32_16x16x32_f16(af[jt], bf[dt], acc[jt][dt], 0, 0, 0);
        }
        __syncthreads();                              // D: before next staging
    }
    // flush: C-layout col=d=lm, row=j=lq*4+reg
    float* __restrict__ ctxp = ws + O_CTX + bh * 16384;
#pragma unroll
    for (int jt = 0; jt < 2; jt++) {
#pragma unroll
        for (int dt = 0; dt < 4; dt++) {
            const int d = dt * 16 + lm;
#pragma unroll
            for (int r = 0; r < 4; r++) {
                const int j = jh * 128 + wv * 32 + jt * 16 + lq * 4 + r;
                atomicAdd(&ctxp[j * 64 + d], acc[jt][dt][r]);
            }
        }
    }
    if (tid < 128) atomicAdd(ws + O_KSUM + bh * 256 + jh * 128 + tid, ksum_s[tid]);
}

// ---------------- query-side: dd, rowmax, qp, attG = qp.ctx / (qp.ksum) (fp16 MFMA) ----
// Ph and Ct LDS dropped: B-fragments direct from projh / ctxT (both L2-resident,
// no intra-block reuse). LDS = Qh + qp ~43 KB -> 3 blocks/CU.
__launch_bounds__(256)
__global__ void k_qout(float* __restrict__ ws) {
    __shared__ _Float16 Qh[64 * 68];      // Q tile [n][d] fp16
    __shared__ _Float16 qp_s[64 * 260];   // qp [n][j] fp16, stride 260
    __shared__ float ksum_s[256];
    __shared__ float diag4[64][4];
    __shared__ float diag_s[64];
    __shared__ unsigned rmax_s[64];
    __shared__ float denom_s[64];
    const int bh = blockIdx.x, b = bh / 6, h = bh % 6;
    const int n0 = blockIdx.y * 64;
    const _Float16* __restrict__ Qp = (const _Float16*)(ws + O_Q) + (size_t)(b * 8 + h) * 8192 * 64;
    const _Float16* __restrict__ projh = (const _Float16*)(ws + O_PH);
    const _Float16* __restrict__ ct = (const _Float16*)(ws + O_CTXT) + (size_t)bh * 16384;
    _Float16* __restrict__ attG = (_Float16*)(ws + O_K);     // [16384][384] fp16
    const int tid = threadIdx.x;
    const int wv = tid >> 6, lane = tid & 63, lm = lane & 15, lq = lane >> 4;
    if (tid < 64) { rmax_s[tid] = 0u; denom_s[tid] = 0.f; }
    ksum_s[tid] = ws[O_KSUM + bh * 256 + tid];

    {   // stage Qh [n][d] fp16 copy + |Q|^2 partials from fp16
        const int r = tid >> 2, dq = (tid & 3) * 16;
        const _Float16* qpp = Qp + (size_t)(n0 + r) * 64 + dq;
        half8 h0 = *(const half8*)(qpp);
        half8 h1 = *(const half8*)(qpp + 8);
        *(half8*)&Qh[r * 68 + dq]     = h0;
        *(half8*)&Qh[r * 68 + dq + 8] = h1;
        diag4[r][tid & 3] = sumsq8(h0) + sumsq8(h1);
    }
    __syncthreads();
    if (tid < 64) {
        float4 d4 = *(float4*)diag4[tid];
        diag_s[tid] = (d4.x + d4.y + d4.z + d4.w) * 0.0625f;
    }
    // dd = Q . proj^T : M=64 n, N=64 j (this wave's slice), K=64; B direct from projh
    floatx4 s4[4][4];
#pragma unroll
    for (int nt = 0; nt < 4; nt++)
#pragma unroll
        for (int jt = 0; jt < 4; jt++) s4[nt][jt] = (floatx4){0.f, 0.f, 0.f, 0.f};
#pragma unroll
    for (int ks = 0; ks < 2; ks++) {
        half8 af[4], bf[4];
#pragma unroll
        for (int nt = 0; nt < 4; nt++)
            af[nt] = *(half8*)&Qh[(nt * 16 + lm) * 68 + ks * 32 + lq * 8];
#pragma unroll
        for (int jt = 0; jt < 4; jt++)
            bf[jt] = *(const half8*)(projh + (wv * 64 + jt * 16 + lm) * 64 + ks * 32 + lq * 8);
#pragma unroll
        for (int nt = 0; nt < 4; nt++)
#pragma unroll
            for (int jt = 0; jt < 4; jt++)
                s4[nt][jt] = __builtin_amdgcn_mfma_f32_16x16x32_f16(af[nt], bf[jt], s4[nt][jt], 0, 0, 0);
    }
    // row maxima over this wave's 64 j -> cross-wave via LDS atomicMax
#pragma unroll
    for (int nt = 0; nt < 4; nt++) {
#pragma unroll
        for (int rr = 0; rr < 4; rr++) {
            float m0 = fmaxf(fmaxf(s4[nt][0][rr], s4[nt][1][rr]),
                             fmaxf(s4[nt][2][rr], s4[nt][3][rr]));
            m0 = fmaxf(m0, __shfl_xor(m0, 1, 64));
            m0 = fmaxf(m0, __shfl_xor(m0, 2, 64));
            m0 = fmaxf(m0, __shfl_xor(m0, 4, 64));
            m0 = fmaxf(m0, __shfl_xor(m0, 8, 64));
            if (lm == 0) atomicMax(&rmax_s[nt * 16 + lq * 4 + rr], encf(m0 * NORMC));
        }
    }
    __syncthreads();     // rmax_s/diag_s ready
    // qp = RATIO*(exp(NORMC*dd - diag - rmax)+KEPS) -> fp16 LDS; denom into s4
#pragma unroll
    for (int nt = 0; nt < 4; nt++) {
#pragma unroll
        for (int rr = 0; rr < 4; rr++) {
            const int row = nt * 16 + lq * 4 + rr;
            const float rmx = decf(rmax_s[row]);
            const float dgv = diag_s[row];
#pragma unroll
            for (int jt = 0; jt < 4; jt++) {
                const int j = wv * 64 + jt * 16 + lm;
                float v = RATIO * (expf(fminf(NORMC * s4[nt][jt][rr] - dgv - rmx, 0.f)) + KEPS);
                qp_s[row * 260 + j] = (_Float16)v;
                s4[nt][jt][rr] = v * ksum_s[j];
            }
            float ds = s4[nt][0][rr] + s4[nt][1][rr] + s4[nt][2][rr] + s4[nt][3][rr];
            ds += __shfl_xor(ds, 1, 64);
            ds += __shfl_xor(ds, 2, 64);
            ds += __shfl_xor(ds, 4, 64);
            ds += __shfl_xor(ds, 8, 64);
            if (lm == 0) atomicAdd(&denom_s[row], ds);
        }
    }
    __syncthreads();     // qp + denom ready
    // attG = qp . ctx : M=64 n, N=16 d (this wave's slice), K=256 j; B direct from ctxT
    floatx4 acc2[4];
#pragma unroll
    for (int nt = 0; nt < 4; nt++) acc2[nt] = (floatx4){0.f, 0.f, 0.f, 0.f};
#pragma unroll
    for (int ks = 0; ks < 8; ks++) {
        half8 bfv = *(const half8*)(ct + (wv * 16 + lm) * 256 + ks * 32 + lq * 8);
#pragma unroll
        for (int nt = 0; nt < 4; nt++) {
            half8 af = *(half8*)&qp_s[(nt * 16 + lm) * 260 + ks * 32 + lq * 8];
            acc2[nt] = __builtin_amdgcn_mfma_f32_16x16x32_f16(af, bfv, acc2[nt], 0, 0, 0);
        }
    }
#pragma unroll
    for (int nt = 0; nt < 4; nt++) {
#pragma unroll
        for (int rr = 0; rr < 4; rr++) {
            const int row = nt * 16 + lq * 4 + rr;
            const float inv = 1.0f / fmaxf(denom_s[row], 1e-30f);
            attG[((size_t)(b * 8192 + n0 + row)) * 384 + h * 64 + wv * 16 + lm] =
                (_Float16)(acc2[nt][rr] * inv);
        }
    }
}

// ---------------- local windowed attention w/ RoPE, heads 6..7 (fp16 MFMA) ----------------
__launch_bounds__(256)
__global__ void k_local(float* __restrict__ ws) {
    __shared__ _Float16 Qh[64 * 68];     // RoPE'd Q [q][d]
    __shared__ _Float16 Kh[64 * 68];     // RoPE'd K chunk [k][d]
    __shared__ _Float16 Vt[64 * 68];     // V chunk transposed [d][k]
    __shared__ _Float16 pT[64 * 68];     // P [q][k] fp16
    const int bhp = blockIdx.x, b = bhp >> 1, lh = bhp & 1, h = 6 + lh;
    const int tile = blockIdx.y;                 // 0..127 (64-query tiles)
    const int w = tile >> 2;                     // window index
    const int q0 = tile * 64;
    const _Float16* __restrict__ Qb = (const _Float16*)(ws + O_Q) + (size_t)(b * 8 + h) * 8192 * 64;
    const _Float16* __restrict__ Kb = (const _Float16*)(ws + O_K) + (size_t)(b * 8 + h) * 8192 * 64;
    const _Float16* __restrict__ Vb = (const _Float16*)(ws + O_V) + (size_t)(b * 8 + h) * 8192 * 64;
    const float* __restrict__ cosT = ws + O_COS;
    const float* __restrict__ sinT = ws + O_SIN;
    const int tid = threadIdx.x;
    const int wv = tid >> 6, lane = tid & 63, lm = lane & 15, lq = lane >> 4;
    // staging mapping: 4 threads per row, 16 dims each
    const int row = tid >> 2, dq = (tid & 3) * 16;
    const int e = dq & 31;
    const int comp = (dq < 32) ? dq + 32 : dq - 32;
    const float sgn = (dq < 32) ? -1.f : 1.f;

    {   // stage Q tile with RoPE -> fp16 [q][d]
        const int qpos = q0 + row;
        const _Float16* bp = Qb + (size_t)qpos * 64;
        const float* cp = cosT + qpos * 32 + e;
        const float* sp = sinT + qpos * 32 + e;
        _Float16 t[16];
#pragma unroll
        for (int w4 = 0; w4 < 4; w4++) {
            float4 c4 = *(const float4*)(cp + 4 * w4);
            float4 s4v = *(const float4*)(sp + 4 * w4);
            half4h xah = *(const half4h*)(bp + dq + 4 * w4);
            half4h xbh = *(const half4h*)(bp + comp + 4 * w4);
            t[4*w4+0] = (_Float16)fmaf(sgn * (float)xbh[0], s4v.x, (float)xah[0] * c4.x);
            t[4*w4+1] = (_Float16)fmaf(sgn * (float)xbh[1], s4v.y, (float)xah[1] * c4.y);
            t[4*w4+2] = (_Float16)fmaf(sgn * (float)xbh[2], s4v.z, (float)xah[2] * c4.z);
            t[4*w4+3] = (_Float16)fmaf(sgn * (float)xbh[3], s4v.w, (float)xah[3] * c4.w);
        }
        *(half8*)&Qh[row * 68 + dq]     = *(half8*)&t[0];
        *(half8*)&Qh[row * 68 + dq + 8] = *(half8*)&t[8];
    }
    floatx4 O[4];                    // [df] rows=q (lq*4+r), cols=d (df*16+lm)
#pragma unroll
    for (int df = 0; df < 4; df++) O[df] = (floatx4){0.f, 0.f, 0.f, 0.f};
    float m_run[4] = {-1e30f, -1e30f, -1e30f, -1e30f};
    float l_run[4] = {0.f, 0.f, 0.f, 0.f};

    for (int c = 0; c < 12; c++) {
        const int kp0 = (w - 1) * 256 + c * 64;
        if (kp0 < 0 || kp0 >= 8192) continue;    // look_around pad (block-uniform)
        __syncthreads();             // prior chunk's Vt/pT reads done
        {   // stage K chunk (RoPE) fp16 [k][d]
            const int kpos = kp0 + row;
            const _Float16* bp = Kb + (size_t)kpos * 64;
            const float* cp = cosT + kpos * 32 + e;
            const float* sp = sinT + kpos * 32 + e;
            _Float16 t[16];
#pragma unroll
            for (int w4 = 0; w4 < 4; w4++) {
                float4 c4 = *(const float4*)(cp + 4 * w4);
                float4 s4v = *(const float4*)(sp + 4 * w4);
                half4h xah = *(const half4h*)(bp + dq + 4 * w4);
                half4h xbh = *(const half4h*)(bp + comp + 4 * w4);
                t[4*w4+0] = (_Float16)fmaf(sgn * (float)xbh[0], s4v.x, (float)xah[0] * c4.x);
                t[4*w4+1] = (_Float16)fmaf(sgn * (float)xbh[1], s4v.y, (float)xah[1] * c4.y);
                t[4*w4+2] = (_Float16)fmaf(sgn * (float)xbh[2], s4v.z, (float)xah[2] * c4.z);
                t[4*w4+3] = (_Float16)fmaf(sgn * (float)xbh[3], s4v.w, (float)xah[3] * c4.w);
            }
            *(half8*)&Kh[row * 68 + dq]     = *(half8*)&t[0];
            *(half8*)&Kh[row * 68 + dq + 8] = *(half8*)&t[8];
        }
        {   // stage V transposed fp16 [d][k]: lane d, wave's 16-row block
            const int d = lane, nb = wv * 16;
            _Float16 t[16];
#pragma unroll
            for (int i = 0; i < 16; i++)
                t[i] = Vb[(size_t)(kp0 + nb + i) * 64 + d];
            *(half8*)&Vt[d * 68 + nb]     = *(half8*)&t[0];
            *(half8*)&Vt[d * 68 + nb + 8] = *(half8*)&t[8];
        }
        __syncthreads();             // Kh/Vt ready
        // QK^T: M=16 q (this wave), N=64 k, K=64 d
        floatx4 s4[4];
#pragma unroll
        for (int nf = 0; nf < 4; nf++) s4[nf] = (floatx4){0.f, 0.f, 0.f, 0.f};
#pragma unroll
        for (int ks = 0; ks < 2; ks++) {
            half8 aq = *(half8*)&Qh[(wv * 16 + lm) * 68 + ks * 32 + lq * 8];
            half8 bf[4];
#pragma unroll
            for (int nf = 0; nf < 4; nf++)
                bf[nf] = *(half8*)&Kh[(nf * 16 + lm) * 68 + ks * 32 + lq * 8];
#pragma unroll
            for (int nf = 0; nf < 4; nf++)
                s4[nf] = __builtin_amdgcn_mfma_f32_16x16x32_f16(aq, bf[nf], s4[nf], 0, 0, 0);
        }
        // online softmax in registers; scale = 64^-0.5 = 0.125
        float p[4][4];
#pragma unroll
        for (int r = 0; r < 4; r++) {
            float m0 = fmaxf(fmaxf(s4[0][r], s4[1][r]), fmaxf(s4[2][r], s4[3][r]));
            m0 = fmaxf(m0, __shfl_xor(m0, 1, 64));
            m0 = fmaxf(m0, __shfl_xor(m0, 2, 64));
            m0 = fmaxf(m0, __shfl_xor(m0, 4, 64));
            m0 = fmaxf(m0, __shfl_xor(m0, 8, 64));
            const float mn = fmaxf(m_run[r], m0 * 0.125f);
            const float al = expf(m_run[r] - mn);
            m_run[r] = mn;
            float rs = 0.f;
#pragma unroll
            for (int nf = 0; nf < 4; nf++) {
                float pv = expf(fmaf(s4[nf][r], 0.125f, -mn));
                p[nf][r] = pv;
                rs += pv;
            }
            l_run[r] = l_run[r] * al + rs;   // per-lane partial (4 of 64 cols)
#pragma unroll
            for (int df = 0; df < 4; df++) O[df][r] *= al;
        }
        // P -> LDS fp16 [q][k] (wave-private rows; conflict-free: lq groups 8 banks apart)
#pragma unroll
        for (int nf = 0; nf < 4; nf++)
#pragma unroll
            for (int r = 0; r < 4; r++)
                pT[(wv * 16 + lq * 4 + r) * 68 + nf * 16 + lm] = (_Float16)p[nf][r];
        __syncthreads();             // pT visible
        // PV: M=16 q (this wave), N=64 d, K=64 k
#pragma unroll
        for (int ks = 0; ks < 2; ks++) {
            half8 ap = *(half8*)&pT[(wv * 16 + lm) * 68 + ks * 32 + lq * 8];
            half8 bf[4];
#pragma unroll
            for (int df = 0; df < 4; df++)
                bf[df] = *(half8*)&Vt[(df * 16 + lm) * 68 + ks * 32 + lq * 8];
#pragma unroll
            for (int df = 0; df < 4; df++)
                O[df] = __builtin_amdgcn_mfma_f32_16x16x32_f16(ap, bf[df], O[df], 0, 0, 0);
        }
    }
    // final l reduce over lm, normalize, store
#pragma unroll
    for (int r = 0; r < 4; r++) {
        l_run[r] += __shfl_xor(l_run[r], 1, 64);
        l_run[r] += __shfl_xor(l_run[r], 2, 64);
        l_run[r] += __shfl_xor(l_run[r], 4, 64);
        l_run[r] += __shfl_xor(l_run[r], 8, 64);
        l_run[r] = 1.f / fmaxf(l_run[r], 1e-30f);
    }
    _Float16* __restrict__ attL = (_Float16*)(ws + O_ATTL);   // [2][2][8192][64] fp16
#pragma unroll
    for (int df = 0; df < 4; df++) {
#pragma unroll
        for (int r = 0; r < 4; r++) {
            const int q = q0 + wv * 16 + lq * 4 + r;
            attL[((size_t)(b * 2 + lh) * 8192 + q) * 64 + df * 16 + lm] =
                (_Float16)(O[df][r] * l_run[r]);
        }
    }
}

// ---------------- output projection + bias (fp16 MFMA) ----------------
__launch_bounds__(256)
__global__ void k_out(const float* __restrict__ bo,
                      const float* __restrict__ ws,
                      float* __restrict__ out) {
    __shared__ _Float16 Ah[128 * 72];
    __shared__ _Float16 Bh[128 * 72];
    const _Float16* __restrict__ attG = (const _Float16*)(ws + O_K);      // [16384][384]
    const _Float16* __restrict__ attL = (const _Float16*)(ws + O_ATTL);   // [4][8192][64]
    const _Float16* __restrict__ WoT = (const _Float16*)(ws + O_CTX);     // [512][512] [n][k]
    const int r0 = blockIdx.x * 128, c0 = blockIdx.y * 128;
    const int tid = threadIdx.x;
    const int wv = tid >> 6, lane = tid & 63, lm = lane & 15, lq = lane >> 4;
    const int srow = tid >> 1, skoff = (tid & 1) * 32;
    floatx4 acc[2][8];
#pragma unroll
    for (int m = 0; m < 2; m++)
#pragma unroll
        for (int n = 0; n < 8; n++) acc[m][n] = (floatx4){0.f, 0.f, 0.f, 0.f};

    for (int c = 0; c < 8; c++) {
        const int k0 = c * 64;
        {   // stage A: att fp16 direct copy (32-seg never straddles the 384 boundary)
            const int row = r0 + srow;
            const int kk = k0 + skoff;
            const _Float16* ap;
            if (kk < 384) {
                ap = attG + (size_t)row * 384 + kk;
            } else {
                const int bb = row >> 13, nn = row & 8191;
                const int kr = kk - 384;
                ap = attL + ((size_t)(bb * 2 + (kr >> 6)) * 8192 + nn) * 64 + (kr & 63);
            }
#pragma unroll
            for (int q = 0; q < 4; q++)
                *(uint4*)&Ah[srow * 72 + skoff + 8 * q] = *(const uint4*)(ap + 8 * q);
        }
        {   // stage B: WoT fp16 direct copy
            const _Float16* bp = WoT + (size_t)(c0 + srow) * 512 + k0 + skoff;
#pragma unroll
            for (int q = 0; q < 4; q++)
                *(uint4*)&Bh[srow * 72 + skoff + 8 * q] = *(const uint4*)(bp + 8 * q);
        }
        __syncthreads();
#pragma unroll
        for (int ks = 0; ks < 2; ks++) {
            half8 af[2], bf[8];
            af[0] = *(half8*)&Ah[(wv * 32 + lm) * 72 + ks * 32 + lq * 8];
            af[1] = *(half8*)&Ah[(wv * 32 + 16 + lm) * 72 + ks * 32 + lq * 8];
#pragma unroll
            for (int n = 0; n < 8; n++)
                bf[n] = *(half8*)&Bh[(n * 16 + lm) * 72 + ks * 32 + lq * 8];
#pragma unroll
            for (int m = 0; m < 2; m++)
#pragma unroll
                for (int n = 0; n < 8; n++)
                    acc[m][n] = __builtin_amdgcn_mfma_f32_16x16x32_f16(af[m], bf[n], acc[m][n], 0, 0, 0);
        }
        __syncthreads();
    }
#pragma unroll
    for (int n = 0; n < 8; n++) {
        const int col = c0 + n * 16 + lm;
        const float bias = bo[col];
#pragma unroll
        for (int m = 0; m < 2; m++) {
            const int rbase = r0 + wv * 32 + m * 16 + lq * 4;
#pragma unroll
            for (int j = 0; j < 4; j++)
                out[(size_t)(rbase + j) * 512 + col] = acc[m][n][j] + bias;
        }
    }
}

extern "C" void kernel_launch(void* const* d_in, const int* in_sizes, int n_in,
                              void* d_out, int out_size, void* d_ws, size_t ws_size,
                              hipStream_t stream) {
    const float* x    = (const float*)d_in[0];
    const float* Wq   = (const float*)d_in[1];
    const float* Wk   = (const float*)d_in[2];
    const float* Wv   = (const float*)d_in[3];
    const float* Wo   = (const float*)d_in[4];
    const float* bo   = (const float*)d_in[5];
    const float* proj = (const float*)d_in[6];
    float* ws = (float*)d_ws;
    float* out = (float*)d_out;

    hipMemsetAsync(d_ws, 0, (size_t)O_ZEND * 4, stream);                 // kmax/ksum/ctx
    hipLaunchKernelGGL(k_rope,   dim3(1024), dim3(256), 0, stream, ws);
    hipLaunchKernelGGL(k_half_x, dim3(4096), dim3(256), 0, stream, x, ws);
    hipLaunchKernelGGL(k_half_w, dim3(8, 8, 3), dim3(256), 0, stream, Wq, Wk, Wv, ws);
    hipLaunchKernelGGL(k_qkv,    dim3(128, 4, 3), dim3(256), 0, stream, ws);
    hipLaunchKernelGGL(k_half_p, dim3(8), dim3(256), 0, stream, proj, ws);  // XH tail dead now
    hipLaunchKernelGGL(k_kmax,   dim3(12, 128), dim3(256), 0, stream, ws);
    hipLaunchKernelGGL(k_kctx,   dim3(12, 32, 2), dim3(256), 0, stream, ws);
    hipLaunchKernelGGL(k_ctxt,   dim3(12, 4), dim3(256), 0, stream, ws);    // ctx -> ctxT fp16
    hipLaunchKernelGGL(k_local,  dim3(4, 128), dim3(256), 0, stream, ws);   // before k_qout!
    hipLaunchKernelGGL(k_qout,   dim3(12, 128), dim3(256), 0, stream, ws);
    hipLaunchKernelGGL(k_half_wo, dim3(8, 8), dim3(256), 0, stream, Wo, ws); // ctx dead -> WoT
    hipLaunchKernelGGL(k_out,    dim3(128, 4), dim3(256), 0, stream, bo, ws, out);
}

// Round 6
// 324.164 us; speedup vs baseline: 2.0564x; 1.0018x over previous
//
#include <hip/hip_runtime.h>

// ---------------- constants ----------------
#define NTOK 8192
#define NORMC 0.35355339059327373f   // 64^-0.25
#define RATIO 0.0625f                // 256^-0.5
#define KEPS  1e-4f

// ws offsets in 4-byte elements (total 27987008)
#define O_KMAX 0                      // 12 x u32 (encoded max)
#define O_KSUM 64                     // 12*256 f32
#define O_CTX  3136                   // 12*256*64 f32; after k_qout reused as WoT fp16 [512][512]
#define O_ZEND 199744                 // zeroed region end
#define O_COS  199744                 // 8192*32
#define O_SIN  461888                 // 8192*32
#define O_Q    724032                 // fp16 [2][8][8192][64] -> ends 4918336
#define O_K    9112640                // fp16 K [9112640,13306944); later attG fp16 [16384][384]
#define O_XH   13306944               // fp16 x [16384][512] [13306944,17501248) (dead after k_qkv)
#define O_V    17501248               // fp16 V [17501248,21695552)
#define O_QR   21695552               // fp16 RoPE'd Q heads6-7 [2][2][8192][64] -> 22744128
#define O_KR   22744128               // fp16 RoPE'd K heads6-7 -> 23792704
#define O_ATTL 25889856               // fp16 [2][2][8192][64] (ends 26938432)
#define O_WH   25889856               // fp16 W^T [3][512][512] (dead after k_qkv)
#define O_PH   26938432               // fp16 proj [256][64] (8192 f32)
#define O_CTXT 26946624               // fp16 ctxT [12][64][256] (98304 f32) -> 27044928
// end of use: 27044928 < 27987008

typedef _Float16 half8 __attribute__((ext_vector_type(8)));
typedef _Float16 half4h __attribute__((ext_vector_type(4)));
typedef float floatx4 __attribute__((ext_vector_type(4)));

__device__ __forceinline__ unsigned encf(float f) {
    unsigned u = __float_as_uint(f);
    return (u & 0x80000000u) ? ~u : (u | 0x80000000u);
}
__device__ __forceinline__ float decf(unsigned u) {
    return (u & 0x80000000u) ? __uint_as_float(u & 0x7fffffffu) : __uint_as_float(~u);
}
__device__ __forceinline__ float sumsq8(half8 h) {
    float s = 0.f;
#pragma unroll
    for (int i = 0; i < 8; i++) { float v = (float)h[i]; s = fmaf(v, v, s); }
    return s;
}

// ---------------- RoPE tables (double precision angles) ----------------
__global__ void k_rope(float* __restrict__ ws) {
    int idx = blockIdx.x * 256 + threadIdx.x;      // 8192*32
    int t = idx >> 5, i = idx & 31;
    double invf = pow(10000.0, -(double)(2 * i) / 64.0);
    double ang = (double)t * invf;
    ws[O_COS + idx] = (float)cos(ang);
    ws[O_SIN + idx] = (float)sin(ang);
}

// ---------------- x -> fp16 ----------------
__launch_bounds__(256)
__global__ void k_half_x(const float* __restrict__ x, float* __restrict__ ws) {
    const int idx = blockIdx.x * 256 + threadIdx.x;   // *8 elements
    const float* p = x + (size_t)idx * 8;
    float4 a = *(const float4*)p, b = *(const float4*)(p + 4);
    half8 h = {(_Float16)a.x, (_Float16)a.y, (_Float16)a.z, (_Float16)a.w,
               (_Float16)b.x, (_Float16)b.y, (_Float16)b.z, (_Float16)b.w};
    *(half8*)((_Float16*)(ws + O_XH) + (size_t)idx * 8) = h;
}

// ---------------- proj -> fp16 [256][64] ----------------
__launch_bounds__(256)
__global__ void k_half_p(const float* __restrict__ proj, float* __restrict__ ws) {
    const int idx = blockIdx.x * 256 + threadIdx.x;
    const float* p = proj + (size_t)idx * 8;
    float4 a = *(const float4*)p, b = *(const float4*)(p + 4);
    half8 h = {(_Float16)a.x, (_Float16)a.y, (_Float16)a.z, (_Float16)a.w,
               (_Float16)b.x, (_Float16)b.y, (_Float16)b.z, (_Float16)b.w};
    *(half8*)((_Float16*)(ws + O_PH) + (size_t)idx * 8) = h;
}

// ---------------- RoPE'd Q/K fp16 for local heads 6..7, precomputed once ----------------
__launch_bounds__(256)
__global__ void k_ropeqk(float* __restrict__ ws) {
    const int idx = blockIdx.x * 256 + threadIdx.x;   // 32768 rows * 4 thr/row
    const int rg = idx >> 2, dqo = (idx & 3) * 16;
    const int b = rg >> 14, lh = (rg >> 13) & 1, n = rg & 8191;
    const int h = 6 + lh;
    const int e = dqo & 31;
    const int comp = (dqo < 32) ? dqo + 32 : dqo - 32;
    const float sgn = (dqo < 32) ? -1.f : 1.f;
    const _Float16* Qs = (const _Float16*)(ws + O_Q) + ((size_t)(b * 8 + h) * 8192 + n) * 64;
    const _Float16* Ks = (const _Float16*)(ws + O_K) + ((size_t)(b * 8 + h) * 8192 + n) * 64;
    _Float16* Qd = (_Float16*)(ws + O_QR) + ((size_t)(b * 2 + lh) * 8192 + n) * 64;
    _Float16* Kd = (_Float16*)(ws + O_KR) + ((size_t)(b * 2 + lh) * 8192 + n) * 64;
    const float* cp = ws + O_COS + n * 32 + e;
    const float* sp = ws + O_SIN + n * 32 + e;
    _Float16 tq[16], tk[16];
#pragma unroll
    for (int w4 = 0; w4 < 4; w4++) {
        float4 c4 = *(const float4*)(cp + 4 * w4);
        float4 s4v = *(const float4*)(sp + 4 * w4);
        half4h qa = *(const half4h*)(Qs + dqo + 4 * w4);
        half4h qb = *(const half4h*)(Qs + comp + 4 * w4);
        half4h ka = *(const half4h*)(Ks + dqo + 4 * w4);
        half4h kb = *(const half4h*)(Ks + comp + 4 * w4);
        tq[4*w4+0] = (_Float16)fmaf(sgn * (float)qb[0], s4v.x, (float)qa[0] * c4.x);
        tq[4*w4+1] = (_Float16)fmaf(sgn * (float)qb[1], s4v.y, (float)qa[1] * c4.y);
        tq[4*w4+2] = (_Float16)fmaf(sgn * (float)qb[2], s4v.z, (float)qa[2] * c4.z);
        tq[4*w4+3] = (_Float16)fmaf(sgn * (float)qb[3], s4v.w, (float)qa[3] * c4.w);
        tk[4*w4+0] = (_Float16)fmaf(sgn * (float)kb[0], s4v.x, (float)ka[0] * c4.x);
        tk[4*w4+1] = (_Float16)fmaf(sgn * (float)kb[1], s4v.y, (float)ka[1] * c4.y);
        tk[4*w4+2] = (_Float16)fmaf(sgn * (float)kb[2], s4v.z, (float)ka[2] * c4.z);
        tk[4*w4+3] = (_Float16)fmaf(sgn * (float)kb[3], s4v.w, (float)ka[3] * c4.w);
    }
    *(half8*)(Qd + dqo)     = *(half8*)&tq[0];
    *(half8*)(Qd + dqo + 8) = *(half8*)&tq[8];
    *(half8*)(Kd + dqo)     = *(half8*)&tk[0];
    *(half8*)(Kd + dqo + 8) = *(half8*)&tk[8];
}

// ---------------- ctx f32 [12][256][64] -> ctxT fp16 [12][64][256] ----------------
__launch_bounds__(256)
__global__ void k_ctxt(float* __restrict__ ws) {
    __shared__ float T[64][65];
    const int bh = blockIdx.x, j0 = blockIdx.y * 64;
    const float* __restrict__ ctxp = ws + O_CTX + bh * 16384;
    _Float16* __restrict__ ct = (_Float16*)(ws + O_CTXT) + bh * 16384;
    const int lx = threadIdx.x & 63, ly = threadIdx.x >> 6;
#pragma unroll
    for (int i = 0; i < 16; i++) {
        const int jl = ly * 16 + i;
        T[jl][lx] = ctxp[(j0 + jl) * 64 + lx];
    }
    __syncthreads();
#pragma unroll
    for (int i = 0; i < 16; i++) {
        const int d = ly * 16 + i;
        ct[d * 256 + j0 + lx] = (_Float16)T[lx][d];
    }
}

// ---------------- W -> fp16, transposed to [n][k] ----------------
__launch_bounds__(256)
__global__ void k_half_w(const float* __restrict__ Wq,
                         const float* __restrict__ Wk,
                         const float* __restrict__ Wv,
                         float* __restrict__ ws) {
    __shared__ float T[64][65];
    const int z = blockIdx.z;
    const float* __restrict__ W = (z == 0) ? Wq : ((z == 1) ? Wk : Wv);
    _Float16* __restrict__ Wt = (_Float16*)(ws + O_WH) + (size_t)z * 262144;
    const int k0 = blockIdx.x * 64, n0 = blockIdx.y * 64;
    const int lx = threadIdx.x & 63, ly = threadIdx.x >> 6;
#pragma unroll
    for (int i = 0; i < 16; i++) {
        const int kk = ly * 16 + i;
        T[lx][kk] = W[(k0 + kk) * 512 + n0 + lx];
    }
    __syncthreads();
#pragma unroll
    for (int i = 0; i < 16; i++) {
        const int nn = ly * 16 + i;
        Wt[(n0 + nn) * 512 + k0 + lx] = (_Float16)T[nn][lx];
    }
}

// ---------------- Wo -> fp16 transposed [n][k], into dead ctx region ----------------
__launch_bounds__(256)
__global__ void k_half_wo(const float* __restrict__ Wo, float* __restrict__ ws) {
    __shared__ float T[64][65];
    _Float16* __restrict__ Wt = (_Float16*)(ws + O_CTX);
    const int k0 = blockIdx.x * 64, n0 = blockIdx.y * 64;
    const int lx = threadIdx.x & 63, ly = threadIdx.x >> 6;
#pragma unroll
    for (int i = 0; i < 16; i++) {
        const int kk = ly * 16 + i;
        T[lx][kk] = Wo[(k0 + kk) * 512 + n0 + lx];
    }
    __syncthreads();
#pragma unroll
    for (int i = 0; i < 16; i++) {
        const int nn = ly * 16 + i;
        Wt[(n0 + nn) * 512 + k0 + lx] = (_Float16)T[nn][lx];
    }
}

// ---------------- QKV projection via fp16 MFMA (fp16 in, fp16 out) ----------------
__launch_bounds__(256)
__global__ void k_qkv(float* __restrict__ ws) {
    __shared__ _Float16 Ah[128 * 72];
    __shared__ _Float16 Bh[128 * 72];
    const int z = blockIdx.z;
    const _Float16* __restrict__ xh = (const _Float16*)(ws + O_XH);
    const _Float16* __restrict__ Wt = (const _Float16*)(ws + O_WH) + (size_t)z * 262144;
    _Float16* __restrict__ out = (_Float16*)(ws + ((z == 0) ? O_Q : ((z == 1) ? O_K : O_V)));
    const int r0 = blockIdx.x * 128, c0 = blockIdx.y * 128;
    const int tid = threadIdx.x;
    const int wv = tid >> 6, lane = tid & 63, lm = lane & 15, lq = lane >> 4;
    const int srow = tid >> 1, skoff = (tid & 1) * 32;
    floatx4 acc[2][8];
#pragma unroll
    for (int m = 0; m < 2; m++)
#pragma unroll
        for (int n = 0; n < 8; n++) acc[m][n] = (floatx4){0.f, 0.f, 0.f, 0.f};

    for (int c = 0; c < 8; c++) {
        const int k0 = c * 64;
        {
            const _Float16* ap = xh + (size_t)(r0 + srow) * 512 + k0 + skoff;
#pragma unroll
            for (int q = 0; q < 4; q++)
                *(uint4*)&Ah[srow * 72 + skoff + 8 * q] = *(const uint4*)(ap + 8 * q);
        }
        {
            const _Float16* bp = Wt + (size_t)(c0 + srow) * 512 + k0 + skoff;
#pragma unroll
            for (int q = 0; q < 4; q++)
                *(uint4*)&Bh[srow * 72 + skoff + 8 * q] = *(const uint4*)(bp + 8 * q);
        }
        __syncthreads();
#pragma unroll
        for (int ks = 0; ks < 2; ks++) {
            half8 af[2], bf[8];
            af[0] = *(half8*)&Ah[(wv * 32 + lm) * 72 + ks * 32 + lq * 8];
            af[1] = *(half8*)&Ah[(wv * 32 + 16 + lm) * 72 + ks * 32 + lq * 8];
#pragma unroll
            for (int n = 0; n < 8; n++)
                bf[n] = *(half8*)&Bh[(n * 16 + lm) * 72 + ks * 32 + lq * 8];
#pragma unroll
            for (int m = 0; m < 2; m++)
#pragma unroll
                for (int n = 0; n < 8; n++)
                    acc[m][n] = __builtin_amdgcn_mfma_f32_16x16x32_f16(af[m], bf[n], acc[m][n], 0, 0, 0);
        }
        __syncthreads();
    }
    const int bi = r0 >> 13;
#pragma unroll
    for (int n = 0; n < 8; n++) {
        const int col = c0 + n * 16 + lm;
        const int h = col >> 6, d = col & 63;
#pragma unroll
        for (int m = 0; m < 2; m++) {
            const int rbase = r0 + wv * 32 + m * 16 + lq * 4;
#pragma unroll
            for (int j = 0; j < 4; j++) {
                const int ng = (rbase + j) & 8191;
                out[((size_t)(bi * 8 + h) * 8192 + ng) * 64 + d] = (_Float16)acc[m][n][j];
            }
        }
    }
}

// ---------------- key-side global max of dd = norm*(K.projT) (fp16 MFMA) ----------------
__launch_bounds__(256)
__global__ void k_kmax(float* __restrict__ ws) {
    __shared__ _Float16 Kh[64 * 68];
    __shared__ unsigned bmax;
    const int bh = blockIdx.x, b = bh / 6, h = bh % 6;
    const _Float16* __restrict__ Kp = (const _Float16*)(ws + O_K) + (size_t)(b * 8 + h) * 8192 * 64;
    const _Float16* __restrict__ projh = (const _Float16*)(ws + O_PH);
    const int n0 = blockIdx.y * 64;
    const int tid = threadIdx.x;
    const int wv = tid >> 6, lane = tid & 63, lm = lane & 15, lq = lane >> 4;
    if (tid == 0) bmax = 0u;
    {
        const int r = tid >> 2, dq = (tid & 3) * 16;
        const _Float16* kpp = Kp + (size_t)(n0 + r) * 64 + dq;
        *(uint4*)&Kh[r * 68 + dq]     = *(const uint4*)(kpp);
        *(uint4*)&Kh[r * 68 + dq + 8] = *(const uint4*)(kpp + 8);
    }
    __syncthreads();
    floatx4 s4[4][4];
#pragma unroll
    for (int nt = 0; nt < 4; nt++)
#pragma unroll
        for (int jt = 0; jt < 4; jt++) s4[nt][jt] = (floatx4){0.f, 0.f, 0.f, 0.f};
#pragma unroll
    for (int ks = 0; ks < 2; ks++) {
        half8 af[4], bf[4];
#pragma unroll
        for (int nt = 0; nt < 4; nt++)
            af[nt] = *(half8*)&Kh[(nt * 16 + lm) * 68 + ks * 32 + lq * 8];
#pragma unroll
        for (int jt = 0; jt < 4; jt++)
            bf[jt] = *(const half8*)(projh + (wv * 64 + jt * 16 + lm) * 64 + ks * 32 + lq * 8);
#pragma unroll
        for (int nt = 0; nt < 4; nt++)
#pragma unroll
            for (int jt = 0; jt < 4; jt++)
                s4[nt][jt] = __builtin_amdgcn_mfma_f32_16x16x32_f16(af[nt], bf[jt], s4[nt][jt], 0, 0, 0);
    }
    float m = -1e30f;
#pragma unroll
    for (int nt = 0; nt < 4; nt++)
#pragma unroll
        for (int jt = 0; jt < 4; jt++)
#pragma unroll
            for (int r = 0; r < 4; r++) m = fmaxf(m, s4[nt][jt][r]);
    m = fmaxf(m, __shfl_xor(m, 1, 64));
    m = fmaxf(m, __shfl_xor(m, 2, 64));
    m = fmaxf(m, __shfl_xor(m, 4, 64));
    m = fmaxf(m, __shfl_xor(m, 8, 64));
    m = fmaxf(m, __shfl_xor(m, 16, 64));
    m = fmaxf(m, __shfl_xor(m, 32, 64));
    if (lane == 0) atomicMax(&bmax, encf(m * NORMC));
    __syncthreads();
    if (tid == 0) atomicMax((unsigned*)ws + O_KMAX + bh, bmax);
}

// ---------------- key-side: kp, k_sum, ctx = kp^T @ V  (fp16 MFMA, reg-prefetch) ----------
__launch_bounds__(256)
__global__ void k_kctx(float* __restrict__ ws) {
    __shared__ _Float16 Kh[64 * 68];
    __shared__ _Float16 Vt[64 * 68];
    __shared__ _Float16 kpt[128 * 68];
    __shared__ float diag4[64][4];
    __shared__ float ksum_s[128];
    const int bh = blockIdx.x, b = bh / 6, h = bh % 6;
    const int n0 = blockIdx.y * 256;
    const int jh = blockIdx.z;
    const _Float16* __restrict__ Kp = (const _Float16*)(ws + O_K) + (size_t)(b * 8 + h) * 8192 * 64;
    const _Float16* __restrict__ Vp = (const _Float16*)(ws + O_V) + (size_t)(b * 8 + h) * 8192 * 64;
    const _Float16* __restrict__ projh = (const _Float16*)(ws + O_PH);
    const float kmax = decf(((const unsigned*)ws)[O_KMAX + bh]);
    const int tid = threadIdx.x;
    const int wv = tid >> 6, lane = tid & 63, lm = lane & 15, lq = lane >> 4;
    const int r = tid >> 2, dqo = (tid & 3) * 16;       // K staging mapping
    const int vd = tid & 63, vnb = (tid >> 6) * 16;     // V staging mapping
    if (tid < 128) ksum_s[tid] = 0.f;

    half8 kb0, kb1;
    _Float16 vb[16];
    {   // prefetch chunk 0
        const _Float16* kpp = Kp + (size_t)(n0 + r) * 64 + dqo;
        kb0 = *(const half8*)(kpp);
        kb1 = *(const half8*)(kpp + 8);
#pragma unroll
        for (int i = 0; i < 16; i++) vb[i] = Vp[(size_t)(n0 + vnb + i) * 64 + vd];
    }
    floatx4 acc[2][4];
#pragma unroll
    for (int jt = 0; jt < 2; jt++)
#pragma unroll
        for (int dt = 0; dt < 4; dt++) acc[jt][dt] = (floatx4){0.f, 0.f, 0.f, 0.f};

    for (int nc = 0; nc < 4; nc++) {
        if (nc) __syncthreads();                  // D: prev chunk's LDS reads done
        // write prefetched K/V into LDS + diag partials
        *(half8*)&Kh[r * 68 + dqo]     = kb0;
        *(half8*)&Kh[r * 68 + dqo + 8] = kb1;
        diag4[r][tid & 3] = sumsq8(kb0) + sumsq8(kb1);
        *(half8*)&Vt[vd * 68 + vnb]     = *(half8*)&vb[0];
        *(half8*)&Vt[vd * 68 + vnb + 8] = *(half8*)&vb[8];
        __syncthreads();                          // A: staging visible
        if (nc < 3) {                             // prefetch next chunk (overlaps compute)
            const int ns = n0 + (nc + 1) * 64;
            const _Float16* kpp = Kp + (size_t)(ns + r) * 64 + dqo;
            kb0 = *(const half8*)(kpp);
            kb1 = *(const half8*)(kpp + 8);
#pragma unroll
            for (int i = 0; i < 16; i++) vb[i] = Vp[(size_t)(ns + vnb + i) * 64 + vd];
        }
        // dd[n][j]: M=64 n, N=32 j (this wave), K=64
        floatx4 s4[4][2];
#pragma unroll
        for (int nt = 0; nt < 4; nt++)
#pragma unroll
            for (int jt = 0; jt < 2; jt++) s4[nt][jt] = (floatx4){0.f, 0.f, 0.f, 0.f};
#pragma unroll
        for (int ks = 0; ks < 2; ks++) {
            half8 af[4], bf[2];
#pragma unroll
            for (int nt = 0; nt < 4; nt++)
                af[nt] = *(half8*)&Kh[(nt * 16 + lm) * 68 + ks * 32 + lq * 8];
#pragma unroll
            for (int jt = 0; jt < 2; jt++)
                bf[jt] = *(const half8*)(projh + (jh * 128 + wv * 32 + jt * 16 + lm) * 64 + ks * 32 + lq * 8);
#pragma unroll
            for (int nt = 0; nt < 4; nt++)
#pragma unroll
                for (int jt = 0; jt < 2; jt++)
                    s4[nt][jt] = __builtin_amdgcn_mfma_f32_16x16x32_f16(af[nt], bf[jt], s4[nt][jt], 0, 0, 0);
        }
        // exp; kp -> kpt (WAVE-PRIVATE rows: written & read only by this wave)
        float jsum[2] = {0.f, 0.f};
#pragma unroll
        for (int nt = 0; nt < 4; nt++) {
            float dg[4];
#pragma unroll
            for (int rr = 0; rr < 4; rr++) {
                float4 d4 = *(float4*)diag4[nt * 16 + lq * 4 + rr];
                dg[rr] = (d4.x + d4.y + d4.z + d4.w) * 0.0625f;
            }
#pragma unroll
            for (int jt = 0; jt < 2; jt++) {
                half4h kv;
#pragma unroll
                for (int rr = 0; rr < 4; rr++) {
                    float v = RATIO * (expf(fminf(NORMC * s4[nt][jt][rr] - dg[rr] - kmax, 0.f)) + KEPS);
                    jsum[jt] += v;
                    kv[rr] = (_Float16)v;
                }
                *(half4h*)&kpt[(wv * 32 + jt * 16 + lm) * 68 + nt * 16 + lq * 4] = kv;
            }
        }
#pragma unroll
        for (int jt = 0; jt < 2; jt++)
            atomicAdd(&ksum_s[wv * 32 + jt * 16 + lm], jsum[jt]);
        // kpt rows are wave-private -> own-wave LDS drain suffices (no barrier)
        asm volatile("s_waitcnt lgkmcnt(0)" ::: "memory");
        // ctx[j][d] += kp^T @ V: M=32 j (this wave), N=64 d, K=64 n
#pragma unroll
        for (int ks = 0; ks < 2; ks++) {
            half8 af[2], bf[4];
#pragma unroll
            for (int jt = 0; jt < 2; jt++)
                af[jt] = *(half8*)&kpt[(wv * 32 + jt * 16 + lm) * 68 + ks * 32 + lq * 8];
#pragma unroll
            for (int dt = 0; dt < 4; dt++)
                bf[dt] = *(half8*)&Vt[(dt * 16 + lm) * 68 + ks * 32 + lq * 8];
#pragma unroll
            for (int jt = 0; jt < 2; jt++)
#pragma unroll
                for (int dt = 0; dt < 4; dt++)
                    acc[jt][dt] = __builtin_amdgcn_mfma_f32_16x16x32_f16(af[jt], bf[dt], acc[jt][dt], 0, 0, 0);
        }
    }
    __syncthreads();   // ksum_s complete
    float* __restrict__ ctxp = ws + O_CTX + bh * 16384;
#pragma unroll
    for (int jt = 0; jt < 2; jt++) {
#pragma unroll
        for (int dt = 0; dt < 4; dt++) {
            const int d = dt * 16 + lm;
#pragma unroll
            for (int rr = 0; rr < 4; rr++) {
                const int j = jh * 128 + wv * 32 + jt * 16 + lq * 4 + rr;
                atomicAdd(&ctxp[j * 64 + d], acc[jt][dt][rr]);
            }
        }
    }
    if (tid < 128) atomicAdd(ws + O_KSUM + bh * 256 + jh * 128 + tid, ksum_s[tid]);
}

// ---------------- query-side: dd, rowmax, qp, attG = qp.ctx / (qp.ksum) (fp16 MFMA) ----
__launch_bounds__(256)
__global__ void k_qout(float* __restrict__ ws) {
    __shared__ _Float16 Qh[64 * 68];
    __shared__ _Float16 qp_s[64 * 260];
    __shared__ float ksum_s[256];
    __shared__ float diag4[64][4];
    __shared__ float diag_s[64];
    __shared__ unsigned rmax_s[64];
    __shared__ float denom_s[64];
    const int bh = blockIdx.x, b = bh / 6, h = bh % 6;
    const int n0 = blockIdx.y * 64;
    const _Float16* __restrict__ Qp = (const _Float16*)(ws + O_Q) + (size_t)(b * 8 + h) * 8192 * 64;
    const _Float16* __restrict__ projh = (const _Float16*)(ws + O_PH);
    const _Float16* __restrict__ ct = (const _Float16*)(ws + O_CTXT) + (size_t)bh * 16384;
    _Float16* __restrict__ attG = (_Float16*)(ws + O_K);
    const int tid = threadIdx.x;
    const int wv = tid >> 6, lane = tid & 63, lm = lane & 15, lq = lane >> 4;
    if (tid < 64) { rmax_s[tid] = 0u; denom_s[tid] = 0.f; }
    ksum_s[tid] = ws[O_KSUM + bh * 256 + tid];

    {
        const int r = tid >> 2, dq = (tid & 3) * 16;
        const _Float16* qpp = Qp + (size_t)(n0 + r) * 64 + dq;
        half8 h0 = *(const half8*)(qpp);
        half8 h1 = *(const half8*)(qpp + 8);
        *(half8*)&Qh[r * 68 + dq]     = h0;
        *(half8*)&Qh[r * 68 + dq + 8] = h1;
        diag4[r][tid & 3] = sumsq8(h0) + sumsq8(h1);
    }
    __syncthreads();
    if (tid < 64) {
        float4 d4 = *(float4*)diag4[tid];
        diag_s[tid] = (d4.x + d4.y + d4.z + d4.w) * 0.0625f;
    }
    floatx4 s4[4][4];
#pragma unroll
    for (int nt = 0; nt < 4; nt++)
#pragma unroll
        for (int jt = 0; jt < 4; jt++) s4[nt][jt] = (floatx4){0.f, 0.f, 0.f, 0.f};
#pragma unroll
    for (int ks = 0; ks < 2; ks++) {
        half8 af[4], bf[4];
#pragma unroll
        for (int nt = 0; nt < 4; nt++)
            af[nt] = *(half8*)&Qh[(nt * 16 + lm) * 68 + ks * 32 + lq * 8];
#pragma unroll
        for (int jt = 0; jt < 4; jt++)
            bf[jt] = *(const half8*)(projh + (wv * 64 + jt * 16 + lm) * 64 + ks * 32 + lq * 8);
#pragma unroll
        for (int nt = 0; nt < 4; nt++)
#pragma unroll
            for (int jt = 0; jt < 4; jt++)
                s4[nt][jt] = __builtin_amdgcn_mfma_f32_16x16x32_f16(af[nt], bf[jt], s4[nt][jt], 0, 0, 0);
    }
#pragma unroll
    for (int nt = 0; nt < 4; nt++) {
#pragma unroll
        for (int rr = 0; rr < 4; rr++) {
            float m0 = fmaxf(fmaxf(s4[nt][0][rr], s4[nt][1][rr]),
                             fmaxf(s4[nt][2][rr], s4[nt][3][rr]));
            m0 = fmaxf(m0, __shfl_xor(m0, 1, 64));
            m0 = fmaxf(m0, __shfl_xor(m0, 2, 64));
            m0 = fmaxf(m0, __shfl_xor(m0, 4, 64));
            m0 = fmaxf(m0, __shfl_xor(m0, 8, 64));
            if (lm == 0) atomicMax(&rmax_s[nt * 16 + lq * 4 + rr], encf(m0 * NORMC));
        }
    }
    __syncthreads();
#pragma unroll
    for (int nt = 0; nt < 4; nt++) {
#pragma unroll
        for (int rr = 0; rr < 4; rr++) {
            const int row = nt * 16 + lq * 4 + rr;
            const float rmx = decf(rmax_s[row]);
            const float dgv = diag_s[row];
#pragma unroll
            for (int jt = 0; jt < 4; jt++) {
                const int j = wv * 64 + jt * 16 + lm;
                float v = RATIO * (expf(fminf(NORMC * s4[nt][jt][rr] - dgv - rmx, 0.f)) + KEPS);
                qp_s[row * 260 + j] = (_Float16)v;
                s4[nt][jt][rr] = v * ksum_s[j];
            }
            float ds = s4[nt][0][rr] + s4[nt][1][rr] + s4[nt][2][rr] + s4[nt][3][rr];
            ds += __shfl_xor(ds, 1, 64);
            ds += __shfl_xor(ds, 2, 64);
            ds += __shfl_xor(ds, 4, 64);
            ds += __shfl_xor(ds, 8, 64);
            if (lm == 0) atomicAdd(&denom_s[row], ds);
        }
    }
    __syncthreads();
    floatx4 acc2[4];
#pragma unroll
    for (int nt = 0; nt < 4; nt++) acc2[nt] = (floatx4){0.f, 0.f, 0.f, 0.f};
#pragma unroll
    for (int ks = 0; ks < 8; ks++) {
        half8 bfv = *(const half8*)(ct + (wv * 16 + lm) * 256 + ks * 32 + lq * 8);
#pragma unroll
        for (int nt = 0; nt < 4; nt++) {
            half8 af = *(half8*)&qp_s[(nt * 16 + lm) * 260 + ks * 32 + lq * 8];
            acc2[nt] = __builtin_amdgcn_mfma_f32_16x16x32_f16(af, bfv, acc2[nt], 0, 0, 0);
        }
    }
#pragma unroll
    for (int nt = 0; nt < 4; nt++) {
#pragma unroll
        for (int rr = 0; rr < 4; rr++) {
            const int row = nt * 16 + lq * 4 + rr;
            const float inv = 1.0f / fmaxf(denom_s[row], 1e-30f);
            attG[((size_t)(b * 8192 + n0 + row)) * 384 + h * 64 + wv * 16 + lm] =
                (_Float16)(acc2[nt][rr] * inv);
        }
    }
}

// ---------------- local windowed attention, heads 6..7 (pre-RoPE'd, reg-prefetch) -------
__launch_bounds__(256)
__global__ void k_local(float* __restrict__ ws) {
    __shared__ _Float16 Kh[64 * 68];     // K chunk [k][d]
    __shared__ _Float16 Vt[64 * 68];     // V chunk transposed [d][k]
    __shared__ _Float16 pT[64 * 68];     // P [q][k] fp16
    const int bhp = blockIdx.x, b = bhp >> 1, lh = bhp & 1, h = 6 + lh;
    const int tile = blockIdx.y;
    const int w = tile >> 2;
    const int q0 = tile * 64;
    const _Float16* __restrict__ Qr = (const _Float16*)(ws + O_QR) + (size_t)(b * 2 + lh) * 8192 * 64;
    const _Float16* __restrict__ Kr = (const _Float16*)(ws + O_KR) + (size_t)(b * 2 + lh) * 8192 * 64;
    const _Float16* __restrict__ Vb = (const _Float16*)(ws + O_V) + (size_t)(b * 8 + h) * 8192 * 64;
    const int tid = threadIdx.x;
    const int wv = tid >> 6, lane = tid & 63, lm = lane & 15, lq = lane >> 4;
    const int row = tid >> 2, dqo = (tid & 3) * 16;     // K staging mapping
    const int vd = lane, vnb = wv * 16;                 // V staging mapping

    // Q fragment fixed per lane for all chunks (rows wave-private)
    const _Float16* qrow = Qr + (size_t)(q0 + wv * 16 + lm) * 64 + lq * 8;
    const half8 aq0 = *(const half8*)(qrow);
    const half8 aq1 = *(const half8*)(qrow + 32);

    const int clo = (w == 0) ? 4 : 0;
    const int chi = min(12, 132 - 4 * w);
    half8 kb0, kb1;
    _Float16 vb[16];
    {   // prefetch first chunk
        const int kp0 = (w - 1) * 256 + clo * 64;
        const _Float16* kp = Kr + (size_t)(kp0 + row) * 64 + dqo;
        kb0 = *(const half8*)(kp);
        kb1 = *(const half8*)(kp + 8);
#pragma unroll
        for (int i = 0; i < 16; i++) vb[i] = Vb[(size_t)(kp0 + vnb + i) * 64 + vd];
    }
    floatx4 O[4];
#pragma unroll
    for (int df = 0; df < 4; df++) O[df] = (floatx4){0.f, 0.f, 0.f, 0.f};
    float m_run[4] = {-1e30f, -1e30f, -1e30f, -1e30f};
    float l_run[4] = {0.f, 0.f, 0.f, 0.f};

    for (int c = clo; c < chi; c++) {
        if (c > clo) __syncthreads();    // prev chunk's Vt/pT reads done
        *(half8*)&Kh[row * 68 + dqo]     = kb0;
        *(half8*)&Kh[row * 68 + dqo + 8] = kb1;
        *(half8*)&Vt[vd * 68 + vnb]     = *(half8*)&vb[0];
        *(half8*)&Vt[vd * 68 + vnb + 8] = *(half8*)&vb[8];
        __syncthreads();                 // Kh/Vt ready
        if (c + 1 < chi) {               // prefetch next (overlaps compute)
            const int kp0 = (w - 1) * 256 + (c + 1) * 64;
            const _Float16* kp = Kr + (size_t)(kp0 + row) * 64 + dqo;
            kb0 = *(const half8*)(kp);
            kb1 = *(const half8*)(kp + 8);
#pragma unroll
            for (int i = 0; i < 16; i++) vb[i] = Vb[(size_t)(kp0 + vnb + i) * 64 + vd];
        }
        // QK^T: M=16 q (this wave), N=64 k, K=64 d
        floatx4 s4[4];
#pragma unroll
        for (int nf = 0; nf < 4; nf++) s4[nf] = (floatx4){0.f, 0.f, 0.f, 0.f};
#pragma unroll
        for (int ks = 0; ks < 2; ks++) {
            half8 aq = ks ? aq1 : aq0;
            half8 bf[4];
#pragma unroll
            for (int nf = 0; nf < 4; nf++)
                bf[nf] = *(half8*)&Kh[(nf * 16 + lm) * 68 + ks * 32 + lq * 8];
#pragma unroll
            for (int nf = 0; nf < 4; nf++)
                s4[nf] = __builtin_amdgcn_mfma_f32_16x16x32_f16(aq, bf[nf], s4[nf], 0, 0, 0);
        }
        // online softmax in registers; scale = 0.125
        float p[4][4];
#pragma unroll
        for (int rr = 0; rr < 4; rr++) {
            float m0 = fmaxf(fmaxf(s4[0][rr], s4[1][rr]), fmaxf(s4[2][rr], s4[3][rr]));
            m0 = fmaxf(m0, __shfl_xor(m0, 1, 64));
            m0 = fmaxf(m0, __shfl_xor(m0, 2, 64));
            m0 = fmaxf(m0, __shfl_xor(m0, 4, 64));
            m0 = fmaxf(m0, __shfl_xor(m0, 8, 64));
            const float mn = fmaxf(m_run[rr], m0 * 0.125f);
            const float al = expf(m_run[rr] - mn);
            m_run[rr] = mn;
            float rs = 0.f;
#pragma unroll
            for (int nf = 0; nf < 4; nf++) {
                float pv = expf(fmaf(s4[nf][rr], 0.125f, -mn));
                p[nf][rr] = pv;
                rs += pv;
            }
            l_run[rr] = l_run[rr] * al + rs;
#pragma unroll
            for (int df = 0; df < 4; df++) O[df][rr] *= al;
        }
        // P -> LDS (wave-private rows)
#pragma unroll
        for (int nf = 0; nf < 4; nf++)
#pragma unroll
            for (int rr = 0; rr < 4; rr++)
                pT[(wv * 16 + lq * 4 + rr) * 68 + nf * 16 + lm] = (_Float16)p[nf][rr];
        asm volatile("s_waitcnt lgkmcnt(0)" ::: "memory");   // own pT writes done
        // PV: M=16 q, N=64 d, K=64 k
#pragma unroll
        for (int ks = 0; ks < 2; ks++) {
            half8 ap = *(half8*)&pT[(wv * 16 + lm) * 68 + ks * 32 + lq * 8];
            half8 bf[4];
#pragma unroll
            for (int df = 0; df < 4; df++)
                bf[df] = *(half8*)&Vt[(df * 16 + lm) * 68 + ks * 32 + lq * 8];
#pragma unroll
            for (int df = 0; df < 4; df++)
                O[df] = __builtin_amdgcn_mfma_f32_16x16x32_f16(ap, bf[df], O[df], 0, 0, 0);
        }
    }
#pragma unroll
    for (int rr = 0; rr < 4; rr++) {
        l_run[rr] += __shfl_xor(l_run[rr], 1, 64);
        l_run[rr] += __shfl_xor(l_run[rr], 2, 64);
        l_run[rr] += __shfl_xor(l_run[rr], 4, 64);
        l_run[rr] += __shfl_xor(l_run[rr], 8, 64);
        l_run[rr] = 1.f / fmaxf(l_run[rr], 1e-30f);
    }
    _Float16* __restrict__ attL = (_Float16*)(ws + O_ATTL);
#pragma unroll
    for (int df = 0; df < 4; df++) {
#pragma unroll
        for (int rr = 0; rr < 4; rr++) {
            const int q = q0 + wv * 16 + lq * 4 + rr;
            attL[((size_t)(b * 2 + lh) * 8192 + q) * 64 + df * 16 + lm] =
                (_Float16)(O[df][rr] * l_run[rr]);
        }
    }
}

// ---------------- output projection + bias (fp16 MFMA) ----------------
__launch_bounds__(256)
__global__ void k_out(const float* __restrict__ bo,
                      const float* __restrict__ ws,
                      float* __restrict__ out) {
    __shared__ _Float16 Ah[128 * 72];
    __shared__ _Float16 Bh[128 * 72];
    const _Float16* __restrict__ attG = (const _Float16*)(ws + O_K);
    const _Float16* __restrict__ attL = (const _Float16*)(ws + O_ATTL);
    const _Float16* __restrict__ WoT = (const _Float16*)(ws + O_CTX);
    const int r0 = blockIdx.x * 128, c0 = blockIdx.y * 128;
    const int tid = threadIdx.x;
    const int wv = tid >> 6, lane = tid & 63, lm = lane & 15, lq = lane >> 4;
    const int srow = tid >> 1, skoff = (tid & 1) * 32;
    floatx4 acc[2][8];
#pragma unroll
    for (int m = 0; m < 2; m++)
#pragma unroll
        for (int n = 0; n < 8; n++) acc[m][n] = (floatx4){0.f, 0.f, 0.f, 0.f};

    for (int c = 0; c < 8; c++) {
        const int k0 = c * 64;
        {
            const int row = r0 + srow;
            const int kk = k0 + skoff;
            const _Float16* ap;
            if (kk < 384) {
                ap = attG + (size_t)row * 384 + kk;
            } else {
                const int bb = row >> 13, nn = row & 8191;
                const int kr = kk - 384;
                ap = attL + ((size_t)(bb * 2 + (kr >> 6)) * 8192 + nn) * 64 + (kr & 63);
            }
#pragma unroll
            for (int q = 0; q < 4; q++)
                *(uint4*)&Ah[srow * 72 + skoff + 8 * q] = *(const uint4*)(ap + 8 * q);
        }
        {
            const _Float16* bp = WoT + (size_t)(c0 + srow) * 512 + k0 + skoff;
#pragma unroll
            for (int q = 0; q < 4; q++)
                *(uint4*)&Bh[srow * 72 + skoff + 8 * q] = *(const uint4*)(bp + 8 * q);
        }
        __syncthreads();
#pragma unroll
        for (int ks = 0; ks < 2; ks++) {
            half8 af[2], bf[8];
            af[0] = *(half8*)&Ah[(wv * 32 + lm) * 72 + ks * 32 + lq * 8];
            af[1] = *(half8*)&Ah[(wv * 32 + 16 + lm) * 72 + ks * 32 + lq * 8];
#pragma unroll
            for (int n = 0; n < 8; n++)
                bf[n] = *(half8*)&Bh[(n * 16 + lm) * 72 + ks * 32 + lq * 8];
#pragma unroll
            for (int m = 0; m < 2; m++)
#pragma unroll
                for (int n = 0; n < 8; n++)
                    acc[m][n] = __builtin_amdgcn_mfma_f32_16x16x32_f16(af[m], bf[n], acc[m][n], 0, 0, 0);
        }
        __syncthreads();
    }
#pragma unroll
    for (int n = 0; n < 8; n++) {
        const int col = c0 + n * 16 + lm;
        const float bias = bo[col];
#pragma unroll
        for (int m = 0; m < 2; m++) {
            const int rbase = r0 + wv * 32 + m * 16 + lq * 4;
#pragma unroll
            for (int j = 0; j < 4; j++)
                out[(size_t)(rbase + j) * 512 + col] = acc[m][n][j] + bias;
        }
    }
}

extern "C" void kernel_launch(void* const* d_in, const int* in_sizes, int n_in,
                              void* d_out, int out_size, void* d_ws, size_t ws_size,
                              hipStream_t stream) {
    const float* x    = (const float*)d_in[0];
    const float* Wq   = (const float*)d_in[1];
    const float* Wk   = (const float*)d_in[2];
    const float* Wv   = (const float*)d_in[3];
    const float* Wo   = (const float*)d_in[4];
    const float* bo   = (const float*)d_in[5];
    const float* proj = (const float*)d_in[6];
    float* ws = (float*)d_ws;
    float* out = (float*)d_out;

    hipMemsetAsync(d_ws, 0, (size_t)O_ZEND * 4, stream);                 // kmax/ksum/ctx
    hipLaunchKernelGGL(k_rope,   dim3(1024), dim3(256), 0, stream, ws);
    hipLaunchKernelGGL(k_half_x, dim3(4096), dim3(256), 0, stream, x, ws);
    hipLaunchKernelGGL(k_half_w, dim3(8, 8, 3), dim3(256), 0, stream, Wq, Wk, Wv, ws);
    hipLaunchKernelGGL(k_qkv,    dim3(128, 4, 3), dim3(256), 0, stream, ws);
    hipLaunchKernelGGL(k_ropeqk, dim3(512), dim3(256), 0, stream, ws);      // RoPE'd Q/K once
    hipLaunchKernelGGL(k_half_p, dim3(8), dim3(256), 0, stream, proj, ws);
    hipLaunchKernelGGL(k_kmax,   dim3(12, 128), dim3(256), 0, stream, ws);
    hipLaunchKernelGGL(k_kctx,   dim3(12, 32, 2), dim3(256), 0, stream, ws);
    hipLaunchKernelGGL(k_ctxt,   dim3(12, 4), dim3(256), 0, stream, ws);    // ctx -> ctxT fp16
    hipLaunchKernelGGL(k_local,  dim3(4, 128), dim3(256), 0, stream, ws);   // before k_qout!
    hipLaunchKernelGGL(k_qout,   dim3(12, 128), dim3(256), 0, stream, ws);
    hipLaunchKernelGGL(k_half_wo, dim3(8, 8), dim3(256), 0, stream, Wo, ws); // ctx dead -> WoT
    hipLaunchKernelGGL(k_out,    dim3(128, 4), dim3(256), 0, stream, bo, ws, out);
}

// Round 7
// 302.379 us; speedup vs baseline: 2.2046x; 1.0720x over previous
//
#include <hip/hip_runtime.h>

// ---------------- constants ----------------
#define NTOK 8192
#define NORMC 0.35355339059327373f   // 64^-0.25
#define RATIO 0.0625f                // 256^-0.5
#define KEPS  1e-4f

// ws offsets in 4-byte elements (total 27987008)
#define O_KMAX 0                      // 12 x u32 (encoded max)
#define O_KSUM 64                     // 12*256 f32  (zeroed region ends 3136)
#define O_CTX  3136                   // now only reused as WoT fp16 [512][512] after k_qout
#define O_COS  199744                 // 8192*32
#define O_SIN  461888                 // 8192*32
#define O_Q    724032                 // fp16 [2][8][8192][64] -> ends 4918336
#define O_K    9112640                // fp16 K [9112640,13306944); later attG fp16 [16384][384]
#define O_XH   13306944               // fp16 x [16384][512] (dead after k_qkv)
// O_CPART: fp16 ctx partials [12][2][32][128][64] (3145728 f32) in dead XH region
#define O_CPART 13306944              // ends 16452672 < 17501248
#define O_V    17501248               // fp16 V [17501248,21695552)
#define O_QR   21695552               // fp16 RoPE'd Q heads6-7 [2][2][8192][64] -> 22744128
#define O_KR   22744128               // fp16 RoPE'd K heads6-7 -> 23792704
#define O_ATTL 25889856               // fp16 [2][2][8192][64] (ends 26938432)
#define O_WH   25889856               // fp16 W^T [3][512][512] (dead after k_qkv)
#define O_PH   26938432               // fp16 proj [256][64] (8192 f32)
#define O_CTXT 26946624               // fp16 ctxT [12][64][256] (98304 f32) -> 27044928
// end of use: 27044928 < 27987008

typedef _Float16 half8 __attribute__((ext_vector_type(8)));
typedef _Float16 half4h __attribute__((ext_vector_type(4)));
typedef float floatx4 __attribute__((ext_vector_type(4)));

__device__ __forceinline__ unsigned encf(float f) {
    unsigned u = __float_as_uint(f);
    return (u & 0x80000000u) ? ~u : (u | 0x80000000u);
}
__device__ __forceinline__ float decf(unsigned u) {
    return (u & 0x80000000u) ? __uint_as_float(u & 0x7fffffffu) : __uint_as_float(~u);
}
__device__ __forceinline__ float sumsq8(half8 h) {
    float s = 0.f;
#pragma unroll
    for (int i = 0; i < 8; i++) { float v = (float)h[i]; s = fmaf(v, v, s); }
    return s;
}

// ---------------- RoPE tables (double precision angles) ----------------
__global__ void k_rope(float* __restrict__ ws) {
    int idx = blockIdx.x * 256 + threadIdx.x;      // 8192*32
    int t = idx >> 5, i = idx & 31;
    double invf = pow(10000.0, -(double)(2 * i) / 64.0);
    double ang = (double)t * invf;
    ws[O_COS + idx] = (float)cos(ang);
    ws[O_SIN + idx] = (float)sin(ang);
}

// ---------------- x -> fp16 ----------------
__launch_bounds__(256)
__global__ void k_half_x(const float* __restrict__ x, float* __restrict__ ws) {
    const int idx = blockIdx.x * 256 + threadIdx.x;   // *8 elements
    const float* p = x + (size_t)idx * 8;
    float4 a = *(const float4*)p, b = *(const float4*)(p + 4);
    half8 h = {(_Float16)a.x, (_Float16)a.y, (_Float16)a.z, (_Float16)a.w,
               (_Float16)b.x, (_Float16)b.y, (_Float16)b.z, (_Float16)b.w};
    *(half8*)((_Float16*)(ws + O_XH) + (size_t)idx * 8) = h;
}

// ---------------- proj -> fp16 [256][64] ----------------
__launch_bounds__(256)
__global__ void k_half_p(const float* __restrict__ proj, float* __restrict__ ws) {
    const int idx = blockIdx.x * 256 + threadIdx.x;
    const float* p = proj + (size_t)idx * 8;
    float4 a = *(const float4*)p, b = *(const float4*)(p + 4);
    half8 h = {(_Float16)a.x, (_Float16)a.y, (_Float16)a.z, (_Float16)a.w,
               (_Float16)b.x, (_Float16)b.y, (_Float16)b.z, (_Float16)b.w};
    *(half8*)((_Float16*)(ws + O_PH) + (size_t)idx * 8) = h;
}

// ---------------- RoPE'd Q/K fp16 for local heads 6..7, precomputed once ----------------
__launch_bounds__(256)
__global__ void k_ropeqk(float* __restrict__ ws) {
    const int idx = blockIdx.x * 256 + threadIdx.x;   // 32768 rows * 4 thr/row
    const int rg = idx >> 2, dqo = (idx & 3) * 16;
    const int b = rg >> 14, lh = (rg >> 13) & 1, n = rg & 8191;
    const int h = 6 + lh;
    const int e = dqo & 31;
    const int comp = (dqo < 32) ? dqo + 32 : dqo - 32;
    const float sgn = (dqo < 32) ? -1.f : 1.f;
    const _Float16* Qs = (const _Float16*)(ws + O_Q) + ((size_t)(b * 8 + h) * 8192 + n) * 64;
    const _Float16* Ks = (const _Float16*)(ws + O_K) + ((size_t)(b * 8 + h) * 8192 + n) * 64;
    _Float16* Qd = (_Float16*)(ws + O_QR) + ((size_t)(b * 2 + lh) * 8192 + n) * 64;
    _Float16* Kd = (_Float16*)(ws + O_KR) + ((size_t)(b * 2 + lh) * 8192 + n) * 64;
    const float* cp = ws + O_COS + n * 32 + e;
    const float* sp = ws + O_SIN + n * 32 + e;
    _Float16 tq[16], tk[16];
#pragma unroll
    for (int w4 = 0; w4 < 4; w4++) {
        float4 c4 = *(const float4*)(cp + 4 * w4);
        float4 s4v = *(const float4*)(sp + 4 * w4);
        half4h qa = *(const half4h*)(Qs + dqo + 4 * w4);
        half4h qb = *(const half4h*)(Qs + comp + 4 * w4);
        half4h ka = *(const half4h*)(Ks + dqo + 4 * w4);
        half4h kb = *(const half4h*)(Ks + comp + 4 * w4);
        tq[4*w4+0] = (_Float16)fmaf(sgn * (float)qb[0], s4v.x, (float)qa[0] * c4.x);
        tq[4*w4+1] = (_Float16)fmaf(sgn * (float)qb[1], s4v.y, (float)qa[1] * c4.y);
        tq[4*w4+2] = (_Float16)fmaf(sgn * (float)qb[2], s4v.z, (float)qa[2] * c4.z);
        tq[4*w4+3] = (_Float16)fmaf(sgn * (float)qb[3], s4v.w, (float)qa[3] * c4.w);
        tk[4*w4+0] = (_Float16)fmaf(sgn * (float)kb[0], s4v.x, (float)ka[0] * c4.x);
        tk[4*w4+1] = (_Float16)fmaf(sgn * (float)kb[1], s4v.y, (float)ka[1] * c4.y);
        tk[4*w4+2] = (_Float16)fmaf(sgn * (float)kb[2], s4v.z, (float)ka[2] * c4.z);
        tk[4*w4+3] = (_Float16)fmaf(sgn * (float)kb[3], s4v.w, (float)ka[3] * c4.w);
    }
    *(half8*)(Qd + dqo)     = *(half8*)&tq[0];
    *(half8*)(Qd + dqo + 8) = *(half8*)&tq[8];
    *(half8*)(Kd + dqo)     = *(half8*)&tk[0];
    *(half8*)(Kd + dqo + 8) = *(half8*)&tk[8];
}

// ---------------- ctx partials fp16 [12][2][32][128][64] -> ctxT fp16 [12][64][256] ------
__launch_bounds__(256)
__global__ void k_ctxt(float* __restrict__ ws) {
    __shared__ float T[16][65];
    const int bh = blockIdx.x, j0 = blockIdx.y * 16;      // 16 j per block
    const int jh = j0 >> 7, jrel0 = j0 & 127;
    const _Float16* __restrict__ pp =
        (const _Float16*)(ws + O_CPART) + ((size_t)(bh * 2 + jh) * 32) * 8192;
    _Float16* __restrict__ ct = (_Float16*)(ws + O_CTXT) + (size_t)bh * 16384;
    const int tid = threadIdx.x;
    const int lx = tid & 63, ly = tid >> 6;               // lx=d, ly covers 4 j
#pragma unroll
    for (int i = 0; i < 4; i++) {
        const int jl = ly * 4 + i;
        float s = 0.f;
#pragma unroll 8
        for (int sl = 0; sl < 32; sl++)
            s += (float)pp[((size_t)sl * 128 + jrel0 + jl) * 64 + lx];
        T[jl][lx] = s;
    }
    __syncthreads();
    // write ctxT[d][j0..j0+15]: 4 threads per d, 4 consecutive j each (8B stores)
    const int d = tid >> 2, j4 = (tid & 3) * 4;
    half4h v;
#pragma unroll
    for (int ii = 0; ii < 4; ii++) v[ii] = (_Float16)T[j4 + ii][d];
    *(half4h*)(ct + d * 256 + j0 + j4) = v;
}

// ---------------- W -> fp16, transposed to [n][k] ----------------
__launch_bounds__(256)
__global__ void k_half_w(const float* __restrict__ Wq,
                         const float* __restrict__ Wk,
                         const float* __restrict__ Wv,
                         float* __restrict__ ws) {
    __shared__ float T[64][65];
    const int z = blockIdx.z;
    const float* __restrict__ W = (z == 0) ? Wq : ((z == 1) ? Wk : Wv);
    _Float16* __restrict__ Wt = (_Float16*)(ws + O_WH) + (size_t)z * 262144;
    const int k0 = blockIdx.x * 64, n0 = blockIdx.y * 64;
    const int lx = threadIdx.x & 63, ly = threadIdx.x >> 6;
#pragma unroll
    for (int i = 0; i < 16; i++) {
        const int kk = ly * 16 + i;
        T[lx][kk] = W[(k0 + kk) * 512 + n0 + lx];
    }
    __syncthreads();
#pragma unroll
    for (int i = 0; i < 16; i++) {
        const int nn = ly * 16 + i;
        Wt[(n0 + nn) * 512 + k0 + lx] = (_Float16)T[nn][lx];
    }
}

// ---------------- Wo -> fp16 transposed [n][k], into dead ctx region ----------------
__launch_bounds__(256)
__global__ void k_half_wo(const float* __restrict__ Wo, float* __restrict__ ws) {
    __shared__ float T[64][65];
    _Float16* __restrict__ Wt = (_Float16*)(ws + O_CTX);
    const int k0 = blockIdx.x * 64, n0 = blockIdx.y * 64;
    const int lx = threadIdx.x & 63, ly = threadIdx.x >> 6;
#pragma unroll
    for (int i = 0; i < 16; i++) {
        const int kk = ly * 16 + i;
        T[lx][kk] = Wo[(k0 + kk) * 512 + n0 + lx];
    }
    __syncthreads();
#pragma unroll
    for (int i = 0; i < 16; i++) {
        const int nn = ly * 16 + i;
        Wt[(n0 + nn) * 512 + k0 + lx] = (_Float16)T[nn][lx];
    }
}

// ---------------- QKV projection via fp16 MFMA (fp16 in, fp16 out) ----------------
__launch_bounds__(256)
__global__ void k_qkv(float* __restrict__ ws) {
    __shared__ _Float16 Ah[128 * 72];
    __shared__ _Float16 Bh[128 * 72];
    const int z = blockIdx.z;
    const _Float16* __restrict__ xh = (const _Float16*)(ws + O_XH);
    const _Float16* __restrict__ Wt = (const _Float16*)(ws + O_WH) + (size_t)z * 262144;
    _Float16* __restrict__ out = (_Float16*)(ws + ((z == 0) ? O_Q : ((z == 1) ? O_K : O_V)));
    const int r0 = blockIdx.x * 128, c0 = blockIdx.y * 128;
    const int tid = threadIdx.x;
    const int wv = tid >> 6, lane = tid & 63, lm = lane & 15, lq = lane >> 4;
    const int srow = tid >> 1, skoff = (tid & 1) * 32;
    floatx4 acc[2][8];
#pragma unroll
    for (int m = 0; m < 2; m++)
#pragma unroll
        for (int n = 0; n < 8; n++) acc[m][n] = (floatx4){0.f, 0.f, 0.f, 0.f};

    for (int c = 0; c < 8; c++) {
        const int k0 = c * 64;
        {
            const _Float16* ap = xh + (size_t)(r0 + srow) * 512 + k0 + skoff;
#pragma unroll
            for (int q = 0; q < 4; q++)
                *(uint4*)&Ah[srow * 72 + skoff + 8 * q] = *(const uint4*)(ap + 8 * q);
        }
        {
            const _Float16* bp = Wt + (size_t)(c0 + srow) * 512 + k0 + skoff;
#pragma unroll
            for (int q = 0; q < 4; q++)
                *(uint4*)&Bh[srow * 72 + skoff + 8 * q] = *(const uint4*)(bp + 8 * q);
        }
        __syncthreads();
#pragma unroll
        for (int ks = 0; ks < 2; ks++) {
            half8 af[2], bf[8];
            af[0] = *(half8*)&Ah[(wv * 32 + lm) * 72 + ks * 32 + lq * 8];
            af[1] = *(half8*)&Ah[(wv * 32 + 16 + lm) * 72 + ks * 32 + lq * 8];
#pragma unroll
            for (int n = 0; n < 8; n++)
                bf[n] = *(half8*)&Bh[(n * 16 + lm) * 72 + ks * 32 + lq * 8];
#pragma unroll
            for (int m = 0; m < 2; m++)
#pragma unroll
                for (int n = 0; n < 8; n++)
                    acc[m][n] = __builtin_amdgcn_mfma_f32_16x16x32_f16(af[m], bf[n], acc[m][n], 0, 0, 0);
        }
        __syncthreads();
    }
    const int bi = r0 >> 13;
#pragma unroll
    for (int n = 0; n < 8; n++) {
        const int col = c0 + n * 16 + lm;
        const int h = col >> 6, d = col & 63;
#pragma unroll
        for (int m = 0; m < 2; m++) {
            const int rbase = r0 + wv * 32 + m * 16 + lq * 4;
#pragma unroll
            for (int j = 0; j < 4; j++) {
                const int ng = (rbase + j) & 8191;
                out[((size_t)(bi * 8 + h) * 8192 + ng) * 64 + d] = (_Float16)acc[m][n][j];
            }
        }
    }
}

// ---------------- key-side global max of dd = norm*(K.projT) (fp16 MFMA) ----------------
__launch_bounds__(256)
__global__ void k_kmax(float* __restrict__ ws) {
    __shared__ _Float16 Kh[64 * 68];
    __shared__ unsigned bmax;
    const int bh = blockIdx.x, b = bh / 6, h = bh % 6;
    const _Float16* __restrict__ Kp = (const _Float16*)(ws + O_K) + (size_t)(b * 8 + h) * 8192 * 64;
    const _Float16* __restrict__ projh = (const _Float16*)(ws + O_PH);
    const int n0 = blockIdx.y * 64;
    const int tid = threadIdx.x;
    const int wv = tid >> 6, lane = tid & 63, lm = lane & 15, lq = lane >> 4;
    if (tid == 0) bmax = 0u;
    {
        const int r = tid >> 2, dq = (tid & 3) * 16;
        const _Float16* kpp = Kp + (size_t)(n0 + r) * 64 + dq;
        *(uint4*)&Kh[r * 68 + dq]     = *(const uint4*)(kpp);
        *(uint4*)&Kh[r * 68 + dq + 8] = *(const uint4*)(kpp + 8);
    }
    __syncthreads();
    floatx4 s4[4][4];
#pragma unroll
    for (int nt = 0; nt < 4; nt++)
#pragma unroll
        for (int jt = 0; jt < 4; jt++) s4[nt][jt] = (floatx4){0.f, 0.f, 0.f, 0.f};
#pragma unroll
    for (int ks = 0; ks < 2; ks++) {
        half8 af[4], bf[4];
#pragma unroll
        for (int nt = 0; nt < 4; nt++)
            af[nt] = *(half8*)&Kh[(nt * 16 + lm) * 68 + ks * 32 + lq * 8];
#pragma unroll
        for (int jt = 0; jt < 4; jt++)
            bf[jt] = *(const half8*)(projh + (wv * 64 + jt * 16 + lm) * 64 + ks * 32 + lq * 8);
#pragma unroll
        for (int nt = 0; nt < 4; nt++)
#pragma unroll
            for (int jt = 0; jt < 4; jt++)
                s4[nt][jt] = __builtin_amdgcn_mfma_f32_16x16x32_f16(af[nt], bf[jt], s4[nt][jt], 0, 0, 0);
    }
    float m = -1e30f;
#pragma unroll
    for (int nt = 0; nt < 4; nt++)
#pragma unroll
        for (int jt = 0; jt < 4; jt++)
#pragma unroll
            for (int r = 0; r < 4; r++) m = fmaxf(m, s4[nt][jt][r]);
    m = fmaxf(m, __shfl_xor(m, 1, 64));
    m = fmaxf(m, __shfl_xor(m, 2, 64));
    m = fmaxf(m, __shfl_xor(m, 4, 64));
    m = fmaxf(m, __shfl_xor(m, 8, 64));
    m = fmaxf(m, __shfl_xor(m, 16, 64));
    m = fmaxf(m, __shfl_xor(m, 32, 64));
    if (lane == 0) atomicMax(&bmax, encf(m * NORMC));
    __syncthreads();
    if (tid == 0) atomicMax((unsigned*)ws + O_KMAX + bh, bmax);
}

// ---------------- key-side: kp, k_sum, ctx partials (fp16 MFMA, no global atomics) ------
__launch_bounds__(256)
__global__ void k_kctx(float* __restrict__ ws) {
    __shared__ _Float16 Kh[64 * 68];
    __shared__ _Float16 Vt[64 * 68];
    __shared__ _Float16 kpt[128 * 68];
    __shared__ float diag4[64][4];
    __shared__ float ksum_s[128];
    const int bh = blockIdx.x, b = bh / 6, h = bh % 6;
    const int n0 = blockIdx.y * 256;
    const int jh = blockIdx.z;
    const _Float16* __restrict__ Kp = (const _Float16*)(ws + O_K) + (size_t)(b * 8 + h) * 8192 * 64;
    const _Float16* __restrict__ Vp = (const _Float16*)(ws + O_V) + (size_t)(b * 8 + h) * 8192 * 64;
    const _Float16* __restrict__ projh = (const _Float16*)(ws + O_PH);
    const float kmax = decf(((const unsigned*)ws)[O_KMAX + bh]);
    const int tid = threadIdx.x;
    const int wv = tid >> 6, lane = tid & 63, lm = lane & 15, lq = lane >> 4;
    if (tid < 128) ksum_s[tid] = 0.f;

    floatx4 acc[2][4];
#pragma unroll
    for (int jt = 0; jt < 2; jt++)
#pragma unroll
        for (int dt = 0; dt < 4; dt++) acc[jt][dt] = (floatx4){0.f, 0.f, 0.f, 0.f};

    for (int nc = 0; nc < 4; nc++) {
        const int ns = n0 + nc * 64;
        if (nc) __syncthreads();                  // D: prev chunk's LDS reads done
        {   // stage Kh [n][d] fp16 copy + diag partials
            const int r = tid >> 2, dq = (tid & 3) * 16;
            const _Float16* kpp = Kp + (size_t)(ns + r) * 64 + dq;
            half8 h0 = *(const half8*)(kpp);
            half8 h1 = *(const half8*)(kpp + 8);
            *(half8*)&Kh[r * 68 + dq]     = h0;
            *(half8*)&Kh[r * 68 + dq + 8] = h1;
            diag4[r][tid & 3] = sumsq8(h0) + sumsq8(h1);
        }
        {   // stage Vt transposed [d][n]
            const int d = tid & 63, nb = (tid >> 6) * 16;
            _Float16 t[16];
#pragma unroll
            for (int i = 0; i < 16; i++)
                t[i] = Vp[(size_t)(ns + nb + i) * 64 + d];
            *(half8*)&Vt[d * 68 + nb]     = *(half8*)&t[0];
            *(half8*)&Vt[d * 68 + nb + 8] = *(half8*)&t[8];
        }
        __syncthreads();                          // A: staging visible
        // dd[n][j]: M=64 n, N=32 j (this wave), K=64
        floatx4 s4[4][2];
#pragma unroll
        for (int nt = 0; nt < 4; nt++)
#pragma unroll
            for (int jt = 0; jt < 2; jt++) s4[nt][jt] = (floatx4){0.f, 0.f, 0.f, 0.f};
#pragma unroll
        for (int ks = 0; ks < 2; ks++) {
            half8 af[4], bf[2];
#pragma unroll
            for (int nt = 0; nt < 4; nt++)
                af[nt] = *(half8*)&Kh[(nt * 16 + lm) * 68 + ks * 32 + lq * 8];
#pragma unroll
            for (int jt = 0; jt < 2; jt++)
                bf[jt] = *(const half8*)(projh + (jh * 128 + wv * 32 + jt * 16 + lm) * 64 + ks * 32 + lq * 8);
#pragma unroll
            for (int nt = 0; nt < 4; nt++)
#pragma unroll
                for (int jt = 0; jt < 2; jt++)
                    s4[nt][jt] = __builtin_amdgcn_mfma_f32_16x16x32_f16(af[nt], bf[jt], s4[nt][jt], 0, 0, 0);
        }
        // exp; kp -> kpt (WAVE-PRIVATE rows)
        float jsum[2] = {0.f, 0.f};
#pragma unroll
        for (int nt = 0; nt < 4; nt++) {
            float dg[4];
#pragma unroll
            for (int rr = 0; rr < 4; rr++) {
                float4 d4 = *(float4*)diag4[nt * 16 + lq * 4 + rr];
                dg[rr] = (d4.x + d4.y + d4.z + d4.w) * 0.0625f;
            }
#pragma unroll
            for (int jt = 0; jt < 2; jt++) {
                half4h kv;
#pragma unroll
                for (int rr = 0; rr < 4; rr++) {
                    float v = RATIO * (__expf(fminf(NORMC * s4[nt][jt][rr] - dg[rr] - kmax, 0.f)) + KEPS);
                    jsum[jt] += v;
                    kv[rr] = (_Float16)v;
                }
                *(half4h*)&kpt[(wv * 32 + jt * 16 + lm) * 68 + nt * 16 + lq * 4] = kv;
            }
        }
#pragma unroll
        for (int jt = 0; jt < 2; jt++)
            atomicAdd(&ksum_s[wv * 32 + jt * 16 + lm], jsum[jt]);
        // kpt rows are wave-private -> own-wave LDS drain suffices (no barrier)
        asm volatile("s_waitcnt lgkmcnt(0)" ::: "memory");
        // ctx[j][d] += kp^T @ V: M=32 j (this wave), N=64 d, K=64 n
#pragma unroll
        for (int ks = 0; ks < 2; ks++) {
            half8 af[2], bf[4];
#pragma unroll
            for (int jt = 0; jt < 2; jt++)
                af[jt] = *(half8*)&kpt[(wv * 32 + jt * 16 + lm) * 68 + ks * 32 + lq * 8];
#pragma unroll
            for (int dt = 0; dt < 4; dt++)
                bf[dt] = *(half8*)&Vt[(dt * 16 + lm) * 68 + ks * 32 + lq * 8];
#pragma unroll
            for (int jt = 0; jt < 2; jt++)
#pragma unroll
                for (int dt = 0; dt < 4; dt++)
                    acc[jt][dt] = __builtin_amdgcn_mfma_f32_16x16x32_f16(af[jt], bf[dt], acc[jt][dt], 0, 0, 0);
        }
    }
    __syncthreads();   // ksum_s complete
    // flush ctx partial as PLAIN fp16 stores (no cross-XCD atomics)
    _Float16* __restrict__ cp = (_Float16*)(ws + O_CPART) +
        (((size_t)(bh * 2 + jh) * 32 + blockIdx.y) * 128) * 64;
#pragma unroll
    for (int jt = 0; jt < 2; jt++) {
#pragma unroll
        for (int dt = 0; dt < 4; dt++) {
            const int d = dt * 16 + lm;
#pragma unroll
            for (int rr = 0; rr < 4; rr++) {
                const int jl = wv * 32 + jt * 16 + lq * 4 + rr;
                cp[jl * 64 + d] = (_Float16)acc[jt][dt][rr];
            }
        }
    }
    if (tid < 128) atomicAdd(ws + O_KSUM + bh * 256 + jh * 128 + tid, ksum_s[tid]);
}

// ---------------- query-side: dd, rowmax, qp, attG = qp.ctx / (qp.ksum) (fp16 MFMA) ----
__launch_bounds__(256)
__global__ void k_qout(float* __restrict__ ws) {
    __shared__ _Float16 Qh[64 * 68];
    __shared__ _Float16 qp_s[64 * 260];
    __shared__ float ksum_s[256];
    __shared__ float diag4[64][4];
    __shared__ float diag_s[64];
    __shared__ unsigned rmax_s[64];
    __shared__ float denom_s[64];
    const int bh = blockIdx.x, b = bh / 6, h = bh % 6;
    const int n0 = blockIdx.y * 64;
    const _Float16* __restrict__ Qp = (const _Float16*)(ws + O_Q) + (size_t)(b * 8 + h) * 8192 * 64;
    const _Float16* __restrict__ projh = (const _Float16*)(ws + O_PH);
    const _Float16* __restrict__ ct = (const _Float16*)(ws + O_CTXT) + (size_t)bh * 16384;
    _Float16* __restrict__ attG = (_Float16*)(ws + O_K);
    const int tid = threadIdx.x;
    const int wv = tid >> 6, lane = tid & 63, lm = lane & 15, lq = lane >> 4;
    if (tid < 64) { rmax_s[tid] = 0u; denom_s[tid] = 0.f; }
    ksum_s[tid] = ws[O_KSUM + bh * 256 + tid];

    {
        const int r = tid >> 2, dq = (tid & 3) * 16;
        const _Float16* qpp = Qp + (size_t)(n0 + r) * 64 + dq;
        half8 h0 = *(const half8*)(qpp);
        half8 h1 = *(const half8*)(qpp + 8);
        *(half8*)&Qh[r * 68 + dq]     = h0;
        *(half8*)&Qh[r * 68 + dq + 8] = h1;
        diag4[r][tid & 3] = sumsq8(h0) + sumsq8(h1);
    }
    __syncthreads();
    if (tid < 64) {
        float4 d4 = *(float4*)diag4[tid];
        diag_s[tid] = (d4.x + d4.y + d4.z + d4.w) * 0.0625f;
    }
    floatx4 s4[4][4];
#pragma unroll
    for (int nt = 0; nt < 4; nt++)
#pragma unroll
        for (int jt = 0; jt < 4; jt++) s4[nt][jt] = (floatx4){0.f, 0.f, 0.f, 0.f};
#pragma unroll
    for (int ks = 0; ks < 2; ks++) {
        half8 af[4], bf[4];
#pragma unroll
        for (int nt = 0; nt < 4; nt++)
            af[nt] = *(half8*)&Qh[(nt * 16 + lm) * 68 + ks * 32 + lq * 8];
#pragma unroll
        for (int jt = 0; jt < 4; jt++)
            bf[jt] = *(const half8*)(projh + (wv * 64 + jt * 16 + lm) * 64 + ks * 32 + lq * 8);
#pragma unroll
        for (int nt = 0; nt < 4; nt++)
#pragma unroll
            for (int jt = 0; jt < 4; jt++)
                s4[nt][jt] = __builtin_amdgcn_mfma_f32_16x16x32_f16(af[nt], bf[jt], s4[nt][jt], 0, 0, 0);
    }
#pragma unroll
    for (int nt = 0; nt < 4; nt++) {
#pragma unroll
        for (int rr = 0; rr < 4; rr++) {
            float m0 = fmaxf(fmaxf(s4[nt][0][rr], s4[nt][1][rr]),
                             fmaxf(s4[nt][2][rr], s4[nt][3][rr]));
            m0 = fmaxf(m0, __shfl_xor(m0, 1, 64));
            m0 = fmaxf(m0, __shfl_xor(m0, 2, 64));
            m0 = fmaxf(m0, __shfl_xor(m0, 4, 64));
            m0 = fmaxf(m0, __shfl_xor(m0, 8, 64));
            if (lm == 0) atomicMax(&rmax_s[nt * 16 + lq * 4 + rr], encf(m0 * NORMC));
        }
    }
    __syncthreads();
#pragma unroll
    for (int nt = 0; nt < 4; nt++) {
#pragma unroll
        for (int rr = 0; rr < 4; rr++) {
            const int row = nt * 16 + lq * 4 + rr;
            const float rmx = decf(rmax_s[row]);
            const float dgv = diag_s[row];
#pragma unroll
            for (int jt = 0; jt < 4; jt++) {
                const int j = wv * 64 + jt * 16 + lm;
                float v = RATIO * (__expf(fminf(NORMC * s4[nt][jt][rr] - dgv - rmx, 0.f)) + KEPS);
                qp_s[row * 260 + j] = (_Float16)v;
                s4[nt][jt][rr] = v * ksum_s[j];
            }
            float ds = s4[nt][0][rr] + s4[nt][1][rr] + s4[nt][2][rr] + s4[nt][3][rr];
            ds += __shfl_xor(ds, 1, 64);
            ds += __shfl_xor(ds, 2, 64);
            ds += __shfl_xor(ds, 4, 64);
            ds += __shfl_xor(ds, 8, 64);
            if (lm == 0) atomicAdd(&denom_s[row], ds);
        }
    }
    __syncthreads();
    floatx4 acc2[4];
#pragma unroll
    for (int nt = 0; nt < 4; nt++) acc2[nt] = (floatx4){0.f, 0.f, 0.f, 0.f};
#pragma unroll
    for (int ks = 0; ks < 8; ks++) {
        half8 bfv = *(const half8*)(ct + (wv * 16 + lm) * 256 + ks * 32 + lq * 8);
#pragma unroll
        for (int nt = 0; nt < 4; nt++) {
            half8 af = *(half8*)&qp_s[(nt * 16 + lm) * 260 + ks * 32 + lq * 8];
            acc2[nt] = __builtin_amdgcn_mfma_f32_16x16x32_f16(af, bfv, acc2[nt], 0, 0, 0);
        }
    }
#pragma unroll
    for (int nt = 0; nt < 4; nt++) {
#pragma unroll
        for (int rr = 0; rr < 4; rr++) {
            const int row = nt * 16 + lq * 4 + rr;
            const float inv = 1.0f / fmaxf(denom_s[row], 1e-30f);
            attG[((size_t)(b * 8192 + n0 + row)) * 384 + h * 64 + wv * 16 + lm] =
                (_Float16)(acc2[nt][rr] * inv);
        }
    }
}

// ---------------- local windowed attention, heads 6..7 (pre-RoPE'd, reg-prefetch) -------
__launch_bounds__(256)
__global__ void k_local(float* __restrict__ ws) {
    __shared__ _Float16 Kh[64 * 68];
    __shared__ _Float16 Vt[64 * 68];
    __shared__ _Float16 pT[64 * 68];
    const int bhp = blockIdx.x, b = bhp >> 1, lh = bhp & 1, h = 6 + lh;
    const int tile = blockIdx.y;
    const int w = tile >> 2;
    const int q0 = tile * 64;
    const _Float16* __restrict__ Qr = (const _Float16*)(ws + O_QR) + (size_t)(b * 2 + lh) * 8192 * 64;
    const _Float16* __restrict__ Kr = (const _Float16*)(ws + O_KR) + (size_t)(b * 2 + lh) * 8192 * 64;
    const _Float16* __restrict__ Vb = (const _Float16*)(ws + O_V) + (size_t)(b * 8 + h) * 8192 * 64;
    const int tid = threadIdx.x;
    const int wv = tid >> 6, lane = tid & 63, lm = lane & 15, lq = lane >> 4;
    const int row = tid >> 2, dqo = (tid & 3) * 16;
    const int vd = lane, vnb = wv * 16;

    const _Float16* qrow = Qr + (size_t)(q0 + wv * 16 + lm) * 64 + lq * 8;
    const half8 aq0 = *(const half8*)(qrow);
    const half8 aq1 = *(const half8*)(qrow + 32);

    const int clo = (w == 0) ? 4 : 0;
    const int chi = min(12, 132 - 4 * w);
    half8 kb0, kb1;
    _Float16 vb[16];
    {
        const int kp0 = (w - 1) * 256 + clo * 64;
        const _Float16* kp = Kr + (size_t)(kp0 + row) * 64 + dqo;
        kb0 = *(const half8*)(kp);
        kb1 = *(const half8*)(kp + 8);
#pragma unroll
        for (int i = 0; i < 16; i++) vb[i] = Vb[(size_t)(kp0 + vnb + i) * 64 + vd];
    }
    floatx4 O[4];
#pragma unroll
    for (int df = 0; df < 4; df++) O[df] = (floatx4){0.f, 0.f, 0.f, 0.f};
    float m_run[4] = {-1e30f, -1e30f, -1e30f, -1e30f};
    float l_run[4] = {0.f, 0.f, 0.f, 0.f};

    for (int c = clo; c < chi; c++) {
        if (c > clo) __syncthreads();
        *(half8*)&Kh[row * 68 + dqo]     = kb0;
        *(half8*)&Kh[row * 68 + dqo + 8] = kb1;
        *(half8*)&Vt[vd * 68 + vnb]     = *(half8*)&vb[0];
        *(half8*)&Vt[vd * 68 + vnb + 8] = *(half8*)&vb[8];
        __syncthreads();
        if (c + 1 < chi) {
            const int kp0 = (w - 1) * 256 + (c + 1) * 64;
            const _Float16* kp = Kr + (size_t)(kp0 + row) * 64 + dqo;
            kb0 = *(const half8*)(kp);
            kb1 = *(const half8*)(kp + 8);
#pragma unroll
            for (int i = 0; i < 16; i++) vb[i] = Vb[(size_t)(kp0 + vnb + i) * 64 + vd];
        }
        floatx4 s4[4];
#pragma unroll
        for (int nf = 0; nf < 4; nf++) s4[nf] = (floatx4){0.f, 0.f, 0.f, 0.f};
#pragma unroll
        for (int ks = 0; ks < 2; ks++) {
            half8 aq = ks ? aq1 : aq0;
            half8 bf[4];
#pragma unroll
            for (int nf = 0; nf < 4; nf++)
                bf[nf] = *(half8*)&Kh[(nf * 16 + lm) * 68 + ks * 32 + lq * 8];
#pragma unroll
            for (int nf = 0; nf < 4; nf++)
                s4[nf] = __builtin_amdgcn_mfma_f32_16x16x32_f16(aq, bf[nf], s4[nf], 0, 0, 0);
        }
        float p[4][4];
#pragma unroll
        for (int rr = 0; rr < 4; rr++) {
            float m0 = fmaxf(fmaxf(s4[0][rr], s4[1][rr]), fmaxf(s4[2][rr], s4[3][rr]));
            m0 = fmaxf(m0, __shfl_xor(m0, 1, 64));
            m0 = fmaxf(m0, __shfl_xor(m0, 2, 64));
            m0 = fmaxf(m0, __shfl_xor(m0, 4, 64));
            m0 = fmaxf(m0, __shfl_xor(m0, 8, 64));
            const float mn = fmaxf(m_run[rr], m0 * 0.125f);
            const float al = __expf(m_run[rr] - mn);
            m_run[rr] = mn;
            float rs = 0.f;
#pragma unroll
            for (int nf = 0; nf < 4; nf++) {
                float pv = __expf(fmaf(s4[nf][rr], 0.125f, -mn));
                p[nf][rr] = pv;
                rs += pv;
            }
            l_run[rr] = l_run[rr] * al + rs;
#pragma unroll
            for (int df = 0; df < 4; df++) O[df][rr] *= al;
        }
#pragma unroll
        for (int nf = 0; nf < 4; nf++)
#pragma unroll
            for (int rr = 0; rr < 4; rr++)
                pT[(wv * 16 + lq * 4 + rr) * 68 + nf * 16 + lm] = (_Float16)p[nf][rr];
        asm volatile("s_waitcnt lgkmcnt(0)" ::: "memory");
#pragma unroll
        for (int ks = 0; ks < 2; ks++) {
            half8 ap = *(half8*)&pT[(wv * 16 + lm) * 68 + ks * 32 + lq * 8];
            half8 bf[4];
#pragma unroll
            for (int df = 0; df < 4; df++)
                bf[df] = *(half8*)&Vt[(df * 16 + lm) * 68 + ks * 32 + lq * 8];
#pragma unroll
            for (int df = 0; df < 4; df++)
                O[df] = __builtin_amdgcn_mfma_f32_16x16x32_f16(ap, bf[df], O[df], 0, 0, 0);
        }
    }
#pragma unroll
    for (int rr = 0; rr < 4; rr++) {
        l_run[rr] += __shfl_xor(l_run[rr], 1, 64);
        l_run[rr] += __shfl_xor(l_run[rr], 2, 64);
        l_run[rr] += __shfl_xor(l_run[rr], 4, 64);
        l_run[rr] += __shfl_xor(l_run[rr], 8, 64);
        l_run[rr] = 1.f / fmaxf(l_run[rr], 1e-30f);
    }
    _Float16* __restrict__ attL = (_Float16*)(ws + O_ATTL);
#pragma unroll
    for (int df = 0; df < 4; df++) {
#pragma unroll
        for (int rr = 0; rr < 4; rr++) {
            const int q = q0 + wv * 16 + lq * 4 + rr;
            attL[((size_t)(b * 2 + lh) * 8192 + q) * 64 + df * 16 + lm] =
                (_Float16)(O[df][rr] * l_run[rr]);
        }
    }
}

// ---------------- output projection + bias (fp16 MFMA) ----------------
__launch_bounds__(256)
__global__ void k_out(const float* __restrict__ bo,
                      const float* __restrict__ ws,
                      float* __restrict__ out) {
    __shared__ _Float16 Ah[128 * 72];
    __shared__ _Float16 Bh[128 * 72];
    const _Float16* __restrict__ attG = (const _Float16*)(ws + O_K);
    const _Float16* __restrict__ attL = (const _Float16*)(ws + O_ATTL);
    const _Float16* __restrict__ WoT = (const _Float16*)(ws + O_CTX);
    const int r0 = blockIdx.x * 128, c0 = blockIdx.y * 128;
    const int tid = threadIdx.x;
    const int wv = tid >> 6, lane = tid & 63, lm = lane & 15, lq = lane >> 4;
    const int srow = tid >> 1, skoff = (tid & 1) * 32;
    floatx4 acc[2][8];
#pragma unroll
    for (int m = 0; m < 2; m++)
#pragma unroll
        for (int n = 0; n < 8; n++) acc[m][n] = (floatx4){0.f, 0.f, 0.f, 0.f};

    for (int c = 0; c < 8; c++) {
        const int k0 = c * 64;
        {
            const int row = r0 + srow;
            const int kk = k0 + skoff;
            const _Float16* ap;
            if (kk < 384) {
                ap = attG + (size_t)row * 384 + kk;
            } else {
                const int bb = row >> 13, nn = row & 8191;
                const int kr = kk - 384;
                ap = attL + ((size_t)(bb * 2 + (kr >> 6)) * 8192 + nn) * 64 + (kr & 63);
            }
#pragma unroll
            for (int q = 0; q < 4; q++)
                *(uint4*)&Ah[srow * 72 + skoff + 8 * q] = *(const uint4*)(ap + 8 * q);
        }
        {
            const _Float16* bp = WoT + (size_t)(c0 + srow) * 512 + k0 + skoff;
#pragma unroll
            for (int q = 0; q < 4; q++)
                *(uint4*)&Bh[srow * 72 + skoff + 8 * q] = *(const uint4*)(bp + 8 * q);
        }
        __syncthreads();
#pragma unroll
        for (int ks = 0; ks < 2; ks++) {
            half8 af[2], bf[8];
            af[0] = *(half8*)&Ah[(wv * 32 + lm) * 72 + ks * 32 + lq * 8];
            af[1] = *(half8*)&Ah[(wv * 32 + 16 + lm) * 72 + ks * 32 + lq * 8];
#pragma unroll
            for (int n = 0; n < 8; n++)
                bf[n] = *(half8*)&Bh[(n * 16 + lm) * 72 + ks * 32 + lq * 8];
#pragma unroll
            for (int m = 0; m < 2; m++)
#pragma unroll
                for (int n = 0; n < 8; n++)
                    acc[m][n] = __builtin_amdgcn_mfma_f32_16x16x32_f16(af[m], bf[n], acc[m][n], 0, 0, 0);
        }
        __syncthreads();
    }
#pragma unroll
    for (int n = 0; n < 8; n++) {
        const int col = c0 + n * 16 + lm;
        const float bias = bo[col];
#pragma unroll
        for (int m = 0; m < 2; m++) {
            const int rbase = r0 + wv * 32 + m * 16 + lq * 4;
#pragma unroll
            for (int j = 0; j < 4; j++)
                out[(size_t)(rbase + j) * 512 + col] = acc[m][n][j] + bias;
        }
    }
}

extern "C" void kernel_launch(void* const* d_in, const int* in_sizes, int n_in,
                              void* d_out, int out_size, void* d_ws, size_t ws_size,
                              hipStream_t stream) {
    const float* x    = (const float*)d_in[0];
    const float* Wq   = (const float*)d_in[1];
    const float* Wk   = (const float*)d_in[2];
    const float* Wv   = (const float*)d_in[3];
    const float* Wo   = (const float*)d_in[4];
    const float* bo   = (const float*)d_in[5];
    const float* proj = (const float*)d_in[6];
    float* ws = (float*)d_ws;
    float* out = (float*)d_out;

    hipMemsetAsync(d_ws, 0, (size_t)3136 * 4, stream);                   // kmax/ksum only
    hipLaunchKernelGGL(k_rope,   dim3(1024), dim3(256), 0, stream, ws);
    hipLaunchKernelGGL(k_half_x, dim3(4096), dim3(256), 0, stream, x, ws);
    hipLaunchKernelGGL(k_half_w, dim3(8, 8, 3), dim3(256), 0, stream, Wq, Wk, Wv, ws);
    hipLaunchKernelGGL(k_qkv,    dim3(128, 4, 3), dim3(256), 0, stream, ws);
    hipLaunchKernelGGL(k_ropeqk, dim3(512), dim3(256), 0, stream, ws);
    hipLaunchKernelGGL(k_half_p, dim3(8), dim3(256), 0, stream, proj, ws);
    hipLaunchKernelGGL(k_kmax,   dim3(12, 128), dim3(256), 0, stream, ws);
    hipLaunchKernelGGL(k_kctx,   dim3(12, 32, 2), dim3(256), 0, stream, ws);
    hipLaunchKernelGGL(k_ctxt,   dim3(12, 16), dim3(256), 0, stream, ws);   // reduce partials
    hipLaunchKernelGGL(k_local,  dim3(4, 128), dim3(256), 0, stream, ws);   // before k_qout!
    hipLaunchKernelGGL(k_qout,   dim3(12, 128), dim3(256), 0, stream, ws);
    hipLaunchKernelGGL(k_half_wo, dim3(8, 8), dim3(256), 0, stream, Wo, ws); // ctx region -> WoT
    hipLaunchKernelGGL(k_out,    dim3(128, 4), dim3(256), 0, stream, bo, ws, out);
}